// Round 6
// baseline (650.524 us; speedup 1.0000x reference)
//
#include <hip/hip_runtime.h>
#include <math.h>

#define BB 4
#define NN 1024
#define DIMM 1024
#define HHH 16
#define DHH 64
#define BN 4096            // B*N rows
#define EPS_LN 1e-6f

typedef __bf16 bf16_t;
typedef __bf16 bf16x8 __attribute__((ext_vector_type(8)));
typedef float f32x4 __attribute__((ext_vector_type(4)));
typedef float f32x16 __attribute__((ext_vector_type(16)));
#define MFMA16(a, b, c) __builtin_amdgcn_mfma_f32_16x16x32_bf16(a, b, c, 0, 0, 0)
#define MFMA32(a, b, c) __builtin_amdgcn_mfma_f32_32x32x16_bf16(a, b, c, 0, 0, 0)
#define AS1 __attribute__((address_space(1)))
#define AS3 __attribute__((address_space(3)))

__device__ inline unsigned pk2(float a, float b) {
  union { bf16_t h[2]; unsigned u; } c;
  c.h[0] = (bf16_t)a; c.h[1] = (bf16_t)b;
  return c.u;
}

// ============================================================
// pack_x: Axaug[4096][2048] = bf16([xr | xi])
// ============================================================
__global__ __launch_bounds__(256) void pack_x(
    const float* __restrict__ xr, const float* __restrict__ xi,
    bf16_t* __restrict__ out)
{
  int t = blockIdx.x * 256 + threadIdx.x;
  size_t e = (size_t)t * 8;
  int row = (int)(e >> 11), col = (int)(e & 2047);
  const float* src = (col < 1024) ? (xr + (size_t)row * 1024 + col)
                                  : (xi + (size_t)row * 1024 + col - 1024);
  float4 a = *(const float4*)src;
  float4 b = *(const float4*)(src + 4);
  bf16x8 o;
  o[0] = (bf16_t)a.x; o[1] = (bf16_t)a.y; o[2] = (bf16_t)a.z; o[3] = (bf16_t)a.w;
  o[4] = (bf16_t)b.x; o[5] = (bf16_t)b.y; o[6] = (bf16_t)b.z; o[7] = (bf16_t)b.w;
  *(bf16x8*)(out + e) = o;
}

// ============================================================
// pack_w: Wcat[2048][2048]: rows 0-1023 = [Wr | -Wi], rows 1024-2047 = [Wi | Wr]
// ============================================================
__global__ __launch_bounds__(256) void pack_w(
    const float* __restrict__ Wr, const float* __restrict__ Wi,
    const float* __restrict__ br, const float* __restrict__ bi,
    bf16_t* __restrict__ Wcat, float* __restrict__ bcat)
{
  int t = blockIdx.x * 256 + threadIdx.x;
  size_t e = (size_t)t * 8;
  int row = (int)(e >> 11), col = (int)(e & 2047);
  const float* src;
  float sgn = 1.f;
  if (row < 1024) {
    if (col < 1024) src = Wr + (size_t)row * 1024 + col;
    else          { src = Wi + (size_t)row * 1024 + col - 1024; sgn = -1.f; }
  } else {
    int r2 = row - 1024;
    if (col < 1024) src = Wi + (size_t)r2 * 1024 + col;
    else            src = Wr + (size_t)r2 * 1024 + col - 1024;
  }
  float4 a = *(const float4*)src;
  float4 b = *(const float4*)(src + 4);
  bf16x8 o;
  o[0] = (bf16_t)(sgn * a.x); o[1] = (bf16_t)(sgn * a.y);
  o[2] = (bf16_t)(sgn * a.z); o[3] = (bf16_t)(sgn * a.w);
  o[4] = (bf16_t)(sgn * b.x); o[5] = (bf16_t)(sgn * b.y);
  o[6] = (bf16_t)(sgn * b.z); o[7] = (bf16_t)(sgn * b.w);
  *(bf16x8*)(Wcat + e) = o;
  if (e < 2048) {
#pragma unroll
    for (int j = 0; j < 8; ++j) {
      int n = (int)e + j;
      bcat[n] = (n < 1024) ? br[n] : bi[n - 1024];
    }
  }
}

// ============================================================
// bf16 MFMA GEMM (NT), m97 structure (unchanged).
// ============================================================
__global__ __launch_bounds__(256) void gemm_bf16(
    const bf16_t* __restrict__ A, const bf16_t* __restrict__ Bt,
    const float* __restrict__ bias,
    float* __restrict__ Cr, float* __restrict__ Ci, int ldc)
{
  __shared__ bf16_t sA[128 * 64];
  __shared__ bf16_t sB[128 * 64];
  const int tid = threadIdx.x;
  const int w = tid >> 6, l = tid & 63;
  const int lo4 = l & 15, hi = l >> 4;
  const int wr = w >> 1, wc = w & 1;
  const int row0 = blockIdx.y * 128, col0 = blockIdx.x * 128;

  const int srow = (l >> 3);
  const int scol = (l & 7) * 8;
  const bf16_t* gA[4];
  const bf16_t* gB[4];
#pragma unroll
  for (int i = 0; i < 4; ++i) {
    int r = (w * 4 + i) * 8 + srow;
    gA[i] = A  + (size_t)(row0 + r) * 2048 + scol;
    gB[i] = Bt + (size_t)(col0 + r) * 2048 + scol;
  }

  f32x4 acc[4][4] = {};
  for (int k0 = 0; k0 < 2048; k0 += 64) {
    __syncthreads();
#pragma unroll
    for (int i = 0; i < 4; ++i) {
      __builtin_amdgcn_global_load_lds((const AS1 void*)(gA[i] + k0),
                                       (AS3 void*)&sA[(w * 4 + i) * 512], 16, 0, 0);
      __builtin_amdgcn_global_load_lds((const AS1 void*)(gB[i] + k0),
                                       (AS3 void*)&sB[(w * 4 + i) * 512], 16, 0, 0);
    }
    __syncthreads();
#pragma unroll
    for (int kk = 0; kk < 2; ++kk) {
      bf16x8 am[4], bn[4];
#pragma unroll
      for (int i = 0; i < 4; ++i)
        am[i] = *(const bf16x8*)&sA[(wr * 64 + i * 16 + lo4) * 64 + kk * 32 + hi * 8];
#pragma unroll
      for (int j = 0; j < 4; ++j)
        bn[j] = *(const bf16x8*)&sB[(wc * 64 + j * 16 + lo4) * 64 + kk * 32 + hi * 8];
#pragma unroll
      for (int i = 0; i < 4; ++i)
#pragma unroll
        for (int j = 0; j < 4; ++j)
          acc[i][j] = MFMA16(am[i], bn[j], acc[i][j]);
    }
  }
  const int colg0 = col0 + wc * 64;
  float* Cp = (colg0 < 1024) ? Cr : Ci;
  const int cb = colg0 & 1023;
#pragma unroll
  for (int i = 0; i < 4; ++i) {
#pragma unroll
    for (int j = 0; j < 4; ++j) {
      float bv = bias[colg0 + j * 16 + lo4];
#pragma unroll
      for (int r = 0; r < 4; ++r) {
        int rowg = row0 + wr * 64 + i * 16 + hi * 4 + r;
        Cp[(size_t)rowg * ldc + cb + j * 16 + lo4] = acc[i][j][r] + bv;
      }
    }
  }
}

// ============================================================
// Complex LayerNorm (fp32 in-place, unchanged)
// ============================================================
__global__ __launch_bounds__(256) void cln_kernel(
    float* __restrict__ re, float* __restrict__ im,
    const float* __restrict__ gamma, const float* __restrict__ beta)
{
  __shared__ float red[8];
  const int row = blockIdx.x;
  const int tid = threadIdx.x;
  float* pr = re + (size_t)row * DIMM;
  float* pi = im + (size_t)row * DIMM;
  float vr[4], vi[4], mg[4];
  float s = 0.f, s2 = 0.f;
#pragma unroll
  for (int t = 0; t < 4; ++t) {
    int c = tid + t * 256;
    vr[t] = pr[c]; vi[t] = pi[c];
    mg[t] = sqrtf(vr[t] * vr[t] + vi[t] * vi[t]);
    s += mg[t]; s2 += mg[t] * mg[t];
  }
#pragma unroll
  for (int o = 32; o; o >>= 1) { s += __shfl_down(s, o); s2 += __shfl_down(s2, o); }
  if ((tid & 63) == 0) { red[tid >> 6] = s; red[4 + (tid >> 6)] = s2; }
  __syncthreads();
  if (tid == 0) {
    float S = red[0] + red[1] + red[2] + red[3];
    float S2 = red[4] + red[5] + red[6] + red[7];
    float mean = S * (1.f / DIMM);
    float var = S2 * (1.f / DIMM) - mean * mean;
    red[0] = mean;
    red[1] = rsqrtf(var + EPS_LN);
  }
  __syncthreads();
  float mean = red[0], inv = red[1];
#pragma unroll
  for (int t = 0; t < 4; ++t) {
    int c = tid + t * 256;
    float nm = (mg[t] - mean) * inv * gamma[c] + beta[c];
    float invm = mg[t] > 0.f ? 1.f / mg[t] : 0.f;
    float cr = mg[t] > 0.f ? vr[t] * invm : 1.f;
    float ci = mg[t] > 0.f ? vi[t] * invm : 0.f;
    pr[c] = nm * cr;
    pi[c] = nm * ci;
  }
}

// ============================================================
// 1024-pt radix-2 DIF FFT, LDS twiddle table; fp32 in, bf16 out.
// ============================================================
#define FD 4
__global__ __launch_bounds__(512) void fft_kernel(
    const float* __restrict__ inR, const float* __restrict__ inI,
    bf16_t* __restrict__ outR, bf16_t* __restrict__ outI,
    int in_sb, int in_sh, int in_sn, int in_sd,
    int out_sb, int out_sh, int out_sn, int out_sd,
    float sign, float oscale)
{
  __shared__ float lr[FD][NN + 1], li[FD][NN + 1];
  __shared__ float2 tw[512];
  const int tid = threadIdx.x;
  const int dc = blockIdx.x & 15;
  const int bh = blockIdx.x >> 4;
  const int b = bh >> 4, h = bh & 15;
  const float* bR = inR + (size_t)b * in_sb + (size_t)h * in_sh;
  const float* bI = inI + (size_t)b * in_sb + (size_t)h * in_sh;
  {
    float ang = sign * 3.14159265358979323846f * (float)tid * (1.f / 512.f);
    float sn, cs;
    __sincosf(ang, &sn, &cs);
    tw[tid] = make_float2(cs, sn);
  }
#pragma unroll
  for (int it = 0; it < 8; ++it) {
    int flat = it * 512 + tid;
    int ds = flat & 3, n = flat >> 2;
    size_t ga = (size_t)(dc * FD + ds) * in_sd + (size_t)n * in_sn;
    lr[ds][n] = bR[ga];
    li[ds][n] = bI[ga];
  }
  __syncthreads();
  const int dsub = tid & 3;
  const int jb = tid >> 2;
  for (int hs = 9; hs >= 0; --hs) {
    int half = 1 << hs;
#pragma unroll
    for (int it = 0; it < 4; ++it) {
      int j = jb + it * 128;
      int o = j & (half - 1);
      int i0 = ((j >> hs) << (hs + 1)) + o;
      int i1 = i0 + half;
      float ar = lr[dsub][i0], ai = li[dsub][i0];
      float br_ = lr[dsub][i1], bi_ = li[dsub][i1];
      lr[dsub][i0] = ar + br_;
      li[dsub][i0] = ai + bi_;
      float sr = ar - br_, si = ai - bi_;
      float2 t = tw[o << (9 - hs)];
      lr[dsub][i1] = sr * t.x - si * t.y;
      li[dsub][i1] = sr * t.y + si * t.x;
    }
    __syncthreads();
  }
  bf16_t* oR = outR + (size_t)b * out_sb + (size_t)h * out_sh;
  bf16_t* oI = outI + (size_t)b * out_sb + (size_t)h * out_sh;
#pragma unroll
  for (int it = 0; it < 8; ++it) {
    int flat = it * 512 + tid;
    int ds = flat & 3, n = flat >> 2;
    int rev = __brev((unsigned)n) >> 22;
    size_t ga = (size_t)(dc * FD + ds) * out_sd + (size_t)n * out_sn;
    oR[ga] = (bf16_t)(lr[ds][rev] * oscale);
    oI[ga] = (bf16_t)(li[ds][rev] * oscale);
  }
}

// ============================================================
// Flash attention v3: swapped-operand 32x32 MFMA, no LDS,
// + register double-buffer prefetch (batch-issue V[t], K[t+1] before
//   consuming; hides L2/L3 latency under softmax+MFMA at 2 waves/SIMD)
// + XCD-locality blockIdx swizzle (8 q-blocks of one bh -> same XCD L2).
// Grid 512 = 64 bh x 8 qb; block 256 = 4 waves x 32 q-rows.
// ============================================================
__global__ __launch_bounds__(256, 2) void fattn(
    const bf16_t* __restrict__ Qf, const bf16_t* __restrict__ Kf,
    const bf16_t* __restrict__ VfT, float* __restrict__ OT)
{
  const int tid = threadIdx.x;
  const int w = tid >> 6, l = tid & 63;
  const int lq = l & 31;            // q-column within wave tile
  const int h = l >> 5;             // lane half
  // XCD-locality swizzle (bijective on 0..511): xcd = i&7 owns bh in [xcd*8, xcd*8+8)
  const int i = blockIdx.x;
  const int j = i >> 3;
  const int bh = (i & 7) * 8 + (j >> 3);
  const int q0 = (j & 7) * 128 + w * 32;

  // Q fragments (B-operand): frag kk holds k = kk*16 + h*8 + j
  bf16x8 bq[8];
  const bf16_t* qp = Qf + ((size_t)bh * NN + q0 + lq) * 128 + h * 8;
#pragma unroll
  for (int kk = 0; kk < 8; ++kk) bq[kk] = *(const bf16x8*)(qp + kk * 16);

  f32x16 o[4] = {};                 // O^T d-blocks (static indexing only)
  float m = -3e38f, ln = 0.f;

  const bf16_t* kb = Kf + (size_t)bh * NN * 128 + h * 8;
  const bf16_t* vb = VfT + (size_t)bh * 128 * NN;

  // prologue: K[0] into registers
  bf16x8 kc[8];
  {
    const bf16_t* kp0 = kb + (size_t)lq * 128;
#pragma unroll
    for (int kk = 0; kk < 8; ++kk) kc[kk] = *(const bf16x8*)(kp0 + kk * 16);
  }

#pragma unroll 2
  for (int kv0 = 0; kv0 < NN; kv0 += 32) {
    // ---- batch-issue V[t] loads (consumed after softmax) ----
    bf16x8 vc[8];
#pragma unroll
    for (int db = 0; db < 4; ++db)
#pragma unroll
      for (int ks = 0; ks < 2; ++ks)
        vc[db * 2 + ks] = *(const bf16x8*)
            (vb + (size_t)(db * 32 + lq) * NN + kv0 + ks * 16 + h * 8);
    // ---- batch-issue K[t+1] loads (consumed next iteration; wrap tail) ----
    bf16x8 kn[8];
    {
      int kvn = (kv0 + 32) & (NN - 1);
      const bf16_t* kpn = kb + (size_t)(kvn + lq) * 128;
#pragma unroll
      for (int kk = 0; kk < 8; ++kk) kn[kk] = *(const bf16x8*)(kpn + kk * 16);
    }
    // ---- S^T[k][q] from in-register K (no memory wait) ----
    f32x16 s = {};
#pragma unroll
    for (int kk = 0; kk < 8; ++kk) s = MFMA32(kc[kk], bq[kk], s);
    // ---- online softmax (lane owns 16 k-rows of its q-column) ----
    float pmax = s[0];
#pragma unroll
    for (int r = 1; r < 16; ++r) pmax = fmaxf(pmax, s[r]);
    pmax = fmaxf(pmax, __shfl_xor(pmax, 32));
    float mnew = fmaxf(m, pmax);
    float alpha = __expf(m - mnew);
    float pf[16];
    float rs = 0.f;
#pragma unroll
    for (int r = 0; r < 16; ++r) { pf[r] = __expf(s[r] - mnew); rs += pf[r]; }
    rs += __shfl_xor(rs, 32);
    ln = ln * alpha + rs;
    m = mnew;
#pragma unroll
    for (int db = 0; db < 4; ++db)
#pragma unroll
      for (int r = 0; r < 16; ++r) o[db][r] *= alpha;
    // ---- P -> bf16 B-fragments via cross-half exchange ----
    unsigned pw[8], qw[8];
#pragma unroll
    for (int ii = 0; ii < 8; ++ii) pw[ii] = pk2(pf[2 * ii], pf[2 * ii + 1]);
#pragma unroll
    for (int ii = 0; ii < 8; ++ii) qw[ii] = (unsigned)__shfl_xor((int)pw[ii], 32);
#pragma unroll
    for (int ks = 0; ks < 2; ++ks) {
      union { unsigned u[4]; bf16x8 v; } bp;
      bp.u[0] = h ? qw[4 * ks + 2] : pw[4 * ks + 0];
      bp.u[1] = h ? qw[4 * ks + 3] : pw[4 * ks + 1];
      bp.u[2] = h ? pw[4 * ks + 2] : qw[4 * ks + 0];
      bp.u[3] = h ? pw[4 * ks + 3] : qw[4 * ks + 1];
      // ---- O^T[db] += V^T . P (V already in registers) ----
#pragma unroll
      for (int db = 0; db < 4; ++db)
        o[db] = MFMA32(vc[db * 2 + ks], bp.v, o[db]);
    }
    // rotate K double-buffer
#pragma unroll
    for (int kk = 0; kk < 8; ++kk) kc[kk] = kn[kk];
  }
  // ---- normalize + coalesced O^T store ----
  float inv = 1.f / ln;
  const size_t otb = (size_t)bh * 128 * NN + q0 + lq;
#pragma unroll
  for (int db = 0; db < 4; ++db)
#pragma unroll
    for (int r = 0; r < 16; ++r) {
      int dl = (r & 3) + 8 * (r >> 2) + 4 * h;
      OT[otb + (size_t)(db * 32 + dl) * NN] = o[db][r] * inv;
    }
}

// ============================================================
// Host-side orchestration
// ============================================================
extern "C" void kernel_launch(void* const* d_in, const int* in_sizes, int n_in,
                              void* d_out, int out_size, void* d_ws, size_t ws_size,
                              hipStream_t stream) {
  const float* xr   = (const float*)d_in[0];
  const float* xi   = (const float*)d_in[1];
  const float* Wqr  = (const float*)d_in[2];
  const float* Wqi  = (const float*)d_in[3];
  const float* bqr  = (const float*)d_in[4];
  const float* bqi  = (const float*)d_in[5];
  const float* Wkr  = (const float*)d_in[6];
  const float* Wki  = (const float*)d_in[7];
  const float* bkr  = (const float*)d_in[8];
  const float* bki  = (const float*)d_in[9];
  const float* Wvr  = (const float*)d_in[10];
  const float* Wvi  = (const float*)d_in[11];
  const float* bvr  = (const float*)d_in[12];
  const float* bvi  = (const float*)d_in[13];
  const float* Wor  = (const float*)d_in[14];
  const float* Woi  = (const float*)d_in[15];
  const float* bor  = (const float*)d_in[16];
  const float* boi  = (const float*)d_in[17];
  const float* gq   = (const float*)d_in[18];
  const float* beq  = (const float*)d_in[19];
  const float* gk   = (const float*)d_in[20];
  const float* bek  = (const float*)d_in[21];
  const float* gv   = (const float*)d_in[22];
  const float* bev  = (const float*)d_in[23];

  char* wp = (char*)d_ws;
  bf16_t* Axaug = (bf16_t*)wp;  wp += (size_t)4096 * 2048 * 2;
  bf16_t* Wcat  = (bf16_t*)wp;  wp += (size_t)2048 * 2048 * 2;
  float*  bcat  = (float*)wp;   wp += (size_t)2048 * 4;
  float*  Ar    = (float*)wp;   wp += (size_t)4096 * 1024 * 4;
  float*  Ai    = (float*)wp;   wp += (size_t)4096 * 1024 * 4;
  bf16_t* Qf    = (bf16_t*)wp;  wp += (size_t)64 * 1024 * 128 * 2;
  bf16_t* Kf    = (bf16_t*)wp;  wp += (size_t)64 * 1024 * 128 * 2;
  bf16_t* VfT   = (bf16_t*)wp;  wp += (size_t)64 * 1024 * 128 * 2;
  bf16_t* Yaug  = Qf;
  float*  OT    = Ar;   // attn output O^T [BH,128,N] fp32 (spans Ar+Ai)

  const dim3 gGemm(16, 32);
  const int gPackX = (4096 * 2048 / 8) / 256;
  const int gPackW = (2048 * 2048 / 8) / 256;
  const int gCln = BN;
  const int gFft = 64 * 16;
  const int gAtt = 64 * 8;

  pack_x<<<gPackX, 256, 0, stream>>>(xr, xi, Axaug);

  // ---- Q (FFT output scale folds in the 1/8 attention scale) ----
  pack_w<<<gPackW, 256, 0, stream>>>(Wqr, Wqi, bqr, bqi, Wcat, bcat);
  gemm_bf16<<<gGemm, 256, 0, stream>>>(Axaug, Wcat, bcat, Ar, Ai, 1024);
  cln_kernel<<<gCln, 256, 0, stream>>>(Ar, Ai, gq, beq);
  fft_kernel<<<gFft, 512, 0, stream>>>(Ar, Ai, Qf, Qf + 64,
      NN * DIMM, DHH, DIMM, 1,
      16 * NN * 128, NN * 128, 128, 1, -1.0f, 0.03125f * 0.125f);
  // ---- K ----
  pack_w<<<gPackW, 256, 0, stream>>>(Wkr, Wki, bkr, bki, Wcat, bcat);
  gemm_bf16<<<gGemm, 256, 0, stream>>>(Axaug, Wcat, bcat, Ar, Ai, 1024);
  cln_kernel<<<gCln, 256, 0, stream>>>(Ar, Ai, gk, bek);
  fft_kernel<<<gFft, 512, 0, stream>>>(Ar, Ai, Kf, Kf + 64,
      NN * DIMM, DHH, DIMM, 1,
      16 * NN * 128, NN * 128, 128, 1, -1.0f, 0.03125f);
  // ---- V (transposed output [BH,128,N]) ----
  pack_w<<<gPackW, 256, 0, stream>>>(Wvr, Wvi, bvr, bvi, Wcat, bcat);
  gemm_bf16<<<gGemm, 256, 0, stream>>>(Axaug, Wcat, bcat, Ar, Ai, 1024);
  cln_kernel<<<gCln, 256, 0, stream>>>(Ar, Ai, gv, bev);
  fft_kernel<<<gFft, 512, 0, stream>>>(Ar, Ai, VfT, VfT + (size_t)64 * NN,
      NN * DIMM, DHH, DIMM, 1,
      16 * 128 * NN, 128 * NN, 1, NN, -1.0f, 0.03125f);
  // ---- flash attention -> OT [BH,128,N] fp32 ----
  fattn<<<gAtt, 256, 0, stream>>>(Qf, Kf, VfT, OT);
  // ---- inverse FFT: OT (d-major) -> Yaug bf16 [4096][2048] ----
  fft_kernel<<<gFft, 512, 0, stream>>>(OT, OT + (size_t)64 * NN, Yaug, Yaug + 1024,
      16 * 128 * NN, 128 * NN, 1, NN,
      NN * 2048, 64, 2048, 1, +1.0f, 0.03125f);
  // ---- output projection straight into d_out ----
  float* yout = (float*)d_out;
  pack_w<<<gPackW, 256, 0, stream>>>(Wor, Woi, bor, boi, Wcat, bcat);
  gemm_bf16<<<gGemm, 256, 0, stream>>>(Yaug, Wcat, bcat, yout, yout + 1024, 2048);
}

// Round 8
// 612.065 us; speedup vs baseline: 1.0628x; 1.0628x over previous
//
#include <hip/hip_runtime.h>
#include <math.h>

#define BB 4
#define NN 1024
#define DIMM 1024
#define HHH 16
#define DHH 64
#define BN 4096            // B*N rows
#define EPS_LN 1e-6f

typedef __bf16 bf16_t;
typedef __bf16 bf16x8 __attribute__((ext_vector_type(8)));
typedef float f32x4 __attribute__((ext_vector_type(4)));
typedef float f32x16 __attribute__((ext_vector_type(16)));
#define MFMA16(a, b, c) __builtin_amdgcn_mfma_f32_16x16x32_bf16(a, b, c, 0, 0, 0)
#define MFMA32(a, b, c) __builtin_amdgcn_mfma_f32_32x32x16_bf16(a, b, c, 0, 0, 0)
#define AS1 __attribute__((address_space(1)))
#define AS3 __attribute__((address_space(3)))

__device__ inline unsigned pk2(float a, float b) {
  union { bf16_t h[2]; unsigned u; } c;
  c.h[0] = (bf16_t)a; c.h[1] = (bf16_t)b;
  return c.u;
}

// ============================================================
// pack_x: Axaug[4096][2048] = bf16([xr | xi])
// ============================================================
__global__ __launch_bounds__(256) void pack_x(
    const float* __restrict__ xr, const float* __restrict__ xi,
    bf16_t* __restrict__ out)
{
  int t = blockIdx.x * 256 + threadIdx.x;
  size_t e = (size_t)t * 8;
  int row = (int)(e >> 11), col = (int)(e & 2047);
  const float* src = (col < 1024) ? (xr + (size_t)row * 1024 + col)
                                  : (xi + (size_t)row * 1024 + col - 1024);
  float4 a = *(const float4*)src;
  float4 b = *(const float4*)(src + 4);
  bf16x8 o;
  o[0] = (bf16_t)a.x; o[1] = (bf16_t)a.y; o[2] = (bf16_t)a.z; o[3] = (bf16_t)a.w;
  o[4] = (bf16_t)b.x; o[5] = (bf16_t)b.y; o[6] = (bf16_t)b.z; o[7] = (bf16_t)b.w;
  *(bf16x8*)(out + e) = o;
}

// ============================================================
// pack_w: Wcat[2048][2048]: rows 0-1023 = [Wr | -Wi], rows 1024-2047 = [Wi | Wr]
// ============================================================
__global__ __launch_bounds__(256) void pack_w(
    const float* __restrict__ Wr, const float* __restrict__ Wi,
    const float* __restrict__ br, const float* __restrict__ bi,
    bf16_t* __restrict__ Wcat, float* __restrict__ bcat)
{
  int t = blockIdx.x * 256 + threadIdx.x;
  size_t e = (size_t)t * 8;
  int row = (int)(e >> 11), col = (int)(e & 2047);
  const float* src;
  float sgn = 1.f;
  if (row < 1024) {
    if (col < 1024) src = Wr + (size_t)row * 1024 + col;
    else          { src = Wi + (size_t)row * 1024 + col - 1024; sgn = -1.f; }
  } else {
    int r2 = row - 1024;
    if (col < 1024) src = Wi + (size_t)r2 * 1024 + col;
    else            src = Wr + (size_t)r2 * 1024 + col - 1024;
  }
  float4 a = *(const float4*)src;
  float4 b = *(const float4*)(src + 4);
  bf16x8 o;
  o[0] = (bf16_t)(sgn * a.x); o[1] = (bf16_t)(sgn * a.y);
  o[2] = (bf16_t)(sgn * a.z); o[3] = (bf16_t)(sgn * a.w);
  o[4] = (bf16_t)(sgn * b.x); o[5] = (bf16_t)(sgn * b.y);
  o[6] = (bf16_t)(sgn * b.z); o[7] = (bf16_t)(sgn * b.w);
  *(bf16x8*)(Wcat + e) = o;
  if (e < 2048) {
#pragma unroll
    for (int j = 0; j < 8; ++j) {
      int n = (int)e + j;
      bcat[n] = (n < 1024) ? br[n] : bi[n - 1024];
    }
  }
}

// ============================================================
// bf16 MFMA GEMM (NT), m97 structure (unchanged).
// ============================================================
__global__ __launch_bounds__(256) void gemm_bf16(
    const bf16_t* __restrict__ A, const bf16_t* __restrict__ Bt,
    const float* __restrict__ bias,
    float* __restrict__ Cr, float* __restrict__ Ci, int ldc)
{
  __shared__ bf16_t sA[128 * 64];
  __shared__ bf16_t sB[128 * 64];
  const int tid = threadIdx.x;
  const int w = tid >> 6, l = tid & 63;
  const int lo4 = l & 15, hi = l >> 4;
  const int wr = w >> 1, wc = w & 1;
  const int row0 = blockIdx.y * 128, col0 = blockIdx.x * 128;

  const int srow = (l >> 3);
  const int scol = (l & 7) * 8;
  const bf16_t* gA[4];
  const bf16_t* gB[4];
#pragma unroll
  for (int i = 0; i < 4; ++i) {
    int r = (w * 4 + i) * 8 + srow;
    gA[i] = A  + (size_t)(row0 + r) * 2048 + scol;
    gB[i] = Bt + (size_t)(col0 + r) * 2048 + scol;
  }

  f32x4 acc[4][4] = {};
  for (int k0 = 0; k0 < 2048; k0 += 64) {
    __syncthreads();
#pragma unroll
    for (int i = 0; i < 4; ++i) {
      __builtin_amdgcn_global_load_lds((const AS1 void*)(gA[i] + k0),
                                       (AS3 void*)&sA[(w * 4 + i) * 512], 16, 0, 0);
      __builtin_amdgcn_global_load_lds((const AS1 void*)(gB[i] + k0),
                                       (AS3 void*)&sB[(w * 4 + i) * 512], 16, 0, 0);
    }
    __syncthreads();
#pragma unroll
    for (int kk = 0; kk < 2; ++kk) {
      bf16x8 am[4], bn[4];
#pragma unroll
      for (int i = 0; i < 4; ++i)
        am[i] = *(const bf16x8*)&sA[(wr * 64 + i * 16 + lo4) * 64 + kk * 32 + hi * 8];
#pragma unroll
      for (int j = 0; j < 4; ++j)
        bn[j] = *(const bf16x8*)&sB[(wc * 64 + j * 16 + lo4) * 64 + kk * 32 + hi * 8];
#pragma unroll
      for (int i = 0; i < 4; ++i)
#pragma unroll
        for (int j = 0; j < 4; ++j)
          acc[i][j] = MFMA16(am[i], bn[j], acc[i][j]);
    }
  }
  const int colg0 = col0 + wc * 64;
  float* Cp = (colg0 < 1024) ? Cr : Ci;
  const int cb = colg0 & 1023;
#pragma unroll
  for (int i = 0; i < 4; ++i) {
#pragma unroll
    for (int j = 0; j < 4; ++j) {
      float bv = bias[colg0 + j * 16 + lo4];
#pragma unroll
      for (int r = 0; r < 4; ++r) {
        int rowg = row0 + wr * 64 + i * 16 + hi * 4 + r;
        Cp[(size_t)rowg * ldc + cb + j * 16 + lo4] = acc[i][j][r] + bv;
      }
    }
  }
}

// ============================================================
// LN row stats: per (b,n) row of [B,N,DIM] complex, compute
// mean(|z|) and rsqrt(var(|z|)+eps). Normalization applied inline
// in the FFT load stage (saves the cln write+re-read round trip).
// ============================================================
__global__ __launch_bounds__(256) void ln_stats(
    const float* __restrict__ re, const float* __restrict__ im,
    float2* __restrict__ st)
{
  __shared__ float red[8];
  const int row = blockIdx.x;
  const int tid = threadIdx.x;
  const float* pr = re + (size_t)row * DIMM;
  const float* pi = im + (size_t)row * DIMM;
  float s = 0.f, s2 = 0.f;
#pragma unroll
  for (int t = 0; t < 4; ++t) {
    int c = tid + t * 256;
    float vr = pr[c], vi = pi[c];
    float mg = sqrtf(vr * vr + vi * vi);
    s += mg; s2 += mg * mg;
  }
#pragma unroll
  for (int o = 32; o; o >>= 1) { s += __shfl_down(s, o); s2 += __shfl_down(s2, o); }
  if ((tid & 63) == 0) { red[tid >> 6] = s; red[4 + (tid >> 6)] = s2; }
  __syncthreads();
  if (tid == 0) {
    float S = red[0] + red[1] + red[2] + red[3];
    float S2 = red[4] + red[5] + red[6] + red[7];
    float mean = S * (1.f / DIMM);
    float var = S2 * (1.f / DIMM) - mean * mean;
    st[row] = make_float2(mean, rsqrtf(var + EPS_LN));
  }
}

// ============================================================
// 1024-pt radix-2 DIF FFT, LDS twiddle table; fp32 in, bf16 out.
// Optional fused complex-LN on load (stats != nullptr).
// Optional kv-tile-blocked V output (vblk): element (n,d) ->
//   (n>>5)*4096 + d*32 + (n&31)  per (b,h), d in [0,64) per plane.
// ============================================================
#define FD 4
__global__ __launch_bounds__(512) void fft_kernel(
    const float* __restrict__ inR, const float* __restrict__ inI,
    bf16_t* __restrict__ outR, bf16_t* __restrict__ outI,
    int in_sb, int in_sh, int in_sn, int in_sd,
    int out_sb, int out_sh, int out_sn, int out_sd,
    float sign, float oscale, int vblk,
    const float2* __restrict__ stats,
    const float* __restrict__ gamma, const float* __restrict__ beta)
{
  __shared__ float lr[FD][NN + 1], li[FD][NN + 1];
  __shared__ float2 tw[512];
  const int tid = threadIdx.x;
  const int dc = blockIdx.x & 15;
  const int bh = blockIdx.x >> 4;
  const int b = bh >> 4, h = bh & 15;
  const float* bR = inR + (size_t)b * in_sb + (size_t)h * in_sh;
  const float* bI = inI + (size_t)b * in_sb + (size_t)h * in_sh;
  {
    float ang = sign * 3.14159265358979323846f * (float)tid * (1.f / 512.f);
    float sn, cs;
    __sincosf(ang, &sn, &cs);
    tw[tid] = make_float2(cs, sn);
  }
#pragma unroll
  for (int it = 0; it < 8; ++it) {
    int flat = it * 512 + tid;
    int ds = flat & 3, n = flat >> 2;
    size_t ga = (size_t)(dc * FD + ds) * in_sd + (size_t)n * in_sn;
    float vr = bR[ga];
    float vi = bI[ga];
    if (stats) {
      float2 stv = stats[b * NN + n];
      int dim = h * DHH + dc * FD + ds;
      float mag = sqrtf(vr * vr + vi * vi);
      float nm = (mag - stv.x) * stv.y * gamma[dim] + beta[dim];
      if (mag > 0.f) { float sc = nm / mag; vr *= sc; vi *= sc; }
      else           { vr = nm; vi = 0.f; }
    }
    lr[ds][n] = vr;
    li[ds][n] = vi;
  }
  __syncthreads();
  const int dsub = tid & 3;
  const int jb = tid >> 2;
  for (int hs = 9; hs >= 0; --hs) {
    int half = 1 << hs;
#pragma unroll
    for (int it = 0; it < 4; ++it) {
      int j = jb + it * 128;
      int o = j & (half - 1);
      int i0 = ((j >> hs) << (hs + 1)) + o;
      int i1 = i0 + half;
      float ar = lr[dsub][i0], ai = li[dsub][i0];
      float br_ = lr[dsub][i1], bi_ = li[dsub][i1];
      lr[dsub][i0] = ar + br_;
      li[dsub][i0] = ai + bi_;
      float sr = ar - br_, si = ai - bi_;
      float2 t = tw[o << (9 - hs)];
      lr[dsub][i1] = sr * t.x - si * t.y;
      li[dsub][i1] = sr * t.y + si * t.x;
    }
    __syncthreads();
  }
  bf16_t* oR = outR + (size_t)b * out_sb + (size_t)h * out_sh;
  bf16_t* oI = outI + (size_t)b * out_sb + (size_t)h * out_sh;
#pragma unroll
  for (int it = 0; it < 8; ++it) {
    int flat = it * 512 + tid;
    int ds = flat & 3, n = flat >> 2;
    int rev = __brev((unsigned)n) >> 22;
    size_t ga;
    if (vblk) {
      int dch = dc * FD + ds;
      ga = (size_t)(n >> 5) * 4096 + (size_t)dch * 32 + (n & 31);
    } else {
      ga = (size_t)(dc * FD + ds) * out_sd + (size_t)n * out_sn;
    }
    oR[ga] = (bf16_t)(lr[ds][rev] * oscale);
    oI[ga] = (bf16_t)(li[ds][rev] * oscale);
  }
}

// ============================================================
// Flash attention v4: swapped-operand 32x32 MFMA, no LDS,
// XCD-locality swizzle, and kv-tile-blocked V so every V-fragment
// load instruction hits a contiguous fully-utilized 2KB window.
// VfT layout: [bh][n/32][128][32] (rows 0-63 real, 64-127 imag).
// Grid 512 = 64 bh x 8 qb; block 256 = 4 waves x 32 q-rows.
// ============================================================
__global__ __launch_bounds__(256, 2) void fattn(
    const bf16_t* __restrict__ Qf, const bf16_t* __restrict__ Kf,
    const bf16_t* __restrict__ VfT, float* __restrict__ OT)
{
  const int tid = threadIdx.x;
  const int w = tid >> 6, l = tid & 63;
  const int lq = l & 31;            // q-column within wave tile
  const int h = l >> 5;             // lane half
  // XCD-locality swizzle (bijective on 0..511)
  const int i = blockIdx.x;
  const int j = i >> 3;
  const int bh = (i & 7) * 8 + (j >> 3);
  const int q0 = (j & 7) * 128 + w * 32;

  // Q fragments (B-operand): frag kk holds k = kk*16 + h*8 + j
  bf16x8 bq[8];
  const bf16_t* qp = Qf + ((size_t)bh * NN + q0 + lq) * 128 + h * 8;
#pragma unroll
  for (int kk = 0; kk < 8; ++kk) bq[kk] = *(const bf16x8*)(qp + kk * 16);

  f32x16 o[4] = {};                 // O^T d-blocks (static indexing only)
  float m = -3e38f, ln = 0.f;

  const bf16_t* kb = Kf + (size_t)bh * NN * 128 + h * 8;
  const bf16_t* vb = VfT + (size_t)bh * 131072 + (size_t)lq * 32 + h * 8;

  // prologue: K[0] into registers
  bf16x8 kc[8];
  {
    const bf16_t* kp0 = kb + (size_t)lq * 128;
#pragma unroll
    for (int kk = 0; kk < 8; ++kk) kc[kk] = *(const bf16x8*)(kp0 + kk * 16);
  }

#pragma unroll 2
  for (int kv0 = 0; kv0 < NN; kv0 += 32) {
    // ---- batch-issue V[t] loads (blocked layout: contiguous 2KB/instr) ----
    bf16x8 vc[8];
    const bf16_t* vt = vb + (size_t)(kv0 >> 5) * 4096;
#pragma unroll
    for (int db = 0; db < 4; ++db)
#pragma unroll
      for (int ks = 0; ks < 2; ++ks)
        vc[db * 2 + ks] = *(const bf16x8*)(vt + db * 1024 + ks * 16);
    // ---- batch-issue K[t+1] loads (wrap tail) ----
    bf16x8 kn[8];
    {
      int kvn = (kv0 + 32) & (NN - 1);
      const bf16_t* kpn = kb + (size_t)(kvn + lq) * 128;
#pragma unroll
      for (int kk = 0; kk < 8; ++kk) kn[kk] = *(const bf16x8*)(kpn + kk * 16);
    }
    // ---- S^T[k][q] from in-register K ----
    f32x16 s = {};
#pragma unroll
    for (int kk = 0; kk < 8; ++kk) s = MFMA32(kc[kk], bq[kk], s);
    // ---- online softmax (lane owns 16 k-rows of its q-column) ----
    float pmax = s[0];
#pragma unroll
    for (int r = 1; r < 16; ++r) pmax = fmaxf(pmax, s[r]);
    pmax = fmaxf(pmax, __shfl_xor(pmax, 32));
    float mnew = fmaxf(m, pmax);
    float alpha = __expf(m - mnew);
    float pf[16];
    float rs = 0.f;
#pragma unroll
    for (int r = 0; r < 16; ++r) { pf[r] = __expf(s[r] - mnew); rs += pf[r]; }
    rs += __shfl_xor(rs, 32);
    ln = ln * alpha + rs;
    m = mnew;
#pragma unroll
    for (int db = 0; db < 4; ++db)
#pragma unroll
      for (int r = 0; r < 16; ++r) o[db][r] *= alpha;
    // ---- P -> bf16 B-fragments via cross-half exchange ----
    unsigned pw[8], qw[8];
#pragma unroll
    for (int ii = 0; ii < 8; ++ii) pw[ii] = pk2(pf[2 * ii], pf[2 * ii + 1]);
#pragma unroll
    for (int ii = 0; ii < 8; ++ii) qw[ii] = (unsigned)__shfl_xor((int)pw[ii], 32);
#pragma unroll
    for (int ks = 0; ks < 2; ++ks) {
      union { unsigned u[4]; bf16x8 v; } bp;
      bp.u[0] = h ? qw[4 * ks + 2] : pw[4 * ks + 0];
      bp.u[1] = h ? qw[4 * ks + 3] : pw[4 * ks + 1];
      bp.u[2] = h ? pw[4 * ks + 2] : qw[4 * ks + 0];
      bp.u[3] = h ? pw[4 * ks + 3] : qw[4 * ks + 1];
#pragma unroll
      for (int db = 0; db < 4; ++db)
        o[db] = MFMA32(vc[db * 2 + ks], bp.v, o[db]);
    }
    // rotate K double-buffer
#pragma unroll
    for (int kk = 0; kk < 8; ++kk) kc[kk] = kn[kk];
  }
  // ---- normalize + coalesced O^T store ----
  float inv = 1.f / ln;
  const size_t otb = (size_t)bh * 128 * NN + q0 + lq;
#pragma unroll
  for (int db = 0; db < 4; ++db)
#pragma unroll
    for (int r = 0; r < 16; ++r) {
      int dl = (r & 3) + 8 * (r >> 2) + 4 * h;
      OT[otb + (size_t)(db * 32 + dl) * NN] = o[db][r] * inv;
    }
}

// ============================================================
// Host-side orchestration
// ============================================================
extern "C" void kernel_launch(void* const* d_in, const int* in_sizes, int n_in,
                              void* d_out, int out_size, void* d_ws, size_t ws_size,
                              hipStream_t stream) {
  const float* xr   = (const float*)d_in[0];
  const float* xi   = (const float*)d_in[1];
  const float* Wqr  = (const float*)d_in[2];
  const float* Wqi  = (const float*)d_in[3];
  const float* bqr  = (const float*)d_in[4];
  const float* bqi  = (const float*)d_in[5];
  const float* Wkr  = (const float*)d_in[6];
  const float* Wki  = (const float*)d_in[7];
  const float* bkr  = (const float*)d_in[8];
  const float* bki  = (const float*)d_in[9];
  const float* Wvr  = (const float*)d_in[10];
  const float* Wvi  = (const float*)d_in[11];
  const float* bvr  = (const float*)d_in[12];
  const float* bvi  = (const float*)d_in[13];
  const float* Wor  = (const float*)d_in[14];
  const float* Woi  = (const float*)d_in[15];
  const float* bor  = (const float*)d_in[16];
  const float* boi  = (const float*)d_in[17];
  const float* gq   = (const float*)d_in[18];
  const float* beq  = (const float*)d_in[19];
  const float* gk   = (const float*)d_in[20];
  const float* bek  = (const float*)d_in[21];
  const float* gv   = (const float*)d_in[22];
  const float* bev  = (const float*)d_in[23];

  char* wp = (char*)d_ws;
  bf16_t* Axaug = (bf16_t*)wp;  wp += (size_t)4096 * 2048 * 2;
  bf16_t* Wcat  = (bf16_t*)wp;  wp += (size_t)2048 * 2048 * 2;
  float*  bcat  = (float*)wp;   wp += (size_t)2048 * 4;
  float2* lnst  = (float2*)wp;  wp += (size_t)4096 * 8;
  float*  Ar    = (float*)wp;   wp += (size_t)4096 * 1024 * 4;
  float*  Ai    = (float*)wp;   wp += (size_t)4096 * 1024 * 4;
  bf16_t* Qf    = (bf16_t*)wp;  wp += (size_t)64 * 1024 * 128 * 2;
  bf16_t* Kf    = (bf16_t*)wp;  wp += (size_t)64 * 1024 * 128 * 2;
  bf16_t* VfT   = (bf16_t*)wp;  wp += (size_t)64 * 1024 * 128 * 2;
  bf16_t* Yaug  = Qf;
  float*  OT    = Ar;   // attn output O^T [BH,128,N] fp32 (spans Ar+Ai)

  const dim3 gGemm(16, 32);
  const int gPackX = (4096 * 2048 / 8) / 256;
  const int gPackW = (2048 * 2048 / 8) / 256;
  const int gFft = 64 * 16;
  const int gAtt = 64 * 8;

  pack_x<<<gPackX, 256, 0, stream>>>(xr, xi, Axaug);

  // ---- Q (FFT output scale folds in the 1/8 attention scale; LN fused) ----
  pack_w<<<gPackW, 256, 0, stream>>>(Wqr, Wqi, bqr, bqi, Wcat, bcat);
  gemm_bf16<<<gGemm, 256, 0, stream>>>(Axaug, Wcat, bcat, Ar, Ai, 1024);
  ln_stats<<<BN, 256, 0, stream>>>(Ar, Ai, lnst);
  fft_kernel<<<gFft, 512, 0, stream>>>(Ar, Ai, Qf, Qf + 64,
      NN * DIMM, DHH, DIMM, 1,
      16 * NN * 128, NN * 128, 128, 1, -1.0f, 0.03125f * 0.125f, 0,
      lnst, gq, beq);
  // ---- K ----
  pack_w<<<gPackW, 256, 0, stream>>>(Wkr, Wki, bkr, bki, Wcat, bcat);
  gemm_bf16<<<gGemm, 256, 0, stream>>>(Axaug, Wcat, bcat, Ar, Ai, 1024);
  ln_stats<<<BN, 256, 0, stream>>>(Ar, Ai, lnst);
  fft_kernel<<<gFft, 512, 0, stream>>>(Ar, Ai, Kf, Kf + 64,
      NN * DIMM, DHH, DIMM, 1,
      16 * NN * 128, NN * 128, 128, 1, -1.0f, 0.03125f, 0,
      lnst, gk, bek);
  // ---- V (kv-tile-blocked transposed output [bh][n/32][128][32]) ----
  pack_w<<<gPackW, 256, 0, stream>>>(Wvr, Wvi, bvr, bvi, Wcat, bcat);
  gemm_bf16<<<gGemm, 256, 0, stream>>>(Axaug, Wcat, bcat, Ar, Ai, 1024);
  ln_stats<<<BN, 256, 0, stream>>>(Ar, Ai, lnst);
  fft_kernel<<<gFft, 512, 0, stream>>>(Ar, Ai, VfT, VfT + 2048,
      NN * DIMM, DHH, DIMM, 1,
      16 * 131072, 131072, 0, 0, -1.0f, 0.03125f, 1,
      lnst, gv, bev);
  // ---- flash attention -> OT [BH,128,N] fp32 ----
  fattn<<<gAtt, 256, 0, stream>>>(Qf, Kf, VfT, OT);
  // ---- inverse FFT: OT (d-major) -> Yaug bf16 [4096][2048] ----
  fft_kernel<<<gFft, 512, 0, stream>>>(OT, OT + (size_t)64 * NN, Yaug, Yaug + 1024,
      16 * 128 * NN, 128 * NN, 1, NN,
      NN * 2048, 64, 2048, 1, +1.0f, 0.03125f, 0,
      nullptr, nullptr, nullptr);
  // ---- output projection straight into d_out ----
  float* yout = (float*)d_out;
  pack_w<<<gPackW, 256, 0, stream>>>(Wor, Woi, bor, boi, Wcat, bcat);
  gemm_bf16<<<gGemm, 256, 0, stream>>>(Yaug, Wcat, bcat, yout, yout + 1024, 2048);
}

// Round 9
// 593.882 us; speedup vs baseline: 1.0954x; 1.0306x over previous
//
#include <hip/hip_runtime.h>
#include <math.h>

#define BB 4
#define NN 1024
#define DIMM 1024
#define HHH 16
#define DHH 64
#define BN 4096            // B*N rows
#define EPS_LN 1e-6f

typedef __bf16 bf16_t;
typedef __bf16 bf16x8 __attribute__((ext_vector_type(8)));
typedef float f32x4 __attribute__((ext_vector_type(4)));
typedef float f32x16 __attribute__((ext_vector_type(16)));
#define MFMA16(a, b, c) __builtin_amdgcn_mfma_f32_16x16x32_bf16(a, b, c, 0, 0, 0)
#define MFMA32(a, b, c) __builtin_amdgcn_mfma_f32_32x32x16_bf16(a, b, c, 0, 0, 0)
#define AS1 __attribute__((address_space(1)))
#define AS3 __attribute__((address_space(3)))

__device__ inline unsigned pk2(float a, float b) {
  union { bf16_t h[2]; unsigned u; } c;
  c.h[0] = (bf16_t)a; c.h[1] = (bf16_t)b;
  return c.u;
}

// issue-order-pinned 16B global load (compiler cannot sink it to the use)
__device__ __forceinline__ uint4 gload16(const bf16_t* p) {
  uint4 r;
  asm volatile("global_load_dwordx4 %0, %1, off" : "=v"(r) : "v"(p));
  return r;
}
union U16 { uint4 u; bf16x8 v; };

// ============================================================
// pack_x: Axaug[4096][2048] = bf16([xr | xi])
// ============================================================
__global__ __launch_bounds__(256) void pack_x(
    const float* __restrict__ xr, const float* __restrict__ xi,
    bf16_t* __restrict__ out)
{
  int t = blockIdx.x * 256 + threadIdx.x;
  size_t e = (size_t)t * 8;
  int row = (int)(e >> 11), col = (int)(e & 2047);
  const float* src = (col < 1024) ? (xr + (size_t)row * 1024 + col)
                                  : (xi + (size_t)row * 1024 + col - 1024);
  float4 a = *(const float4*)src;
  float4 b = *(const float4*)(src + 4);
  bf16x8 o;
  o[0] = (bf16_t)a.x; o[1] = (bf16_t)a.y; o[2] = (bf16_t)a.z; o[3] = (bf16_t)a.w;
  o[4] = (bf16_t)b.x; o[5] = (bf16_t)b.y; o[6] = (bf16_t)b.z; o[7] = (bf16_t)b.w;
  *(bf16x8*)(out + e) = o;
}

// ============================================================
// pack_w: Wcat[2048][2048]: rows 0-1023 = [Wr | -Wi], rows 1024-2047 = [Wi | Wr]
// ============================================================
__global__ __launch_bounds__(256) void pack_w(
    const float* __restrict__ Wr, const float* __restrict__ Wi,
    const float* __restrict__ br, const float* __restrict__ bi,
    bf16_t* __restrict__ Wcat, float* __restrict__ bcat)
{
  int t = blockIdx.x * 256 + threadIdx.x;
  size_t e = (size_t)t * 8;
  int row = (int)(e >> 11), col = (int)(e & 2047);
  const float* src;
  float sgn = 1.f;
  if (row < 1024) {
    if (col < 1024) src = Wr + (size_t)row * 1024 + col;
    else          { src = Wi + (size_t)row * 1024 + col - 1024; sgn = -1.f; }
  } else {
    int r2 = row - 1024;
    if (col < 1024) src = Wi + (size_t)r2 * 1024 + col;
    else            src = Wr + (size_t)r2 * 1024 + col - 1024;
  }
  float4 a = *(const float4*)src;
  float4 b = *(const float4*)(src + 4);
  bf16x8 o;
  o[0] = (bf16_t)(sgn * a.x); o[1] = (bf16_t)(sgn * a.y);
  o[2] = (bf16_t)(sgn * a.z); o[3] = (bf16_t)(sgn * a.w);
  o[4] = (bf16_t)(sgn * b.x); o[5] = (bf16_t)(sgn * b.y);
  o[6] = (bf16_t)(sgn * b.z); o[7] = (bf16_t)(sgn * b.w);
  *(bf16x8*)(Wcat + e) = o;
  if (e < 2048) {
#pragma unroll
    for (int j = 0; j < 8; ++j) {
      int n = (int)e + j;
      bcat[n] = (n < 1024) ? br[n] : bi[n - 1024];
    }
  }
}

// ============================================================
// bf16 MFMA GEMM (NT), m97 structure (unchanged).
// ============================================================
__global__ __launch_bounds__(256) void gemm_bf16(
    const bf16_t* __restrict__ A, const bf16_t* __restrict__ Bt,
    const float* __restrict__ bias,
    float* __restrict__ Cr, float* __restrict__ Ci, int ldc)
{
  __shared__ bf16_t sA[128 * 64];
  __shared__ bf16_t sB[128 * 64];
  const int tid = threadIdx.x;
  const int w = tid >> 6, l = tid & 63;
  const int lo4 = l & 15, hi = l >> 4;
  const int wr = w >> 1, wc = w & 1;
  const int row0 = blockIdx.y * 128, col0 = blockIdx.x * 128;

  const int srow = (l >> 3);
  const int scol = (l & 7) * 8;
  const bf16_t* gA[4];
  const bf16_t* gB[4];
#pragma unroll
  for (int i = 0; i < 4; ++i) {
    int r = (w * 4 + i) * 8 + srow;
    gA[i] = A  + (size_t)(row0 + r) * 2048 + scol;
    gB[i] = Bt + (size_t)(col0 + r) * 2048 + scol;
  }

  f32x4 acc[4][4] = {};
  for (int k0 = 0; k0 < 2048; k0 += 64) {
    __syncthreads();
#pragma unroll
    for (int i = 0; i < 4; ++i) {
      __builtin_amdgcn_global_load_lds((const AS1 void*)(gA[i] + k0),
                                       (AS3 void*)&sA[(w * 4 + i) * 512], 16, 0, 0);
      __builtin_amdgcn_global_load_lds((const AS1 void*)(gB[i] + k0),
                                       (AS3 void*)&sB[(w * 4 + i) * 512], 16, 0, 0);
    }
    __syncthreads();
#pragma unroll
    for (int kk = 0; kk < 2; ++kk) {
      bf16x8 am[4], bn[4];
#pragma unroll
      for (int i = 0; i < 4; ++i)
        am[i] = *(const bf16x8*)&sA[(wr * 64 + i * 16 + lo4) * 64 + kk * 32 + hi * 8];
#pragma unroll
      for (int j = 0; j < 4; ++j)
        bn[j] = *(const bf16x8*)&sB[(wc * 64 + j * 16 + lo4) * 64 + kk * 32 + hi * 8];
#pragma unroll
      for (int i = 0; i < 4; ++i)
#pragma unroll
        for (int j = 0; j < 4; ++j)
          acc[i][j] = MFMA16(am[i], bn[j], acc[i][j]);
    }
  }
  const int colg0 = col0 + wc * 64;
  float* Cp = (colg0 < 1024) ? Cr : Ci;
  const int cb = colg0 & 1023;
#pragma unroll
  for (int i = 0; i < 4; ++i) {
#pragma unroll
    for (int j = 0; j < 4; ++j) {
      float bv = bias[colg0 + j * 16 + lo4];
#pragma unroll
      for (int r = 0; r < 4; ++r) {
        int rowg = row0 + wr * 64 + i * 16 + hi * 4 + r;
        Cp[(size_t)rowg * ldc + cb + j * 16 + lo4] = acc[i][j][r] + bv;
      }
    }
  }
}

// ============================================================
// LN row stats (unchanged)
// ============================================================
__global__ __launch_bounds__(256) void ln_stats(
    const float* __restrict__ re, const float* __restrict__ im,
    float2* __restrict__ st)
{
  __shared__ float red[8];
  const int row = blockIdx.x;
  const int tid = threadIdx.x;
  const float* pr = re + (size_t)row * DIMM;
  const float* pi = im + (size_t)row * DIMM;
  float s = 0.f, s2 = 0.f;
#pragma unroll
  for (int t = 0; t < 4; ++t) {
    int c = tid + t * 256;
    float vr = pr[c], vi = pi[c];
    float mg = sqrtf(vr * vr + vi * vi);
    s += mg; s2 += mg * mg;
  }
#pragma unroll
  for (int o = 32; o; o >>= 1) { s += __shfl_down(s, o); s2 += __shfl_down(s2, o); }
  if ((tid & 63) == 0) { red[tid >> 6] = s; red[4 + (tid >> 6)] = s2; }
  __syncthreads();
  if (tid == 0) {
    float S = red[0] + red[1] + red[2] + red[3];
    float S2 = red[4] + red[5] + red[6] + red[7];
    float mean = S * (1.f / DIMM);
    float var = S2 * (1.f / DIMM) - mean * mean;
    st[row] = make_float2(mean, rsqrtf(var + EPS_LN));
  }
}

// ============================================================
// 1024-pt radix-2 DIF FFT (unchanged from round 8)
// ============================================================
#define FD 4
__global__ __launch_bounds__(512) void fft_kernel(
    const float* __restrict__ inR, const float* __restrict__ inI,
    bf16_t* __restrict__ outR, bf16_t* __restrict__ outI,
    int in_sb, int in_sh, int in_sn, int in_sd,
    int out_sb, int out_sh, int out_sn, int out_sd,
    float sign, float oscale, int vblk,
    const float2* __restrict__ stats,
    const float* __restrict__ gamma, const float* __restrict__ beta)
{
  __shared__ float lr[FD][NN + 1], li[FD][NN + 1];
  __shared__ float2 tw[512];
  const int tid = threadIdx.x;
  const int dc = blockIdx.x & 15;
  const int bh = blockIdx.x >> 4;
  const int b = bh >> 4, h = bh & 15;
  const float* bR = inR + (size_t)b * in_sb + (size_t)h * in_sh;
  const float* bI = inI + (size_t)b * in_sb + (size_t)h * in_sh;
  {
    float ang = sign * 3.14159265358979323846f * (float)tid * (1.f / 512.f);
    float sn, cs;
    __sincosf(ang, &sn, &cs);
    tw[tid] = make_float2(cs, sn);
  }
#pragma unroll
  for (int it = 0; it < 8; ++it) {
    int flat = it * 512 + tid;
    int ds = flat & 3, n = flat >> 2;
    size_t ga = (size_t)(dc * FD + ds) * in_sd + (size_t)n * in_sn;
    float vr = bR[ga];
    float vi = bI[ga];
    if (stats) {
      float2 stv = stats[b * NN + n];
      int dim = h * DHH + dc * FD + ds;
      float mag = sqrtf(vr * vr + vi * vi);
      float nm = (mag - stv.x) * stv.y * gamma[dim] + beta[dim];
      if (mag > 0.f) { float sc = nm / mag; vr *= sc; vi *= sc; }
      else           { vr = nm; vi = 0.f; }
    }
    lr[ds][n] = vr;
    li[ds][n] = vi;
  }
  __syncthreads();
  const int dsub = tid & 3;
  const int jb = tid >> 2;
  for (int hs = 9; hs >= 0; --hs) {
    int half = 1 << hs;
#pragma unroll
    for (int it = 0; it < 4; ++it) {
      int j = jb + it * 128;
      int o = j & (half - 1);
      int i0 = ((j >> hs) << (hs + 1)) + o;
      int i1 = i0 + half;
      float ar = lr[dsub][i0], ai = li[dsub][i0];
      float br_ = lr[dsub][i1], bi_ = li[dsub][i1];
      lr[dsub][i0] = ar + br_;
      li[dsub][i0] = ai + bi_;
      float sr = ar - br_, si = ai - bi_;
      float2 t = tw[o << (9 - hs)];
      lr[dsub][i1] = sr * t.x - si * t.y;
      li[dsub][i1] = sr * t.y + si * t.x;
    }
    __syncthreads();
  }
  bf16_t* oR = outR + (size_t)b * out_sb + (size_t)h * out_sh;
  bf16_t* oI = outI + (size_t)b * out_sb + (size_t)h * out_sh;
#pragma unroll
  for (int it = 0; it < 8; ++it) {
    int flat = it * 512 + tid;
    int ds = flat & 3, n = flat >> 2;
    int rev = __brev((unsigned)n) >> 22;
    size_t ga;
    if (vblk) {
      int dch = dc * FD + ds;
      ga = (size_t)(n >> 5) * 4096 + (size_t)dch * 32 + (n & 31);
    } else {
      ga = (size_t)(dc * FD + ds) * out_sd + (size_t)n * out_sn;
    }
    oR[ga] = (bf16_t)(lr[ds][rev] * oscale);
    oI[ga] = (bf16_t)(li[ds][rev] * oscale);
  }
}

// ============================================================
// Flash attention v5: swapped-operand 32x32 MFMA, no LDS,
// XCD-locality swizzle, kv-tile-blocked V, and a HAND-PINNED load
// pipeline: inline-asm global_load_dwordx4 (issue-order volatile) +
// counted s_waitcnt vmcnt(N) + sched_barrier (rule #18). Per tile:
// issue V[t]+K[t+1] at top; S-MFMA from in-register K[t]; softmax;
// vmcnt(8) -> PV; vmcnt(0) -> rotate K. Defer-max (THR=8) and
// 4-shuffle P-exchange trim the VALU tail.
// ============================================================
__global__ __launch_bounds__(256, 2) void fattn(
    const bf16_t* __restrict__ Qf, const bf16_t* __restrict__ Kf,
    const bf16_t* __restrict__ VfT, float* __restrict__ OT)
{
  const int tid = threadIdx.x;
  const int w = tid >> 6, l = tid & 63;
  const int lq = l & 31;            // q-column within wave tile
  const int h = l >> 5;             // lane half
  const int i = blockIdx.x;
  const int j = i >> 3;
  const int bh = (i & 7) * 8 + (j >> 3);
  const int q0 = (j & 7) * 128 + w * 32;

  // Q fragments (B-operand)
  bf16x8 bq[8];
  const bf16_t* qp = Qf + ((size_t)bh * NN + q0 + lq) * 128 + h * 8;
#pragma unroll
  for (int kk = 0; kk < 8; ++kk) bq[kk] = *(const bf16x8*)(qp + kk * 16);

  f32x16 o[4] = {};
  float m = -3e38f, ln = 0.f;

  const bf16_t* kb = Kf + (size_t)bh * NN * 128 + h * 8;
  const bf16_t* vb = VfT + (size_t)bh * 131072 + (size_t)lq * 32 + h * 8;

  // prologue: K[0] via pinned loads
  U16 kc[8], kn[8], vc[8];
  {
    const bf16_t* kp0 = kb + (size_t)lq * 128;
#pragma unroll
    for (int kk = 0; kk < 8; ++kk) kc[kk].u = gload16(kp0 + kk * 16);
  }
  asm volatile("s_waitcnt vmcnt(0)");
  __builtin_amdgcn_sched_barrier(0);

  for (int kv0 = 0; kv0 < NN; kv0 += 32) {
    // ---- issue V[t] (8) then K[t+1] (8); pin them at the top ----
    const bf16_t* vt = vb + (size_t)(kv0 >> 5) * 4096;
#pragma unroll
    for (int db = 0; db < 4; ++db)
#pragma unroll
      for (int ks = 0; ks < 2; ++ks)
        vc[db * 2 + ks].u = gload16(vt + db * 1024 + ks * 16);
    {
      int kvn = (kv0 + 32) & (NN - 1);
      const bf16_t* kpn = kb + (size_t)(kvn + lq) * 128;
#pragma unroll
      for (int kk = 0; kk < 8; ++kk) kn[kk].u = gload16(kpn + kk * 16);
    }
    __builtin_amdgcn_sched_barrier(0);

    // ---- S^T[k][q] from in-register K[t] (no memory wait) ----
    f32x16 s = {};
#pragma unroll
    for (int kk = 0; kk < 8; ++kk) s = MFMA32(kc[kk].v, bq[kk], s);

    // ---- online softmax with defer-max (THR=8) ----
    float pmax = s[0];
#pragma unroll
    for (int r = 1; r < 16; ++r) pmax = fmaxf(pmax, s[r]);
    pmax = fmaxf(pmax, __shfl_xor(pmax, 32));
    if (!__all(pmax - m <= 8.f)) {
      float mnew = fmaxf(m, pmax);
      float alpha = __expf(m - mnew);
      m = mnew;
      ln *= alpha;
#pragma unroll
      for (int db = 0; db < 4; ++db)
#pragma unroll
        for (int r = 0; r < 16; ++r) o[db][r] *= alpha;
    }
    float pf[16];
    float rs = 0.f;
#pragma unroll
    for (int r = 0; r < 16; ++r) { pf[r] = __expf(s[r] - m); rs += pf[r]; }
    rs += __shfl_xor(rs, 32);
    ln += rs;

    // ---- P -> bf16; 4 select-shuffles (h=0 sends pw[2,3,6,7], gets pw[0,1,4,5]) ----
    unsigned pw[8];
#pragma unroll
    for (int ii = 0; ii < 8; ++ii) pw[ii] = pk2(pf[2 * ii], pf[2 * ii + 1]);
    unsigned r0 = (unsigned)__shfl_xor((int)(h ? pw[0] : pw[2]), 32);
    unsigned r1 = (unsigned)__shfl_xor((int)(h ? pw[1] : pw[3]), 32);
    unsigned r2 = (unsigned)__shfl_xor((int)(h ? pw[4] : pw[6]), 32);
    unsigned r3 = (unsigned)__shfl_xor((int)(h ? pw[5] : pw[7]), 32);
    U16 bp0, bp1;
    bp0.u.x = h ? r0 : pw[0];  bp0.u.y = h ? r1 : pw[1];
    bp0.u.z = h ? pw[2] : r0;  bp0.u.w = h ? pw[3] : r1;
    bp1.u.x = h ? r2 : pw[4];  bp1.u.y = h ? r3 : pw[5];
    bp1.u.z = h ? pw[6] : r2;  bp1.u.w = h ? pw[7] : r3;

    // ---- wait V only (K[t+1] stays in flight), then PV ----
    asm volatile("s_waitcnt vmcnt(8)");
    __builtin_amdgcn_sched_barrier(0);
#pragma unroll
    for (int db = 0; db < 4; ++db) {
      o[db] = MFMA32(vc[db * 2 + 0].v, bp0.v, o[db]);
      o[db] = MFMA32(vc[db * 2 + 1].v, bp1.v, o[db]);
    }

    // ---- drain K[t+1], rotate ----
    asm volatile("s_waitcnt vmcnt(0)");
    __builtin_amdgcn_sched_barrier(0);
#pragma unroll
    for (int kk = 0; kk < 8; ++kk) kc[kk] = kn[kk];
  }

  // ---- normalize + coalesced O^T store ----
  float inv = 1.f / ln;
  const size_t otb = (size_t)bh * 128 * NN + q0 + lq;
#pragma unroll
  for (int db = 0; db < 4; ++db)
#pragma unroll
    for (int r = 0; r < 16; ++r) {
      int dl = (r & 3) + 8 * (r >> 2) + 4 * h;
      OT[otb + (size_t)(db * 32 + dl) * NN] = o[db][r] * inv;
    }
}

// ============================================================
// Host-side orchestration
// ============================================================
extern "C" void kernel_launch(void* const* d_in, const int* in_sizes, int n_in,
                              void* d_out, int out_size, void* d_ws, size_t ws_size,
                              hipStream_t stream) {
  const float* xr   = (const float*)d_in[0];
  const float* xi   = (const float*)d_in[1];
  const float* Wqr  = (const float*)d_in[2];
  const float* Wqi  = (const float*)d_in[3];
  const float* bqr  = (const float*)d_in[4];
  const float* bqi  = (const float*)d_in[5];
  const float* Wkr  = (const float*)d_in[6];
  const float* Wki  = (const float*)d_in[7];
  const float* bkr  = (const float*)d_in[8];
  const float* bki  = (const float*)d_in[9];
  const float* Wvr  = (const float*)d_in[10];
  const float* Wvi  = (const float*)d_in[11];
  const float* bvr  = (const float*)d_in[12];
  const float* bvi  = (const float*)d_in[13];
  const float* Wor  = (const float*)d_in[14];
  const float* Woi  = (const float*)d_in[15];
  const float* bor  = (const float*)d_in[16];
  const float* boi  = (const float*)d_in[17];
  const float* gq   = (const float*)d_in[18];
  const float* beq  = (const float*)d_in[19];
  const float* gk   = (const float*)d_in[20];
  const float* bek  = (const float*)d_in[21];
  const float* gv   = (const float*)d_in[22];
  const float* bev  = (const float*)d_in[23];

  char* wp = (char*)d_ws;
  bf16_t* Axaug = (bf16_t*)wp;  wp += (size_t)4096 * 2048 * 2;
  bf16_t* Wcat  = (bf16_t*)wp;  wp += (size_t)2048 * 2048 * 2;
  float*  bcat  = (float*)wp;   wp += (size_t)2048 * 4;
  float2* lnst  = (float2*)wp;  wp += (size_t)4096 * 8;
  float*  Ar    = (float*)wp;   wp += (size_t)4096 * 1024 * 4;
  float*  Ai    = (float*)wp;   wp += (size_t)4096 * 1024 * 4;
  bf16_t* Qf    = (bf16_t*)wp;  wp += (size_t)64 * 1024 * 128 * 2;
  bf16_t* Kf    = (bf16_t*)wp;  wp += (size_t)64 * 1024 * 128 * 2;
  bf16_t* VfT   = (bf16_t*)wp;  wp += (size_t)64 * 1024 * 128 * 2;
  bf16_t* Yaug  = Qf;
  float*  OT    = Ar;   // attn output O^T [BH,128,N] fp32 (spans Ar+Ai)

  const dim3 gGemm(16, 32);
  const int gPackX = (4096 * 2048 / 8) / 256;
  const int gPackW = (2048 * 2048 / 8) / 256;
  const int gFft = 64 * 16;
  const int gAtt = 64 * 8;

  pack_x<<<gPackX, 256, 0, stream>>>(xr, xi, Axaug);

  // ---- Q (FFT output scale folds in the 1/8 attention scale; LN fused) ----
  pack_w<<<gPackW, 256, 0, stream>>>(Wqr, Wqi, bqr, bqi, Wcat, bcat);
  gemm_bf16<<<gGemm, 256, 0, stream>>>(Axaug, Wcat, bcat, Ar, Ai, 1024);
  ln_stats<<<BN, 256, 0, stream>>>(Ar, Ai, lnst);
  fft_kernel<<<gFft, 512, 0, stream>>>(Ar, Ai, Qf, Qf + 64,
      NN * DIMM, DHH, DIMM, 1,
      16 * NN * 128, NN * 128, 128, 1, -1.0f, 0.03125f * 0.125f, 0,
      lnst, gq, beq);
  // ---- K ----
  pack_w<<<gPackW, 256, 0, stream>>>(Wkr, Wki, bkr, bki, Wcat, bcat);
  gemm_bf16<<<gGemm, 256, 0, stream>>>(Axaug, Wcat, bcat, Ar, Ai, 1024);
  ln_stats<<<BN, 256, 0, stream>>>(Ar, Ai, lnst);
  fft_kernel<<<gFft, 512, 0, stream>>>(Ar, Ai, Kf, Kf + 64,
      NN * DIMM, DHH, DIMM, 1,
      16 * NN * 128, NN * 128, 128, 1, -1.0f, 0.03125f, 0,
      lnst, gk, bek);
  // ---- V (kv-tile-blocked transposed output [bh][n/32][128][32]) ----
  pack_w<<<gPackW, 256, 0, stream>>>(Wvr, Wvi, bvr, bvi, Wcat, bcat);
  gemm_bf16<<<gGemm, 256, 0, stream>>>(Axaug, Wcat, bcat, Ar, Ai, 1024);
  ln_stats<<<BN, 256, 0, stream>>>(Ar, Ai, lnst);
  fft_kernel<<<gFft, 512, 0, stream>>>(Ar, Ai, VfT, VfT + 2048,
      NN * DIMM, DHH, DIMM, 1,
      16 * 131072, 131072, 0, 0, -1.0f, 0.03125f, 1,
      lnst, gv, bev);
  // ---- flash attention -> OT [BH,128,N] fp32 ----
  fattn<<<gAtt, 256, 0, stream>>>(Qf, Kf, VfT, OT);
  // ---- inverse FFT: OT (d-major) -> Yaug bf16 [4096][2048] ----
  fft_kernel<<<gFft, 512, 0, stream>>>(OT, OT + (size_t)64 * NN, Yaug, Yaug + 1024,
      16 * 128 * NN, 128 * NN, 1, NN,
      NN * 2048, 64, 2048, 1, +1.0f, 0.03125f, 0,
      nullptr, nullptr, nullptr);
  // ---- output projection straight into d_out ----
  float* yout = (float*)d_out;
  pack_w<<<gPackW, 256, 0, stream>>>(Wor, Woi, bor, boi, Wcat, bcat);
  gemm_bf16<<<gGemm, 256, 0, stream>>>(Yaug, Wcat, bcat, yout, yout + 1024, 2048);
}

// Round 10
// 549.326 us; speedup vs baseline: 1.1842x; 1.0811x over previous
//
#include <hip/hip_runtime.h>
#include <math.h>

#define BB 4
#define NN 1024
#define DIMM 1024
#define HHH 16
#define DHH 64
#define BN 4096            // B*N rows
#define EPS_LN 1e-6f

typedef __bf16 bf16_t;
typedef __bf16 bf16x8 __attribute__((ext_vector_type(8)));
typedef float f32x4 __attribute__((ext_vector_type(4)));
typedef float f32x16 __attribute__((ext_vector_type(16)));
#define MFMA16(a, b, c) __builtin_amdgcn_mfma_f32_16x16x32_bf16(a, b, c, 0, 0, 0)
#define MFMA32(a, b, c) __builtin_amdgcn_mfma_f32_32x32x16_bf16(a, b, c, 0, 0, 0)
#define AS1 __attribute__((address_space(1)))
#define AS3 __attribute__((address_space(3)))

__device__ inline unsigned pk2(float a, float b) {
  union { bf16_t h[2]; unsigned u; } c;
  c.h[0] = (bf16_t)a; c.h[1] = (bf16_t)b;
  return c.u;
}
union U16 { uint4 u; bf16x8 v; };

// ============================================================
// pack_x: Axaug[4096][2048] = bf16([xr | xi])
// ============================================================
__global__ __launch_bounds__(256) void pack_x(
    const float* __restrict__ xr, const float* __restrict__ xi,
    bf16_t* __restrict__ out)
{
  int t = blockIdx.x * 256 + threadIdx.x;
  size_t e = (size_t)t * 8;
  int row = (int)(e >> 11), col = (int)(e & 2047);
  const float* src = (col < 1024) ? (xr + (size_t)row * 1024 + col)
                                  : (xi + (size_t)row * 1024 + col - 1024);
  float4 a = *(const float4*)src;
  float4 b = *(const float4*)(src + 4);
  bf16x8 o;
  o[0] = (bf16_t)a.x; o[1] = (bf16_t)a.y; o[2] = (bf16_t)a.z; o[3] = (bf16_t)a.w;
  o[4] = (bf16_t)b.x; o[5] = (bf16_t)b.y; o[6] = (bf16_t)b.z; o[7] = (bf16_t)b.w;
  *(bf16x8*)(out + e) = o;
}

// ============================================================
// pack_w: Wcat[2048][2048]: rows 0-1023 = [Wr | -Wi], rows 1024-2047 = [Wi | Wr]
// ============================================================
__global__ __launch_bounds__(256) void pack_w(
    const float* __restrict__ Wr, const float* __restrict__ Wi,
    const float* __restrict__ br, const float* __restrict__ bi,
    bf16_t* __restrict__ Wcat, float* __restrict__ bcat)
{
  int t = blockIdx.x * 256 + threadIdx.x;
  size_t e = (size_t)t * 8;
  int row = (int)(e >> 11), col = (int)(e & 2047);
  const float* src;
  float sgn = 1.f;
  if (row < 1024) {
    if (col < 1024) src = Wr + (size_t)row * 1024 + col;
    else          { src = Wi + (size_t)row * 1024 + col - 1024; sgn = -1.f; }
  } else {
    int r2 = row - 1024;
    if (col < 1024) src = Wi + (size_t)r2 * 1024 + col;
    else            src = Wr + (size_t)r2 * 1024 + col - 1024;
  }
  float4 a = *(const float4*)src;
  float4 b = *(const float4*)(src + 4);
  bf16x8 o;
  o[0] = (bf16_t)(sgn * a.x); o[1] = (bf16_t)(sgn * a.y);
  o[2] = (bf16_t)(sgn * a.z); o[3] = (bf16_t)(sgn * a.w);
  o[4] = (bf16_t)(sgn * b.x); o[5] = (bf16_t)(sgn * b.y);
  o[6] = (bf16_t)(sgn * b.z); o[7] = (bf16_t)(sgn * b.w);
  *(bf16x8*)(Wcat + e) = o;
  if (e < 2048) {
#pragma unroll
    for (int j = 0; j < 8; ++j) {
      int n = (int)e + j;
      bcat[n] = (n < 1024) ? br[n] : bi[n - 1024];
    }
  }
}

// ============================================================
// bf16 MFMA GEMM (NT), m97 structure (unchanged).
// ============================================================
__global__ __launch_bounds__(256) void gemm_bf16(
    const bf16_t* __restrict__ A, const bf16_t* __restrict__ Bt,
    const float* __restrict__ bias,
    float* __restrict__ Cr, float* __restrict__ Ci, int ldc)
{
  __shared__ bf16_t sA[128 * 64];
  __shared__ bf16_t sB[128 * 64];
  const int tid = threadIdx.x;
  const int w = tid >> 6, l = tid & 63;
  const int lo4 = l & 15, hi = l >> 4;
  const int wr = w >> 1, wc = w & 1;
  const int row0 = blockIdx.y * 128, col0 = blockIdx.x * 128;

  const int srow = (l >> 3);
  const int scol = (l & 7) * 8;
  const bf16_t* gA[4];
  const bf16_t* gB[4];
#pragma unroll
  for (int i = 0; i < 4; ++i) {
    int r = (w * 4 + i) * 8 + srow;
    gA[i] = A  + (size_t)(row0 + r) * 2048 + scol;
    gB[i] = Bt + (size_t)(col0 + r) * 2048 + scol;
  }

  f32x4 acc[4][4] = {};
  for (int k0 = 0; k0 < 2048; k0 += 64) {
    __syncthreads();
#pragma unroll
    for (int i = 0; i < 4; ++i) {
      __builtin_amdgcn_global_load_lds((const AS1 void*)(gA[i] + k0),
                                       (AS3 void*)&sA[(w * 4 + i) * 512], 16, 0, 0);
      __builtin_amdgcn_global_load_lds((const AS1 void*)(gB[i] + k0),
                                       (AS3 void*)&sB[(w * 4 + i) * 512], 16, 0, 0);
    }
    __syncthreads();
#pragma unroll
    for (int kk = 0; kk < 2; ++kk) {
      bf16x8 am[4], bn[4];
#pragma unroll
      for (int i = 0; i < 4; ++i)
        am[i] = *(const bf16x8*)&sA[(wr * 64 + i * 16 + lo4) * 64 + kk * 32 + hi * 8];
#pragma unroll
      for (int j = 0; j < 4; ++j)
        bn[j] = *(const bf16x8*)&sB[(wc * 64 + j * 16 + lo4) * 64 + kk * 32 + hi * 8];
#pragma unroll
      for (int i = 0; i < 4; ++i)
#pragma unroll
        for (int j = 0; j < 4; ++j)
          acc[i][j] = MFMA16(am[i], bn[j], acc[i][j]);
    }
  }
  const int colg0 = col0 + wc * 64;
  float* Cp = (colg0 < 1024) ? Cr : Ci;
  const int cb = colg0 & 1023;
#pragma unroll
  for (int i = 0; i < 4; ++i) {
#pragma unroll
    for (int j = 0; j < 4; ++j) {
      float bv = bias[colg0 + j * 16 + lo4];
#pragma unroll
      for (int r = 0; r < 4; ++r) {
        int rowg = row0 + wr * 64 + i * 16 + hi * 4 + r;
        Cp[(size_t)rowg * ldc + cb + j * 16 + lo4] = acc[i][j][r] + bv;
      }
    }
  }
}

// ============================================================
// LN row stats (unchanged)
// ============================================================
__global__ __launch_bounds__(256) void ln_stats(
    const float* __restrict__ re, const float* __restrict__ im,
    float2* __restrict__ st)
{
  __shared__ float red[8];
  const int row = blockIdx.x;
  const int tid = threadIdx.x;
  const float* pr = re + (size_t)row * DIMM;
  const float* pi = im + (size_t)row * DIMM;
  float s = 0.f, s2 = 0.f;
#pragma unroll
  for (int t = 0; t < 4; ++t) {
    int c = tid + t * 256;
    float vr = pr[c], vi = pi[c];
    float mg = sqrtf(vr * vr + vi * vi);
    s += mg; s2 += mg * mg;
  }
#pragma unroll
  for (int o = 32; o; o >>= 1) { s += __shfl_down(s, o); s2 += __shfl_down(s2, o); }
  if ((tid & 63) == 0) { red[tid >> 6] = s; red[4 + (tid >> 6)] = s2; }
  __syncthreads();
  if (tid == 0) {
    float S = red[0] + red[1] + red[2] + red[3];
    float S2 = red[4] + red[5] + red[6] + red[7];
    float mean = S * (1.f / DIMM);
    float var = S2 * (1.f / DIMM) - mean * mean;
    st[row] = make_float2(mean, rsqrtf(var + EPS_LN));
  }
}

// ============================================================
// 1024-pt radix-2 DIF FFT, LDS twiddle table; fp32 in, bf16 out.
// omode 0: linear strided. omode 1: V kv-tile-blocked + XOR swizzle
//   ga = (n>>5)*4096 + d*32 + ((n&31) ^ (((d>>1)&3)<<3))  [imag +2048]
// omode 2: K row-major + XOR swizzle  ga = n*128 + (d ^ ((n&7)<<3))
//   [imag +64; bit6 untouched by XOR so the offset commutes]
// ============================================================
#define FD 4
__global__ __launch_bounds__(512) void fft_kernel(
    const float* __restrict__ inR, const float* __restrict__ inI,
    bf16_t* __restrict__ outR, bf16_t* __restrict__ outI,
    int in_sb, int in_sh, int in_sn, int in_sd,
    int out_sb, int out_sh, int out_sn, int out_sd,
    float sign, float oscale, int omode,
    const float2* __restrict__ stats,
    const float* __restrict__ gamma, const float* __restrict__ beta)
{
  __shared__ float lr[FD][NN + 1], li[FD][NN + 1];
  __shared__ float2 tw[512];
  const int tid = threadIdx.x;
  const int dc = blockIdx.x & 15;
  const int bh = blockIdx.x >> 4;
  const int b = bh >> 4, h = bh & 15;
  const float* bR = inR + (size_t)b * in_sb + (size_t)h * in_sh;
  const float* bI = inI + (size_t)b * in_sb + (size_t)h * in_sh;
  {
    float ang = sign * 3.14159265358979323846f * (float)tid * (1.f / 512.f);
    float sn, cs;
    __sincosf(ang, &sn, &cs);
    tw[tid] = make_float2(cs, sn);
  }
#pragma unroll
  for (int it = 0; it < 8; ++it) {
    int flat = it * 512 + tid;
    int ds = flat & 3, n = flat >> 2;
    size_t ga = (size_t)(dc * FD + ds) * in_sd + (size_t)n * in_sn;
    float vr = bR[ga];
    float vi = bI[ga];
    if (stats) {
      float2 stv = stats[b * NN + n];
      int dim = h * DHH + dc * FD + ds;
      float mag = sqrtf(vr * vr + vi * vi);
      float nm = (mag - stv.x) * stv.y * gamma[dim] + beta[dim];
      if (mag > 0.f) { float sc = nm / mag; vr *= sc; vi *= sc; }
      else           { vr = nm; vi = 0.f; }
    }
    lr[ds][n] = vr;
    li[ds][n] = vi;
  }
  __syncthreads();
  const int dsub = tid & 3;
  const int jb = tid >> 2;
  for (int hs = 9; hs >= 0; --hs) {
    int half = 1 << hs;
#pragma unroll
    for (int it = 0; it < 4; ++it) {
      int j = jb + it * 128;
      int o = j & (half - 1);
      int i0 = ((j >> hs) << (hs + 1)) + o;
      int i1 = i0 + half;
      float ar = lr[dsub][i0], ai = li[dsub][i0];
      float br_ = lr[dsub][i1], bi_ = li[dsub][i1];
      lr[dsub][i0] = ar + br_;
      li[dsub][i0] = ai + bi_;
      float sr = ar - br_, si = ai - bi_;
      float2 t = tw[o << (9 - hs)];
      lr[dsub][i1] = sr * t.x - si * t.y;
      li[dsub][i1] = sr * t.y + si * t.x;
    }
    __syncthreads();
  }
  bf16_t* oR = outR + (size_t)b * out_sb + (size_t)h * out_sh;
  bf16_t* oI = outI + (size_t)b * out_sb + (size_t)h * out_sh;
#pragma unroll
  for (int it = 0; it < 8; ++it) {
    int flat = it * 512 + tid;
    int ds = flat & 3, n = flat >> 2;
    int rev = __brev((unsigned)n) >> 22;
    int dch = dc * FD + ds;
    size_t ga;
    if (omode == 1) {
      ga = (size_t)(n >> 5) * 4096 + (size_t)dch * 32
         + ((n & 31) ^ (((dch >> 1) & 3) << 3));
    } else if (omode == 2) {
      ga = (size_t)n * 128 + (dch ^ ((n & 7) << 3));
    } else {
      ga = (size_t)dch * out_sd + (size_t)n * out_sn;
    }
    oR[ga] = (bf16_t)(lr[ds][rev] * oscale);
    oI[ga] = (bf16_t)(li[ds][rev] * oscale);
  }
}

// ============================================================
// Flash attention v6: swapped-operand 32x32 MFMA + LDS-staged K/V.
// Mechanism: 8 waves/CU previously each fetched the same 16KB K/V tile
// (128KB/CU/tile of L1/L2 service — the measured 7.8k cy/tile). Now each
// BLOCK stages the tile once via async global_load_lds (double-buffered,
// 2-phase: stage t+1 -> compute t -> __syncthreads). Bank behavior:
// global layouts carry the XOR pre-swizzle (rule 21: gll writes linearly),
// giving uniform 8-lanes-per-4-bank ds_read_b128 (= conflict minimum).
// Softmax in-register, defer-max THR=8, 4-shuffle P exchange, O^T store.
// ============================================================
__global__ __launch_bounds__(256, 2) void fattn(
    const bf16_t* __restrict__ Qf, const bf16_t* __restrict__ Kfs,
    const bf16_t* __restrict__ Vfs, float* __restrict__ OT)
{
  __shared__ bf16_t K2[2][4096];   // [buf][32 kv x 128 d swizzled]
  __shared__ bf16_t V2[2][4096];   // [buf][128 d x 32 kv swizzled]
  const int tid = threadIdx.x;
  const int w = tid >> 6, l = tid & 63;
  const int lq = l & 31;            // q-column within wave tile
  const int h = l >> 5;             // lane half
  const int i = blockIdx.x;
  const int j = i >> 3;
  const int bh = (i & 7) * 8 + (j >> 3);   // XCD-locality swizzle
  const int q0 = (j & 7) * 128 + w * 32;

  // Q fragments (B-operand): frag kk holds k = kk*16 + h*8 + jj
  bf16x8 bq[8];
  const bf16_t* qp = Qf + ((size_t)bh * NN + q0 + lq) * 128 + h * 8;
#pragma unroll
  for (int kk = 0; kk < 8; ++kk) bq[kk] = *(const bf16x8*)(qp + kk * 16);

  f32x16 o[4] = {};
  float m = -3e38f, ln = 0.f;

  // staging pointers: per-lane global src (linear copy of 8KB tiles)
  const bf16_t* kg = Kfs + (size_t)bh * 131072 + w * 1024 + l * 8;
  const bf16_t* vg = Vfs + (size_t)bh * 131072 + w * 1024 + l * 8;
  const int kswz = (lq & 7) << 3;
  const int vswz = ((lq >> 1) & 3) << 3;

  // prologue: stage tile 0 into buf 0
#pragma unroll
  for (int ii = 0; ii < 2; ++ii) {
    __builtin_amdgcn_global_load_lds((const AS1 void*)(kg + ii * 512),
                                     (AS3 void*)&K2[0][w * 1024 + ii * 512], 16, 0, 0);
    __builtin_amdgcn_global_load_lds((const AS1 void*)(vg + ii * 512),
                                     (AS3 void*)&V2[0][w * 1024 + ii * 512], 16, 0, 0);
  }
  __syncthreads();

  int cur = 0;
  for (int t = 0; t < 32; ++t) {
    // ---- stage tile t+1 into the other buffer (async, fire-and-forget) ----
    if (t < 31) {
      const bf16_t* kt = kg + (size_t)(t + 1) * 4096;
      const bf16_t* vt = vg + (size_t)(t + 1) * 4096;
#pragma unroll
      for (int ii = 0; ii < 2; ++ii) {
        __builtin_amdgcn_global_load_lds((const AS1 void*)(kt + ii * 512),
                                         (AS3 void*)&K2[cur ^ 1][w * 1024 + ii * 512], 16, 0, 0);
        __builtin_amdgcn_global_load_lds((const AS1 void*)(vt + ii * 512),
                                         (AS3 void*)&V2[cur ^ 1][w * 1024 + ii * 512], 16, 0, 0);
      }
    }

    // ---- S^T[k][q]: K frags from LDS (swizzled), Q from registers ----
    f32x16 s = {};
#pragma unroll
    for (int kk = 0; kk < 8; ++kk) {
      bf16x8 ak = *(const bf16x8*)&K2[cur][lq * 128 + ((kk * 16 + h * 8) ^ kswz)];
      s = MFMA32(ak, bq[kk], s);
    }

    // ---- online softmax with defer-max (THR=8) ----
    float pmax = s[0];
#pragma unroll
    for (int r = 1; r < 16; ++r) pmax = fmaxf(pmax, s[r]);
    pmax = fmaxf(pmax, __shfl_xor(pmax, 32));
    if (!__all(pmax - m <= 8.f)) {
      float mnew = fmaxf(m, pmax);
      float alpha = __expf(m - mnew);
      m = mnew;
      ln *= alpha;
#pragma unroll
      for (int db = 0; db < 4; ++db)
#pragma unroll
        for (int r = 0; r < 16; ++r) o[db][r] *= alpha;
    }
    float pf[16];
    float rs = 0.f;
#pragma unroll
    for (int r = 0; r < 16; ++r) { pf[r] = __expf(s[r] - m); rs += pf[r]; }
    rs += __shfl_xor(rs, 32);
    ln += rs;

    // ---- P -> bf16; 4 select-shuffles across the lane halves ----
    unsigned pw[8];
#pragma unroll
    for (int ii = 0; ii < 8; ++ii) pw[ii] = pk2(pf[2 * ii], pf[2 * ii + 1]);
    unsigned r0 = (unsigned)__shfl_xor((int)(h ? pw[0] : pw[2]), 32);
    unsigned r1 = (unsigned)__shfl_xor((int)(h ? pw[1] : pw[3]), 32);
    unsigned r2 = (unsigned)__shfl_xor((int)(h ? pw[4] : pw[6]), 32);
    unsigned r3 = (unsigned)__shfl_xor((int)(h ? pw[5] : pw[7]), 32);
    U16 bp0, bp1;
    bp0.u.x = h ? r0 : pw[0];  bp0.u.y = h ? r1 : pw[1];
    bp0.u.z = h ? pw[2] : r0;  bp0.u.w = h ? pw[3] : r1;
    bp1.u.x = h ? r2 : pw[4];  bp1.u.y = h ? r3 : pw[5];
    bp1.u.z = h ? pw[6] : r2;  bp1.u.w = h ? pw[7] : r3;

    // ---- PV: V frags from LDS (swizzled) ----
#pragma unroll
    for (int db = 0; db < 4; ++db) {
      int r = db * 32 + lq;
      bf16x8 av0 = *(const bf16x8*)&V2[cur][r * 32 + ((h * 8) ^ vswz)];
      bf16x8 av1 = *(const bf16x8*)&V2[cur][r * 32 + ((16 + h * 8) ^ vswz)];
      o[db] = MFMA32(av0, bp0.v, o[db]);
      o[db] = MFMA32(av1, bp1.v, o[db]);
    }

    // ---- barrier: drains the stage (vmcnt 0) + all waves done reading ----
    __syncthreads();
    cur ^= 1;
  }

  // ---- normalize + coalesced O^T store ----
  float inv = 1.f / ln;
  const size_t otb = (size_t)bh * 128 * NN + q0 + lq;
#pragma unroll
  for (int db = 0; db < 4; ++db)
#pragma unroll
    for (int r = 0; r < 16; ++r) {
      int dl = (r & 3) + 8 * (r >> 2) + 4 * h;
      OT[otb + (size_t)(db * 32 + dl) * NN] = o[db][r] * inv;
    }
}

// ============================================================
// Host-side orchestration
// ============================================================
extern "C" void kernel_launch(void* const* d_in, const int* in_sizes, int n_in,
                              void* d_out, int out_size, void* d_ws, size_t ws_size,
                              hipStream_t stream) {
  const float* xr   = (const float*)d_in[0];
  const float* xi   = (const float*)d_in[1];
  const float* Wqr  = (const float*)d_in[2];
  const float* Wqi  = (const float*)d_in[3];
  const float* bqr  = (const float*)d_in[4];
  const float* bqi  = (const float*)d_in[5];
  const float* Wkr  = (const float*)d_in[6];
  const float* Wki  = (const float*)d_in[7];
  const float* bkr  = (const float*)d_in[8];
  const float* bki  = (const float*)d_in[9];
  const float* Wvr  = (const float*)d_in[10];
  const float* Wvi  = (const float*)d_in[11];
  const float* bvr  = (const float*)d_in[12];
  const float* bvi  = (const float*)d_in[13];
  const float* Wor  = (const float*)d_in[14];
  const float* Woi  = (const float*)d_in[15];
  const float* bor  = (const float*)d_in[16];
  const float* boi  = (const float*)d_in[17];
  const float* gq   = (const float*)d_in[18];
  const float* beq  = (const float*)d_in[19];
  const float* gk   = (const float*)d_in[20];
  const float* bek  = (const float*)d_in[21];
  const float* gv   = (const float*)d_in[22];
  const float* bev  = (const float*)d_in[23];

  char* wp = (char*)d_ws;
  bf16_t* Axaug = (bf16_t*)wp;  wp += (size_t)4096 * 2048 * 2;
  bf16_t* Wcat  = (bf16_t*)wp;  wp += (size_t)2048 * 2048 * 2;
  float*  bcat  = (float*)wp;   wp += (size_t)2048 * 4;
  float2* lnst  = (float2*)wp;  wp += (size_t)4096 * 8;
  float*  Ar    = (float*)wp;   wp += (size_t)4096 * 1024 * 4;
  float*  Ai    = (float*)wp;   wp += (size_t)4096 * 1024 * 4;
  bf16_t* Qf    = (bf16_t*)wp;  wp += (size_t)64 * 1024 * 128 * 2;
  bf16_t* Kf    = (bf16_t*)wp;  wp += (size_t)64 * 1024 * 128 * 2;
  bf16_t* VfT   = (bf16_t*)wp;  wp += (size_t)64 * 1024 * 128 * 2;
  bf16_t* Yaug  = Qf;
  float*  OT    = Ar;   // attn output O^T [BH,128,N] fp32 (spans Ar+Ai)

  const dim3 gGemm(16, 32);
  const int gPackX = (4096 * 2048 / 8) / 256;
  const int gPackW = (2048 * 2048 / 8) / 256;
  const int gFft = 64 * 16;
  const int gAtt = 64 * 8;

  pack_x<<<gPackX, 256, 0, stream>>>(xr, xi, Axaug);

  // ---- Q (FFT output scale folds in the 1/8 attention scale; LN fused) ----
  pack_w<<<gPackW, 256, 0, stream>>>(Wqr, Wqi, bqr, bqi, Wcat, bcat);
  gemm_bf16<<<gGemm, 256, 0, stream>>>(Axaug, Wcat, bcat, Ar, Ai, 1024);
  ln_stats<<<BN, 256, 0, stream>>>(Ar, Ai, lnst);
  fft_kernel<<<gFft, 512, 0, stream>>>(Ar, Ai, Qf, Qf + 64,
      NN * DIMM, DHH, DIMM, 1,
      16 * NN * 128, NN * 128, 128, 1, -1.0f, 0.03125f * 0.125f, 0,
      lnst, gq, beq);
  // ---- K (row-major + XOR pre-swizzle for LDS-staged fattn reads) ----
  pack_w<<<gPackW, 256, 0, stream>>>(Wkr, Wki, bkr, bki, Wcat, bcat);
  gemm_bf16<<<gGemm, 256, 0, stream>>>(Axaug, Wcat, bcat, Ar, Ai, 1024);
  ln_stats<<<BN, 256, 0, stream>>>(Ar, Ai, lnst);
  fft_kernel<<<gFft, 512, 0, stream>>>(Ar, Ai, Kf, Kf + 64,
      NN * DIMM, DHH, DIMM, 1,
      16 * NN * 128, NN * 128, 128, 1, -1.0f, 0.03125f, 2,
      lnst, gk, bek);
  // ---- V (kv-tile-blocked + XOR pre-swizzle) ----
  pack_w<<<gPackW, 256, 0, stream>>>(Wvr, Wvi, bvr, bvi, Wcat, bcat);
  gemm_bf16<<<gGemm, 256, 0, stream>>>(Axaug, Wcat, bcat, Ar, Ai, 1024);
  ln_stats<<<BN, 256, 0, stream>>>(Ar, Ai, lnst);
  fft_kernel<<<gFft, 512, 0, stream>>>(Ar, Ai, VfT, VfT + 2048,
      NN * DIMM, DHH, DIMM, 1,
      16 * 131072, 131072, 0, 0, -1.0f, 0.03125f, 1,
      lnst, gv, bev);
  // ---- flash attention -> OT [BH,128,N] fp32 ----
  fattn<<<gAtt, 256, 0, stream>>>(Qf, Kf, VfT, OT);
  // ---- inverse FFT: OT (d-major) -> Yaug bf16 [4096][2048] ----
  fft_kernel<<<gFft, 512, 0, stream>>>(OT, OT + (size_t)64 * NN, Yaug, Yaug + 1024,
      16 * 128 * NN, 128 * NN, 1, NN,
      NN * 2048, 64, 2048, 1, +1.0f, 0.03125f, 0,
      nullptr, nullptr, nullptr);
  // ---- output projection straight into d_out ----
  float* yout = (float*)d_out;
  pack_w<<<gPackW, 256, 0, stream>>>(Wor, Woi, bor, boi, Wcat, bcat);
  gemm_bf16<<<gGemm, 256, 0, stream>>>(Yaug, Wcat, bcat, yout, yout + 1024, 2048);
}

// Round 11
// 476.542 us; speedup vs baseline: 1.3651x; 1.1527x over previous
//
#include <hip/hip_runtime.h>
#include <math.h>

#define BB 4
#define NN 1024
#define DIMM 1024
#define HHH 16
#define DHH 64
#define BN 4096            // B*N rows
#define EPS_LN 1e-6f

typedef __bf16 bf16_t;
typedef __bf16 bf16x8 __attribute__((ext_vector_type(8)));
typedef float f32x4 __attribute__((ext_vector_type(4)));
typedef float f32x16 __attribute__((ext_vector_type(16)));
#define MFMA16(a, b, c) __builtin_amdgcn_mfma_f32_16x16x32_bf16(a, b, c, 0, 0, 0)
#define MFMA32(a, b, c) __builtin_amdgcn_mfma_f32_32x32x16_bf16(a, b, c, 0, 0, 0)
#define AS1 __attribute__((address_space(1)))
#define AS3 __attribute__((address_space(3)))

__device__ inline unsigned pk2(float a, float b) {
  union { bf16_t h[2]; unsigned u; } c;
  c.h[0] = (bf16_t)a; c.h[1] = (bf16_t)b;
  return c.u;
}
union U16 { uint4 u; bf16x8 v; };

// ============================================================
// pack_x: Axaug[4096][2048] = bf16([xr | xi])
// ============================================================
__global__ __launch_bounds__(256) void pack_x(
    const float* __restrict__ xr, const float* __restrict__ xi,
    bf16_t* __restrict__ out)
{
  int t = blockIdx.x * 256 + threadIdx.x;
  size_t e = (size_t)t * 8;
  int row = (int)(e >> 11), col = (int)(e & 2047);
  const float* src = (col < 1024) ? (xr + (size_t)row * 1024 + col)
                                  : (xi + (size_t)row * 1024 + col - 1024);
  float4 a = *(const float4*)src;
  float4 b = *(const float4*)(src + 4);
  bf16x8 o;
  o[0] = (bf16_t)a.x; o[1] = (bf16_t)a.y; o[2] = (bf16_t)a.z; o[3] = (bf16_t)a.w;
  o[4] = (bf16_t)b.x; o[5] = (bf16_t)b.y; o[6] = (bf16_t)b.z; o[7] = (bf16_t)b.w;
  *(bf16x8*)(out + e) = o;
}

// ============================================================
// pack_w: Wcat[2048][2048]: rows 0-1023 = [Wr | -Wi], rows 1024-2047 = [Wi | Wr]
// ============================================================
__global__ __launch_bounds__(256) void pack_w(
    const float* __restrict__ Wr, const float* __restrict__ Wi,
    const float* __restrict__ br, const float* __restrict__ bi,
    bf16_t* __restrict__ Wcat, float* __restrict__ bcat)
{
  int t = blockIdx.x * 256 + threadIdx.x;
  size_t e = (size_t)t * 8;
  int row = (int)(e >> 11), col = (int)(e & 2047);
  const float* src;
  float sgn = 1.f;
  if (row < 1024) {
    if (col < 1024) src = Wr + (size_t)row * 1024 + col;
    else          { src = Wi + (size_t)row * 1024 + col - 1024; sgn = -1.f; }
  } else {
    int r2 = row - 1024;
    if (col < 1024) src = Wi + (size_t)r2 * 1024 + col;
    else            src = Wr + (size_t)r2 * 1024 + col - 1024;
  }
  float4 a = *(const float4*)src;
  float4 b = *(const float4*)(src + 4);
  bf16x8 o;
  o[0] = (bf16_t)(sgn * a.x); o[1] = (bf16_t)(sgn * a.y);
  o[2] = (bf16_t)(sgn * a.z); o[3] = (bf16_t)(sgn * a.w);
  o[4] = (bf16_t)(sgn * b.x); o[5] = (bf16_t)(sgn * b.y);
  o[6] = (bf16_t)(sgn * b.z); o[7] = (bf16_t)(sgn * b.w);
  *(bf16x8*)(Wcat + e) = o;
  if (e < 2048) {
#pragma unroll
    for (int j = 0; j < 8; ++j) {
      int n = (int)e + j;
      bcat[n] = (n < 1024) ? br[n] : bi[n - 1024];
    }
  }
}

// ============================================================
// bf16 MFMA GEMM (NT), m97 structure (unchanged).
// ============================================================
__global__ __launch_bounds__(256) void gemm_bf16(
    const bf16_t* __restrict__ A, const bf16_t* __restrict__ Bt,
    const float* __restrict__ bias,
    float* __restrict__ Cr, float* __restrict__ Ci, int ldc)
{
  __shared__ bf16_t sA[128 * 64];
  __shared__ bf16_t sB[128 * 64];
  const int tid = threadIdx.x;
  const int w = tid >> 6, l = tid & 63;
  const int lo4 = l & 15, hi = l >> 4;
  const int wr = w >> 1, wc = w & 1;
  const int row0 = blockIdx.y * 128, col0 = blockIdx.x * 128;

  const int srow = (l >> 3);
  const int scol = (l & 7) * 8;
  const bf16_t* gA[4];
  const bf16_t* gB[4];
#pragma unroll
  for (int i = 0; i < 4; ++i) {
    int r = (w * 4 + i) * 8 + srow;
    gA[i] = A  + (size_t)(row0 + r) * 2048 + scol;
    gB[i] = Bt + (size_t)(col0 + r) * 2048 + scol;
  }

  f32x4 acc[4][4] = {};
  for (int k0 = 0; k0 < 2048; k0 += 64) {
    __syncthreads();
#pragma unroll
    for (int i = 0; i < 4; ++i) {
      __builtin_amdgcn_global_load_lds((const AS1 void*)(gA[i] + k0),
                                       (AS3 void*)&sA[(w * 4 + i) * 512], 16, 0, 0);
      __builtin_amdgcn_global_load_lds((const AS1 void*)(gB[i] + k0),
                                       (AS3 void*)&sB[(w * 4 + i) * 512], 16, 0, 0);
    }
    __syncthreads();
#pragma unroll
    for (int kk = 0; kk < 2; ++kk) {
      bf16x8 am[4], bn[4];
#pragma unroll
      for (int i = 0; i < 4; ++i)
        am[i] = *(const bf16x8*)&sA[(wr * 64 + i * 16 + lo4) * 64 + kk * 32 + hi * 8];
#pragma unroll
      for (int j = 0; j < 4; ++j)
        bn[j] = *(const bf16x8*)&sB[(wc * 64 + j * 16 + lo4) * 64 + kk * 32 + hi * 8];
#pragma unroll
      for (int i = 0; i < 4; ++i)
#pragma unroll
        for (int j = 0; j < 4; ++j)
          acc[i][j] = MFMA16(am[i], bn[j], acc[i][j]);
    }
  }
  const int colg0 = col0 + wc * 64;
  float* Cp = (colg0 < 1024) ? Cr : Ci;
  const int cb = colg0 & 1023;
#pragma unroll
  for (int i = 0; i < 4; ++i) {
#pragma unroll
    for (int j = 0; j < 4; ++j) {
      float bv = bias[colg0 + j * 16 + lo4];
#pragma unroll
      for (int r = 0; r < 4; ++r) {
        int rowg = row0 + wr * 64 + i * 16 + hi * 4 + r;
        Cp[(size_t)rowg * ldc + cb + j * 16 + lo4] = acc[i][j][r] + bv;
      }
    }
  }
}

// ============================================================
// LN row stats (unchanged)
// ============================================================
__global__ __launch_bounds__(256) void ln_stats(
    const float* __restrict__ re, const float* __restrict__ im,
    float2* __restrict__ st)
{
  __shared__ float red[8];
  const int row = blockIdx.x;
  const int tid = threadIdx.x;
  const float* pr = re + (size_t)row * DIMM;
  const float* pi = im + (size_t)row * DIMM;
  float s = 0.f, s2 = 0.f;
#pragma unroll
  for (int t = 0; t < 4; ++t) {
    int c = tid + t * 256;
    float vr = pr[c], vi = pi[c];
    float mg = sqrtf(vr * vr + vi * vi);
    s += mg; s2 += mg * mg;
  }
#pragma unroll
  for (int o = 32; o; o >>= 1) { s += __shfl_down(s, o); s2 += __shfl_down(s2, o); }
  if ((tid & 63) == 0) { red[tid >> 6] = s; red[4 + (tid >> 6)] = s2; }
  __syncthreads();
  if (tid == 0) {
    float S = red[0] + red[1] + red[2] + red[3];
    float S2 = red[4] + red[5] + red[6] + red[7];
    float mean = S * (1.f / DIMM);
    float var = S2 * (1.f / DIMM) - mean * mean;
    st[row] = make_float2(mean, rsqrtf(var + EPS_LN));
  }
}

// ============================================================
// 1024-pt radix-2 DIF FFT v2: 16 d-lanes/block (256 blocks x 512 thr),
// fully-coalesced IO, phi-swizzled LDS (col ^= (col>>5)&31, stride 1025).
// imode 0: d-contiguous input (64B/thread/n), fused complex-LN optional.
// imode 1: n-contiguous input (iFFT from OT [d][N]).
// omode 0: packed 2x bf16x8 per plane at n*out_sn + dc*16 (Q, Yaug).
// omode 2: same + K XOR-swizzle = 16-col block select + half swap
//          (byte-identical to  ga = n*128 + (dch ^ ((n&7)<<3)) ).
// omode 1: V kv-tile-blocked scalar stores (consecutive-n lanes cover
//          full 64B lines) — byte-identical to round-10 layout.
// ============================================================
#define LIDX(d_, c_) ((d_) * 1025 + ((c_) ^ (((c_) >> 5) & 31)))

__global__ __launch_bounds__(512) void fft_kernel(
    const float* __restrict__ inR, const float* __restrict__ inI,
    bf16_t* __restrict__ outR, bf16_t* __restrict__ outI,
    int in_sb, int in_sh, int in_sn, int in_sd,
    int out_sb, int out_sh, int out_sn,
    float sign, float oscale, int imode, int omode,
    const float2* __restrict__ stats,
    const float* __restrict__ gamma, const float* __restrict__ beta)
{
  __shared__ float lr[16 * 1025], li[16 * 1025];
  __shared__ float2 tw[512];
  const int tid = threadIdx.x;
  const int dc = blockIdx.x & 3;          // 4 chunks of 16 d
  const int bh = blockIdx.x >> 2;
  const int b = bh >> 4, h = bh & 15;
  const float* bR = inR + (size_t)b * in_sb + (size_t)h * in_sh;
  const float* bI = inI + (size_t)b * in_sb + (size_t)h * in_sh;
  {
    float ang = sign * 3.14159265358979323846f * (float)tid * (1.f / 512.f);
    float sn, cs;
    __sincosf(ang, &sn, &cs);
    tw[tid] = make_float2(cs, sn);
  }
  // ---- load (+ optional fused LN) ----
  if (imode == 0) {
    float gg[16], bb[16];
    if (stats) {
#pragma unroll
      for (int ds = 0; ds < 16; ++ds) {
        gg[ds] = gamma[h * DHH + dc * 16 + ds];
        bb[ds] = beta[h * DHH + dc * 16 + ds];
      }
    }
#pragma unroll
    for (int rep = 0; rep < 2; ++rep) {
      int n = tid + rep * 512;
      const float* pR = bR + (size_t)n * in_sn + dc * 16;
      const float* pI = bI + (size_t)n * in_sn + dc * 16;
      union { float4 q[4]; float f[16]; } ur, ui;
#pragma unroll
      for (int k = 0; k < 4; ++k) {
        ur.q[k] = *(const float4*)(pR + k * 4);
        ui.q[k] = *(const float4*)(pI + k * 4);
      }
      if (stats) {
        float2 stv = stats[b * NN + n];
#pragma unroll
        for (int ds = 0; ds < 16; ++ds) {
          float a = ur.f[ds], c2 = ui.f[ds];
          float mag = sqrtf(a * a + c2 * c2);
          float nm = (mag - stv.x) * stv.y * gg[ds] + bb[ds];
          if (mag > 0.f) { float sc = nm / mag; ur.f[ds] = a * sc; ui.f[ds] = c2 * sc; }
          else           { ur.f[ds] = nm; ui.f[ds] = 0.f; }
        }
      }
#pragma unroll
      for (int ds = 0; ds < 16; ++ds) {
        int ax = LIDX(ds, n);
        lr[ax] = ur.f[ds];
        li[ax] = ui.f[ds];
      }
    }
  } else {
    const int ds = tid & 15, nb = tid >> 4;   // nb 0..31
    const float* pR = bR + (size_t)(dc * 16 + ds) * in_sd + nb * 32;
    const float* pI = bI + (size_t)(dc * 16 + ds) * in_sd + nb * 32;
#pragma unroll
    for (int k = 0; k < 32; k += 4) {
      float4 v = *(const float4*)(pR + k);
      float4 w = *(const float4*)(pI + k);
      int c = nb * 32 + k;
      lr[LIDX(ds, c + 0)] = v.x;  li[LIDX(ds, c + 0)] = w.x;
      lr[LIDX(ds, c + 1)] = v.y;  li[LIDX(ds, c + 1)] = w.y;
      lr[LIDX(ds, c + 2)] = v.z;  li[LIDX(ds, c + 2)] = w.z;
      lr[LIDX(ds, c + 3)] = v.w;  li[LIDX(ds, c + 3)] = w.w;
    }
  }
  __syncthreads();
  // ---- radix-2 DIF butterflies ----
  const int dsub = tid & 15;
  const int jb = tid >> 4;                 // 0..31
  for (int hs = 9; hs >= 0; --hs) {
    int half = 1 << hs;
    for (int it = 0; it < 16; ++it) {
      int j = jb + it * 32;                // 0..511
      int o = j & (half - 1);
      int i0 = ((j >> hs) << (hs + 1)) + o;
      int i1 = i0 + half;
      int a0 = LIDX(dsub, i0), a1 = LIDX(dsub, i1);
      float ar = lr[a0], ai = li[a0];
      float br_ = lr[a1], bi_ = li[a1];
      lr[a0] = ar + br_;
      li[a0] = ai + bi_;
      float sr = ar - br_, si = ai - bi_;
      float2 t = tw[o << (9 - hs)];
      lr[a1] = sr * t.x - si * t.y;
      li[a1] = sr * t.y + si * t.x;
    }
    __syncthreads();
  }
  // ---- store (bit-reversal folded into LDS read) ----
  bf16_t* oRb = outR + (size_t)b * out_sb + (size_t)h * out_sh;
  bf16_t* oIb = outI + (size_t)b * out_sb + (size_t)h * out_sh;
#pragma unroll
  for (int rep = 0; rep < 2; ++rep) {
    int n = tid + rep * 512;
    int rv = __brev((unsigned)n) >> 22;
    int phi = rv ^ ((rv >> 5) & 31);
    float fr[16], fi[16];
#pragma unroll
    for (int ds = 0; ds < 16; ++ds) {
      fr[ds] = lr[ds * 1025 + phi] * oscale;
      fi[ds] = li[ds * 1025 + phi] * oscale;
    }
    if (omode == 1) {
      size_t tb = (size_t)(n >> 5) * 4096;
#pragma unroll
      for (int ds = 0; ds < 16; ++ds) {
        int dch = dc * 16 + ds;
        size_t ga = tb + (size_t)dch * 32 + ((n & 31) ^ (((dch >> 1) & 3) << 3));
        oRb[ga] = (bf16_t)fr[ds];
        oIb[ga] = (bf16_t)fi[ds];
      }
    } else {
      int cb = dc * 16, sw = 0;
      if (omode == 2) { cb = (dc ^ ((n >> 1) & 3)) * 16; sw = (n & 1) << 3; }
      bf16x8 v0, v1, w0, w1;
#pragma unroll
      for (int k = 0; k < 8; ++k) {
        v0[k] = (bf16_t)fr[k ^ sw];
        v1[k] = (bf16_t)fr[(k + 8) ^ sw];
        w0[k] = (bf16_t)fi[k ^ sw];
        w1[k] = (bf16_t)fi[(k + 8) ^ sw];
      }
      size_t gb = (size_t)n * out_sn + cb;
      *(bf16x8*)(oRb + gb) = v0;
      *(bf16x8*)(oRb + gb + 8) = v1;
      *(bf16x8*)(oIb + gb) = w0;
      *(bf16x8*)(oIb + gb + 8) = w1;
    }
  }
}

// ============================================================
// Flash attention v6 (unchanged from round 10 — control).
// ============================================================
__global__ __launch_bounds__(256, 2) void fattn(
    const bf16_t* __restrict__ Qf, const bf16_t* __restrict__ Kfs,
    const bf16_t* __restrict__ Vfs, float* __restrict__ OT)
{
  __shared__ bf16_t K2[2][4096];
  __shared__ bf16_t V2[2][4096];
  const int tid = threadIdx.x;
  const int w = tid >> 6, l = tid & 63;
  const int lq = l & 31;
  const int h = l >> 5;
  const int i = blockIdx.x;
  const int j = i >> 3;
  const int bh = (i & 7) * 8 + (j >> 3);
  const int q0 = (j & 7) * 128 + w * 32;

  bf16x8 bq[8];
  const bf16_t* qp = Qf + ((size_t)bh * NN + q0 + lq) * 128 + h * 8;
#pragma unroll
  for (int kk = 0; kk < 8; ++kk) bq[kk] = *(const bf16x8*)(qp + kk * 16);

  f32x16 o[4] = {};
  float m = -3e38f, ln = 0.f;

  const bf16_t* kg = Kfs + (size_t)bh * 131072 + w * 1024 + l * 8;
  const bf16_t* vg = Vfs + (size_t)bh * 131072 + w * 1024 + l * 8;
  const int kswz = (lq & 7) << 3;
  const int vswz = ((lq >> 1) & 3) << 3;

#pragma unroll
  for (int ii = 0; ii < 2; ++ii) {
    __builtin_amdgcn_global_load_lds((const AS1 void*)(kg + ii * 512),
                                     (AS3 void*)&K2[0][w * 1024 + ii * 512], 16, 0, 0);
    __builtin_amdgcn_global_load_lds((const AS1 void*)(vg + ii * 512),
                                     (AS3 void*)&V2[0][w * 1024 + ii * 512], 16, 0, 0);
  }
  __syncthreads();

  int cur = 0;
  for (int t = 0; t < 32; ++t) {
    if (t < 31) {
      const bf16_t* kt = kg + (size_t)(t + 1) * 4096;
      const bf16_t* vt = vg + (size_t)(t + 1) * 4096;
#pragma unroll
      for (int ii = 0; ii < 2; ++ii) {
        __builtin_amdgcn_global_load_lds((const AS1 void*)(kt + ii * 512),
                                         (AS3 void*)&K2[cur ^ 1][w * 1024 + ii * 512], 16, 0, 0);
        __builtin_amdgcn_global_load_lds((const AS1 void*)(vt + ii * 512),
                                         (AS3 void*)&V2[cur ^ 1][w * 1024 + ii * 512], 16, 0, 0);
      }
    }

    f32x16 s = {};
#pragma unroll
    for (int kk = 0; kk < 8; ++kk) {
      bf16x8 ak = *(const bf16x8*)&K2[cur][lq * 128 + ((kk * 16 + h * 8) ^ kswz)];
      s = MFMA32(ak, bq[kk], s);
    }

    float pmax = s[0];
#pragma unroll
    for (int r = 1; r < 16; ++r) pmax = fmaxf(pmax, s[r]);
    pmax = fmaxf(pmax, __shfl_xor(pmax, 32));
    if (!__all(pmax - m <= 8.f)) {
      float mnew = fmaxf(m, pmax);
      float alpha = __expf(m - mnew);
      m = mnew;
      ln *= alpha;
#pragma unroll
      for (int db = 0; db < 4; ++db)
#pragma unroll
        for (int r = 0; r < 16; ++r) o[db][r] *= alpha;
    }
    float pf[16];
    float rs = 0.f;
#pragma unroll
    for (int r = 0; r < 16; ++r) { pf[r] = __expf(s[r] - m); rs += pf[r]; }
    rs += __shfl_xor(rs, 32);
    ln += rs;

    unsigned pw[8];
#pragma unroll
    for (int ii = 0; ii < 8; ++ii) pw[ii] = pk2(pf[2 * ii], pf[2 * ii + 1]);
    unsigned r0 = (unsigned)__shfl_xor((int)(h ? pw[0] : pw[2]), 32);
    unsigned r1 = (unsigned)__shfl_xor((int)(h ? pw[1] : pw[3]), 32);
    unsigned r2 = (unsigned)__shfl_xor((int)(h ? pw[4] : pw[6]), 32);
    unsigned r3 = (unsigned)__shfl_xor((int)(h ? pw[5] : pw[7]), 32);
    U16 bp0, bp1;
    bp0.u.x = h ? r0 : pw[0];  bp0.u.y = h ? r1 : pw[1];
    bp0.u.z = h ? pw[2] : r0;  bp0.u.w = h ? pw[3] : r1;
    bp1.u.x = h ? r2 : pw[4];  bp1.u.y = h ? r3 : pw[5];
    bp1.u.z = h ? pw[6] : r2;  bp1.u.w = h ? pw[7] : r3;

#pragma unroll
    for (int db = 0; db < 4; ++db) {
      int r = db * 32 + lq;
      bf16x8 av0 = *(const bf16x8*)&V2[cur][r * 32 + ((h * 8) ^ vswz)];
      bf16x8 av1 = *(const bf16x8*)&V2[cur][r * 32 + ((16 + h * 8) ^ vswz)];
      o[db] = MFMA32(av0, bp0.v, o[db]);
      o[db] = MFMA32(av1, bp1.v, o[db]);
    }

    __syncthreads();
    cur ^= 1;
  }

  float inv = 1.f / ln;
  const size_t otb = (size_t)bh * 128 * NN + q0 + lq;
#pragma unroll
  for (int db = 0; db < 4; ++db)
#pragma unroll
    for (int r = 0; r < 16; ++r) {
      int dl = (r & 3) + 8 * (r >> 2) + 4 * h;
      OT[otb + (size_t)(db * 32 + dl) * NN] = o[db][r] * inv;
    }
}

// ============================================================
// Host-side orchestration
// ============================================================
extern "C" void kernel_launch(void* const* d_in, const int* in_sizes, int n_in,
                              void* d_out, int out_size, void* d_ws, size_t ws_size,
                              hipStream_t stream) {
  const float* xr   = (const float*)d_in[0];
  const float* xi   = (const float*)d_in[1];
  const float* Wqr  = (const float*)d_in[2];
  const float* Wqi  = (const float*)d_in[3];
  const float* bqr  = (const float*)d_in[4];
  const float* bqi  = (const float*)d_in[5];
  const float* Wkr  = (const float*)d_in[6];
  const float* Wki  = (const float*)d_in[7];
  const float* bkr  = (const float*)d_in[8];
  const float* bki  = (const float*)d_in[9];
  const float* Wvr  = (const float*)d_in[10];
  const float* Wvi  = (const float*)d_in[11];
  const float* bvr  = (const float*)d_in[12];
  const float* bvi  = (const float*)d_in[13];
  const float* Wor  = (const float*)d_in[14];
  const float* Woi  = (const float*)d_in[15];
  const float* bor  = (const float*)d_in[16];
  const float* boi  = (const float*)d_in[17];
  const float* gq   = (const float*)d_in[18];
  const float* beq  = (const float*)d_in[19];
  const float* gk   = (const float*)d_in[20];
  const float* bek  = (const float*)d_in[21];
  const float* gv   = (const float*)d_in[22];
  const float* bev  = (const float*)d_in[23];

  char* wp = (char*)d_ws;
  bf16_t* Axaug = (bf16_t*)wp;  wp += (size_t)4096 * 2048 * 2;
  bf16_t* Wcat  = (bf16_t*)wp;  wp += (size_t)2048 * 2048 * 2;
  float*  bcat  = (float*)wp;   wp += (size_t)2048 * 4;
  float2* lnst  = (float2*)wp;  wp += (size_t)4096 * 8;
  float*  Ar    = (float*)wp;   wp += (size_t)4096 * 1024 * 4;
  float*  Ai    = (float*)wp;   wp += (size_t)4096 * 1024 * 4;
  bf16_t* Qf    = (bf16_t*)wp;  wp += (size_t)64 * 1024 * 128 * 2;
  bf16_t* Kf    = (bf16_t*)wp;  wp += (size_t)64 * 1024 * 128 * 2;
  bf16_t* VfT   = (bf16_t*)wp;  wp += (size_t)64 * 1024 * 128 * 2;
  bf16_t* Yaug  = Qf;
  float*  OT    = Ar;   // attn output O^T [BH,128,N] fp32 (spans Ar+Ai)

  const dim3 gGemm(16, 32);
  const int gPackX = (4096 * 2048 / 8) / 256;
  const int gPackW = (2048 * 2048 / 8) / 256;
  const int gFft = 64 * 4;           // bh x 4 d-chunks of 16
  const int gAtt = 64 * 8;

  pack_x<<<gPackX, 256, 0, stream>>>(xr, xi, Axaug);

  // ---- Q (FFT output scale folds in the 1/8 attention scale; LN fused) ----
  pack_w<<<gPackW, 256, 0, stream>>>(Wqr, Wqi, bqr, bqi, Wcat, bcat);
  gemm_bf16<<<gGemm, 256, 0, stream>>>(Axaug, Wcat, bcat, Ar, Ai, 1024);
  ln_stats<<<BN, 256, 0, stream>>>(Ar, Ai, lnst);
  fft_kernel<<<gFft, 512, 0, stream>>>(Ar, Ai, Qf, Qf + 64,
      NN * DIMM, DHH, DIMM, 1,
      16 * NN * 128, NN * 128, 128,
      -1.0f, 0.03125f * 0.125f, 0, 0, lnst, gq, beq);
  // ---- K (row-major + XOR pre-swizzle) ----
  pack_w<<<gPackW, 256, 0, stream>>>(Wkr, Wki, bkr, bki, Wcat, bcat);
  gemm_bf16<<<gGemm, 256, 0, stream>>>(Axaug, Wcat, bcat, Ar, Ai, 1024);
  ln_stats<<<BN, 256, 0, stream>>>(Ar, Ai, lnst);
  fft_kernel<<<gFft, 512, 0, stream>>>(Ar, Ai, Kf, Kf + 64,
      NN * DIMM, DHH, DIMM, 1,
      16 * NN * 128, NN * 128, 128,
      -1.0f, 0.03125f, 0, 2, lnst, gk, bek);
  // ---- V (kv-tile-blocked + XOR pre-swizzle) ----
  pack_w<<<gPackW, 256, 0, stream>>>(Wvr, Wvi, bvr, bvi, Wcat, bcat);
  gemm_bf16<<<gGemm, 256, 0, stream>>>(Axaug, Wcat, bcat, Ar, Ai, 1024);
  ln_stats<<<BN, 256, 0, stream>>>(Ar, Ai, lnst);
  fft_kernel<<<gFft, 512, 0, stream>>>(Ar, Ai, VfT, VfT + 2048,
      NN * DIMM, DHH, DIMM, 1,
      16 * 131072, 131072, 0,
      -1.0f, 0.03125f, 0, 1, lnst, gv, bev);
  // ---- flash attention -> OT [BH,128,N] fp32 ----
  fattn<<<gAtt, 256, 0, stream>>>(Qf, Kf, VfT, OT);
  // ---- inverse FFT: OT (d-major, n-contiguous reads) -> Yaug ----
  fft_kernel<<<gFft, 512, 0, stream>>>(OT, OT + (size_t)64 * NN, Yaug, Yaug + 1024,
      16 * 128 * NN, 128 * NN, 1, NN,
      NN * 2048, 64, 2048,
      +1.0f, 0.03125f, 1, 0, nullptr, nullptr, nullptr);
  // ---- output projection straight into d_out ----
  float* yout = (float*)d_out;
  pack_w<<<gPackW, 256, 0, stream>>>(Wor, Woi, bor, boi, Wcat, bcat);
  gemm_bf16<<<gGemm, 256, 0, stream>>>(Yaug, Wcat, bcat, yout, yout + 1024, 2048);
}

// Round 12
// 431.696 us; speedup vs baseline: 1.5069x; 1.1039x over previous
//
#include <hip/hip_runtime.h>
#include <math.h>

#define BB 4
#define NN 1024
#define DIMM 1024
#define HHH 16
#define DHH 64
#define BN 4096            // B*N rows
#define EPS_LN 1e-6f

typedef __bf16 bf16_t;
typedef __bf16 bf16x8 __attribute__((ext_vector_type(8)));
typedef float f32x4 __attribute__((ext_vector_type(4)));
typedef float f32x16 __attribute__((ext_vector_type(16)));
#define MFMA16(a, b, c) __builtin_amdgcn_mfma_f32_16x16x32_bf16(a, b, c, 0, 0, 0)
#define MFMA32(a, b, c) __builtin_amdgcn_mfma_f32_32x32x16_bf16(a, b, c, 0, 0, 0)
#define AS1 __attribute__((address_space(1)))
#define AS3 __attribute__((address_space(3)))

__device__ inline unsigned pk2(float a, float b) {
  union { bf16_t h[2]; unsigned u; } c;
  c.h[0] = (bf16_t)a; c.h[1] = (bf16_t)b;
  return c.u;
}
union U16 { uint4 u; bf16x8 v; };

// ============================================================
// pack_x: Axaug[4096][2048] = bf16([xr | xi])
// ============================================================
__global__ __launch_bounds__(256) void pack_x(
    const float* __restrict__ xr, const float* __restrict__ xi,
    bf16_t* __restrict__ out)
{
  int t = blockIdx.x * 256 + threadIdx.x;
  size_t e = (size_t)t * 8;
  int row = (int)(e >> 11), col = (int)(e & 2047);
  const float* src = (col < 1024) ? (xr + (size_t)row * 1024 + col)
                                  : (xi + (size_t)row * 1024 + col - 1024);
  float4 a = *(const float4*)src;
  float4 b = *(const float4*)(src + 4);
  bf16x8 o;
  o[0] = (bf16_t)a.x; o[1] = (bf16_t)a.y; o[2] = (bf16_t)a.z; o[3] = (bf16_t)a.w;
  o[4] = (bf16_t)b.x; o[5] = (bf16_t)b.y; o[6] = (bf16_t)b.z; o[7] = (bf16_t)b.w;
  *(bf16x8*)(out + e) = o;
}

// ============================================================
// pack_w: Wcat[2048][2048]: rows 0-1023 = [Wr | -Wi], rows 1024-2047 = [Wi | Wr]
// ============================================================
__global__ __launch_bounds__(256) void pack_w(
    const float* __restrict__ Wr, const float* __restrict__ Wi,
    const float* __restrict__ br, const float* __restrict__ bi,
    bf16_t* __restrict__ Wcat, float* __restrict__ bcat)
{
  int t = blockIdx.x * 256 + threadIdx.x;
  size_t e = (size_t)t * 8;
  int row = (int)(e >> 11), col = (int)(e & 2047);
  const float* src;
  float sgn = 1.f;
  if (row < 1024) {
    if (col < 1024) src = Wr + (size_t)row * 1024 + col;
    else          { src = Wi + (size_t)row * 1024 + col - 1024; sgn = -1.f; }
  } else {
    int r2 = row - 1024;
    if (col < 1024) src = Wi + (size_t)r2 * 1024 + col;
    else            src = Wr + (size_t)r2 * 1024 + col - 1024;
  }
  float4 a = *(const float4*)src;
  float4 b = *(const float4*)(src + 4);
  bf16x8 o;
  o[0] = (bf16_t)(sgn * a.x); o[1] = (bf16_t)(sgn * a.y);
  o[2] = (bf16_t)(sgn * a.z); o[3] = (bf16_t)(sgn * a.w);
  o[4] = (bf16_t)(sgn * b.x); o[5] = (bf16_t)(sgn * b.y);
  o[6] = (bf16_t)(sgn * b.z); o[7] = (bf16_t)(sgn * b.w);
  *(bf16x8*)(Wcat + e) = o;
  if (e < 2048) {
#pragma unroll
    for (int j = 0; j < 8; ++j) {
      int n = (int)e + j;
      bcat[n] = (n < 1024) ? br[n] : bi[n - 1024];
    }
  }
}

// ============================================================
// bf16 MFMA GEMM (NT), m97 structure (unchanged).
// ============================================================
__global__ __launch_bounds__(256) void gemm_bf16(
    const bf16_t* __restrict__ A, const bf16_t* __restrict__ Bt,
    const float* __restrict__ bias,
    float* __restrict__ Cr, float* __restrict__ Ci, int ldc)
{
  __shared__ bf16_t sA[128 * 64];
  __shared__ bf16_t sB[128 * 64];
  const int tid = threadIdx.x;
  const int w = tid >> 6, l = tid & 63;
  const int lo4 = l & 15, hi = l >> 4;
  const int wr = w >> 1, wc = w & 1;
  const int row0 = blockIdx.y * 128, col0 = blockIdx.x * 128;

  const int srow = (l >> 3);
  const int scol = (l & 7) * 8;
  const bf16_t* gA[4];
  const bf16_t* gB[4];
#pragma unroll
  for (int i = 0; i < 4; ++i) {
    int r = (w * 4 + i) * 8 + srow;
    gA[i] = A  + (size_t)(row0 + r) * 2048 + scol;
    gB[i] = Bt + (size_t)(col0 + r) * 2048 + scol;
  }

  f32x4 acc[4][4] = {};
  for (int k0 = 0; k0 < 2048; k0 += 64) {
    __syncthreads();
#pragma unroll
    for (int i = 0; i < 4; ++i) {
      __builtin_amdgcn_global_load_lds((const AS1 void*)(gA[i] + k0),
                                       (AS3 void*)&sA[(w * 4 + i) * 512], 16, 0, 0);
      __builtin_amdgcn_global_load_lds((const AS1 void*)(gB[i] + k0),
                                       (AS3 void*)&sB[(w * 4 + i) * 512], 16, 0, 0);
    }
    __syncthreads();
#pragma unroll
    for (int kk = 0; kk < 2; ++kk) {
      bf16x8 am[4], bn[4];
#pragma unroll
      for (int i = 0; i < 4; ++i)
        am[i] = *(const bf16x8*)&sA[(wr * 64 + i * 16 + lo4) * 64 + kk * 32 + hi * 8];
#pragma unroll
      for (int j = 0; j < 4; ++j)
        bn[j] = *(const bf16x8*)&sB[(wc * 64 + j * 16 + lo4) * 64 + kk * 32 + hi * 8];
#pragma unroll
      for (int i = 0; i < 4; ++i)
#pragma unroll
        for (int j = 0; j < 4; ++j)
          acc[i][j] = MFMA16(am[i], bn[j], acc[i][j]);
    }
  }
  const int colg0 = col0 + wc * 64;
  float* Cp = (colg0 < 1024) ? Cr : Ci;
  const int cb = colg0 & 1023;
#pragma unroll
  for (int i = 0; i < 4; ++i) {
#pragma unroll
    for (int j = 0; j < 4; ++j) {
      float bv = bias[colg0 + j * 16 + lo4];
#pragma unroll
      for (int r = 0; r < 4; ++r) {
        int rowg = row0 + wr * 64 + i * 16 + hi * 4 + r;
        Cp[(size_t)rowg * ldc + cb + j * 16 + lo4] = acc[i][j][r] + bv;
      }
    }
  }
}

// ============================================================
// LN row stats (unchanged)
// ============================================================
__global__ __launch_bounds__(256) void ln_stats(
    const float* __restrict__ re, const float* __restrict__ im,
    float2* __restrict__ st)
{
  __shared__ float red[8];
  const int row = blockIdx.x;
  const int tid = threadIdx.x;
  const float* pr = re + (size_t)row * DIMM;
  const float* pi = im + (size_t)row * DIMM;
  float s = 0.f, s2 = 0.f;
#pragma unroll
  for (int t = 0; t < 4; ++t) {
    int c = tid + t * 256;
    float vr = pr[c], vi = pi[c];
    float mg = sqrtf(vr * vr + vi * vi);
    s += mg; s2 += mg * mg;
  }
#pragma unroll
  for (int o = 32; o; o >>= 1) { s += __shfl_down(s, o); s2 += __shfl_down(s2, o); }
  if ((tid & 63) == 0) { red[tid >> 6] = s; red[4 + (tid >> 6)] = s2; }
  __syncthreads();
  if (tid == 0) {
    float S = red[0] + red[1] + red[2] + red[3];
    float S2 = red[4] + red[5] + red[6] + red[7];
    float mean = S * (1.f / DIMM);
    float var = S2 * (1.f / DIMM) - mean * mean;
    st[row] = make_float2(mean, rsqrtf(var + EPS_LN));
  }
}

// ============================================================
// 1024-pt RADIX-4 DIF FFT v3: FD=8 d-lanes/block (512 blocks x 512 thr),
// 5 stages (vs 10), LDS 72KB -> 2 blocks/CU, XOR-mixed bank layout:
//   LIDX(d,c) = d*1024 + (c ^ ((c>>5)&31) ^ (d<<2))
// (derived: 2 lanes/bank = free for stages 0-3 + load/store phases).
// Base-4 digit reversal folded into the store read.
// imode/omode semantics and ALL global byte layouts identical to v2.
// ============================================================
#define LIDX(d_, c_) (((d_) << 10) + ((c_) ^ (((c_) >> 5) & 31) ^ (((d_) & 7) << 2)))

__global__ __launch_bounds__(512) void fft_kernel(
    const float* __restrict__ inR, const float* __restrict__ inI,
    bf16_t* __restrict__ outR, bf16_t* __restrict__ outI,
    int in_sb, int in_sh, int in_sn, int in_sd,
    int out_sb, int out_sh, int out_sn,
    float sign, float oscale, int imode, int omode,
    const float2* __restrict__ stats,
    const float* __restrict__ gamma, const float* __restrict__ beta)
{
  __shared__ float lr[8 * 1024], li[8 * 1024];
  __shared__ float2 tw[1024];
  const int tid = threadIdx.x;
  const int dc = blockIdx.x & 7;          // 8 chunks of 8 d
  const int bh = blockIdx.x >> 3;
  const int b = bh >> 4, h = bh & 15;
  const float* bR = inR + (size_t)b * in_sb + (size_t)h * in_sh;
  const float* bI = inI + (size_t)b * in_sb + (size_t)h * in_sh;
#pragma unroll
  for (int t = tid; t < 1024; t += 512) {
    float ang = sign * 3.14159265358979323846f * (float)t * (1.f / 512.f);
    float sn, cs;
    __sincosf(ang, &sn, &cs);
    tw[t] = make_float2(cs, sn);
  }
  // ---- load (+ optional fused LN) ----
  if (imode == 0) {
    float gg[8], bb[8];
    if (stats) {
#pragma unroll
      for (int ds = 0; ds < 8; ++ds) {
        gg[ds] = gamma[h * DHH + dc * 8 + ds];
        bb[ds] = beta[h * DHH + dc * 8 + ds];
      }
    }
#pragma unroll
    for (int rep = 0; rep < 2; ++rep) {
      int n = tid + rep * 512;
      const float* pR = bR + (size_t)n * in_sn + dc * 8;
      const float* pI = bI + (size_t)n * in_sn + dc * 8;
      union { float4 q[2]; float f[8]; } ur, ui;
      ur.q[0] = *(const float4*)pR;      ur.q[1] = *(const float4*)(pR + 4);
      ui.q[0] = *(const float4*)pI;      ui.q[1] = *(const float4*)(pI + 4);
      if (stats) {
        float2 stv = stats[b * NN + n];
#pragma unroll
        for (int ds = 0; ds < 8; ++ds) {
          float a = ur.f[ds], c2 = ui.f[ds];
          float mag = sqrtf(a * a + c2 * c2);
          float nm = (mag - stv.x) * stv.y * gg[ds] + bb[ds];
          if (mag > 0.f) { float sc = nm / mag; ur.f[ds] = a * sc; ui.f[ds] = c2 * sc; }
          else           { ur.f[ds] = nm; ui.f[ds] = 0.f; }
        }
      }
#pragma unroll
      for (int ds = 0; ds < 8; ++ds) {
        int ax = LIDX(ds, n);
        lr[ax] = ur.f[ds];
        li[ax] = ui.f[ds];
      }
    }
  } else {
    const int ds = tid & 7, nb = tid >> 3;   // nb 0..63
    const float* pR = bR + (size_t)(dc * 8 + ds) * in_sd + nb * 16;
    const float* pI = bI + (size_t)(dc * 8 + ds) * in_sd + nb * 16;
#pragma unroll
    for (int k = 0; k < 16; k += 4) {
      float4 v = *(const float4*)(pR + k);
      float4 w = *(const float4*)(pI + k);
      int c = nb * 16 + k;
      lr[LIDX(ds, c + 0)] = v.x;  li[LIDX(ds, c + 0)] = w.x;
      lr[LIDX(ds, c + 1)] = v.y;  li[LIDX(ds, c + 1)] = w.y;
      lr[LIDX(ds, c + 2)] = v.z;  li[LIDX(ds, c + 2)] = w.z;
      lr[LIDX(ds, c + 3)] = v.w;  li[LIDX(ds, c + 3)] = w.w;
    }
  }
  __syncthreads();
  // ---- 5 radix-4 DIF stages ----
  const int dsub = tid & 7;
  const int jb = tid >> 3;                 // 0..63
  int lq2 = 8;
  for (int st = 0; st < 5; ++st) {
    const int qtr = 1 << lq2;
    const int tmul = 1 << (2 * st);
    for (int jt = 0; jt < 4; ++jt) {
      int j = jb + jt * 64;                // 0..255
      int o = j & (qtr - 1);
      int i0 = ((j >> lq2) << (lq2 + 2)) + o;
      int a0 = LIDX(dsub, i0);
      int a1 = LIDX(dsub, i0 + qtr);
      int a2 = LIDX(dsub, i0 + 2 * qtr);
      int a3 = LIDX(dsub, i0 + 3 * qtr);
      float x0r = lr[a0], x0i = li[a0];
      float x1r = lr[a1], x1i = li[a1];
      float x2r = lr[a2], x2i = li[a2];
      float x3r = lr[a3], x3i = li[a3];
      float ar = x0r + x2r, ai2 = x0i + x2i;
      float br = x0r - x2r, bi  = x0i - x2i;
      float cr = x1r + x3r, ci  = x1i + x3i;
      float dr = x1r - x3r, di  = x1i - x3i;
      float2 t1 = tw[o * tmul];
      float2 t2 = tw[2 * o * tmul];
      float2 t3 = tw[3 * o * tmul];
      lr[a0] = ar + cr;  li[a0] = ai2 + ci;
      float u1r = br - sign * di, u1i = bi + sign * dr;
      lr[a1] = u1r * t1.x - u1i * t1.y;  li[a1] = u1r * t1.y + u1i * t1.x;
      float u2r = ar - cr, u2i = ai2 - ci;
      lr[a2] = u2r * t2.x - u2i * t2.y;  li[a2] = u2r * t2.y + u2i * t2.x;
      float u3r = br + sign * di, u3i = bi - sign * dr;
      lr[a3] = u3r * t3.x - u3i * t3.y;  li[a3] = u3r * t3.y + u3i * t3.x;
    }
    __syncthreads();
    lq2 -= 2;
  }
  // ---- store (base-4 digit reversal folded into LDS read) ----
  bf16_t* oRb = outR + (size_t)b * out_sb + (size_t)h * out_sh;
  bf16_t* oIb = outI + (size_t)b * out_sb + (size_t)h * out_sh;
#pragma unroll
  for (int rep = 0; rep < 2; ++rep) {
    int n = tid + rep * 512;
    int rv2 = __brev((unsigned)n) >> 22;
    int p = ((rv2 & 0x155) << 1) | ((rv2 >> 1) & 0x155);   // base-4 digit reversal
    float fr[8], fi[8];
#pragma unroll
    for (int ds = 0; ds < 8; ++ds) {
      fr[ds] = lr[LIDX(ds, p)] * oscale;
      fi[ds] = li[LIDX(ds, p)] * oscale;
    }
    if (omode == 1) {
      size_t tb = (size_t)(n >> 5) * 4096;
#pragma unroll
      for (int ds = 0; ds < 8; ++ds) {
        int dch = dc * 8 + ds;
        size_t ga = tb + (size_t)dch * 32 + ((n & 31) ^ (((dch >> 1) & 3) << 3));
        oRb[ga] = (bf16_t)fr[ds];
        oIb[ga] = (bf16_t)fi[ds];
      }
    } else {
      int cb = dc * 8;
      if (omode == 2) cb = (dc ^ (n & 7)) * 8;
      bf16x8 v0, w0;
#pragma unroll
      for (int k = 0; k < 8; ++k) {
        v0[k] = (bf16_t)fr[k];
        w0[k] = (bf16_t)fi[k];
      }
      size_t gb = (size_t)n * out_sn + cb;
      *(bf16x8*)(oRb + gb) = v0;
      *(bf16x8*)(oIb + gb) = w0;
    }
  }
}

// ============================================================
// Flash attention v6 (unchanged from round 10/11 — control).
// ============================================================
__global__ __launch_bounds__(256, 2) void fattn(
    const bf16_t* __restrict__ Qf, const bf16_t* __restrict__ Kfs,
    const bf16_t* __restrict__ Vfs, float* __restrict__ OT)
{
  __shared__ bf16_t K2[2][4096];
  __shared__ bf16_t V2[2][4096];
  const int tid = threadIdx.x;
  const int w = tid >> 6, l = tid & 63;
  const int lq = l & 31;
  const int h = l >> 5;
  const int i = blockIdx.x;
  const int j = i >> 3;
  const int bh = (i & 7) * 8 + (j >> 3);
  const int q0 = (j & 7) * 128 + w * 32;

  bf16x8 bq[8];
  const bf16_t* qp = Qf + ((size_t)bh * NN + q0 + lq) * 128 + h * 8;
#pragma unroll
  for (int kk = 0; kk < 8; ++kk) bq[kk] = *(const bf16x8*)(qp + kk * 16);

  f32x16 o[4] = {};
  float m = -3e38f, ln = 0.f;

  const bf16_t* kg = Kfs + (size_t)bh * 131072 + w * 1024 + l * 8;
  const bf16_t* vg = Vfs + (size_t)bh * 131072 + w * 1024 + l * 8;
  const int kswz = (lq & 7) << 3;
  const int vswz = ((lq >> 1) & 3) << 3;

#pragma unroll
  for (int ii = 0; ii < 2; ++ii) {
    __builtin_amdgcn_global_load_lds((const AS1 void*)(kg + ii * 512),
                                     (AS3 void*)&K2[0][w * 1024 + ii * 512], 16, 0, 0);
    __builtin_amdgcn_global_load_lds((const AS1 void*)(vg + ii * 512),
                                     (AS3 void*)&V2[0][w * 1024 + ii * 512], 16, 0, 0);
  }
  __syncthreads();

  int cur = 0;
  for (int t = 0; t < 32; ++t) {
    if (t < 31) {
      const bf16_t* kt = kg + (size_t)(t + 1) * 4096;
      const bf16_t* vt = vg + (size_t)(t + 1) * 4096;
#pragma unroll
      for (int ii = 0; ii < 2; ++ii) {
        __builtin_amdgcn_global_load_lds((const AS1 void*)(kt + ii * 512),
                                         (AS3 void*)&K2[cur ^ 1][w * 1024 + ii * 512], 16, 0, 0);
        __builtin_amdgcn_global_load_lds((const AS1 void*)(vt + ii * 512),
                                         (AS3 void*)&V2[cur ^ 1][w * 1024 + ii * 512], 16, 0, 0);
      }
    }

    f32x16 s = {};
#pragma unroll
    for (int kk = 0; kk < 8; ++kk) {
      bf16x8 ak = *(const bf16x8*)&K2[cur][lq * 128 + ((kk * 16 + h * 8) ^ kswz)];
      s = MFMA32(ak, bq[kk], s);
    }

    float pmax = s[0];
#pragma unroll
    for (int r = 1; r < 16; ++r) pmax = fmaxf(pmax, s[r]);
    pmax = fmaxf(pmax, __shfl_xor(pmax, 32));
    if (!__all(pmax - m <= 8.f)) {
      float mnew = fmaxf(m, pmax);
      float alpha = __expf(m - mnew);
      m = mnew;
      ln *= alpha;
#pragma unroll
      for (int db = 0; db < 4; ++db)
#pragma unroll
        for (int r = 0; r < 16; ++r) o[db][r] *= alpha;
    }
    float pf[16];
    float rs = 0.f;
#pragma unroll
    for (int r = 0; r < 16; ++r) { pf[r] = __expf(s[r] - m); rs += pf[r]; }
    rs += __shfl_xor(rs, 32);
    ln += rs;

    unsigned pw[8];
#pragma unroll
    for (int ii = 0; ii < 8; ++ii) pw[ii] = pk2(pf[2 * ii], pf[2 * ii + 1]);
    unsigned r0 = (unsigned)__shfl_xor((int)(h ? pw[0] : pw[2]), 32);
    unsigned r1 = (unsigned)__shfl_xor((int)(h ? pw[1] : pw[3]), 32);
    unsigned r2 = (unsigned)__shfl_xor((int)(h ? pw[4] : pw[6]), 32);
    unsigned r3 = (unsigned)__shfl_xor((int)(h ? pw[5] : pw[7]), 32);
    U16 bp0, bp1;
    bp0.u.x = h ? r0 : pw[0];  bp0.u.y = h ? r1 : pw[1];
    bp0.u.z = h ? pw[2] : r0;  bp0.u.w = h ? pw[3] : r1;
    bp1.u.x = h ? r2 : pw[4];  bp1.u.y = h ? r3 : pw[5];
    bp1.u.z = h ? pw[6] : r2;  bp1.u.w = h ? pw[7] : r3;

#pragma unroll
    for (int db = 0; db < 4; ++db) {
      int r = db * 32 + lq;
      bf16x8 av0 = *(const bf16x8*)&V2[cur][r * 32 + ((h * 8) ^ vswz)];
      bf16x8 av1 = *(const bf16x8*)&V2[cur][r * 32 + ((16 + h * 8) ^ vswz)];
      o[db] = MFMA32(av0, bp0.v, o[db]);
      o[db] = MFMA32(av1, bp1.v, o[db]);
    }

    __syncthreads();
    cur ^= 1;
  }

  float inv = 1.f / ln;
  const size_t otb = (size_t)bh * 128 * NN + q0 + lq;
#pragma unroll
  for (int db = 0; db < 4; ++db)
#pragma unroll
    for (int r = 0; r < 16; ++r) {
      int dl = (r & 3) + 8 * (r >> 2) + 4 * h;
      OT[otb + (size_t)(db * 32 + dl) * NN] = o[db][r] * inv;
    }
}

// ============================================================
// Host-side orchestration
// ============================================================
extern "C" void kernel_launch(void* const* d_in, const int* in_sizes, int n_in,
                              void* d_out, int out_size, void* d_ws, size_t ws_size,
                              hipStream_t stream) {
  const float* xr   = (const float*)d_in[0];
  const float* xi   = (const float*)d_in[1];
  const float* Wqr  = (const float*)d_in[2];
  const float* Wqi  = (const float*)d_in[3];
  const float* bqr  = (const float*)d_in[4];
  const float* bqi  = (const float*)d_in[5];
  const float* Wkr  = (const float*)d_in[6];
  const float* Wki  = (const float*)d_in[7];
  const float* bkr  = (const float*)d_in[8];
  const float* bki  = (const float*)d_in[9];
  const float* Wvr  = (const float*)d_in[10];
  const float* Wvi  = (const float*)d_in[11];
  const float* bvr  = (const float*)d_in[12];
  const float* bvi  = (const float*)d_in[13];
  const float* Wor  = (const float*)d_in[14];
  const float* Woi  = (const float*)d_in[15];
  const float* bor  = (const float*)d_in[16];
  const float* boi  = (const float*)d_in[17];
  const float* gq   = (const float*)d_in[18];
  const float* beq  = (const float*)d_in[19];
  const float* gk   = (const float*)d_in[20];
  const float* bek  = (const float*)d_in[21];
  const float* gv   = (const float*)d_in[22];
  const float* bev  = (const float*)d_in[23];

  char* wp = (char*)d_ws;
  bf16_t* Axaug = (bf16_t*)wp;  wp += (size_t)4096 * 2048 * 2;
  bf16_t* Wcat  = (bf16_t*)wp;  wp += (size_t)2048 * 2048 * 2;
  float*  bcat  = (float*)wp;   wp += (size_t)2048 * 4;
  float2* lnst  = (float2*)wp;  wp += (size_t)4096 * 8;
  float*  Ar    = (float*)wp;   wp += (size_t)4096 * 1024 * 4;
  float*  Ai    = (float*)wp;   wp += (size_t)4096 * 1024 * 4;
  bf16_t* Qf    = (bf16_t*)wp;  wp += (size_t)64 * 1024 * 128 * 2;
  bf16_t* Kf    = (bf16_t*)wp;  wp += (size_t)64 * 1024 * 128 * 2;
  bf16_t* VfT   = (bf16_t*)wp;  wp += (size_t)64 * 1024 * 128 * 2;
  bf16_t* Yaug  = Qf;
  float*  OT    = Ar;   // attn output O^T [BH,128,N] fp32 (spans Ar+Ai)

  const dim3 gGemm(16, 32);
  const int gPackX = (4096 * 2048 / 8) / 256;
  const int gPackW = (2048 * 2048 / 8) / 256;
  const int gFft = 64 * 8;           // bh x 8 d-chunks of 8
  const int gAtt = 64 * 8;

  pack_x<<<gPackX, 256, 0, stream>>>(xr, xi, Axaug);

  // ---- Q (FFT output scale folds in the 1/8 attention scale; LN fused) ----
  pack_w<<<gPackW, 256, 0, stream>>>(Wqr, Wqi, bqr, bqi, Wcat, bcat);
  gemm_bf16<<<gGemm, 256, 0, stream>>>(Axaug, Wcat, bcat, Ar, Ai, 1024);
  ln_stats<<<BN, 256, 0, stream>>>(Ar, Ai, lnst);
  fft_kernel<<<gFft, 512, 0, stream>>>(Ar, Ai, Qf, Qf + 64,
      NN * DIMM, DHH, DIMM, 1,
      16 * NN * 128, NN * 128, 128,
      -1.0f, 0.03125f * 0.125f, 0, 0, lnst, gq, beq);
  // ---- K (row-major + XOR pre-swizzle) ----
  pack_w<<<gPackW, 256, 0, stream>>>(Wkr, Wki, bkr, bki, Wcat, bcat);
  gemm_bf16<<<gGemm, 256, 0, stream>>>(Axaug, Wcat, bcat, Ar, Ai, 1024);
  ln_stats<<<BN, 256, 0, stream>>>(Ar, Ai, lnst);
  fft_kernel<<<gFft, 512, 0, stream>>>(Ar, Ai, Kf, Kf + 64,
      NN * DIMM, DHH, DIMM, 1,
      16 * NN * 128, NN * 128, 128,
      -1.0f, 0.03125f, 0, 2, lnst, gk, bek);
  // ---- V (kv-tile-blocked + XOR pre-swizzle) ----
  pack_w<<<gPackW, 256, 0, stream>>>(Wvr, Wvi, bvr, bvi, Wcat, bcat);
  gemm_bf16<<<gGemm, 256, 0, stream>>>(Axaug, Wcat, bcat, Ar, Ai, 1024);
  ln_stats<<<BN, 256, 0, stream>>>(Ar, Ai, lnst);
  fft_kernel<<<gFft, 512, 0, stream>>>(Ar, Ai, VfT, VfT + 2048,
      NN * DIMM, DHH, DIMM, 1,
      16 * 131072, 131072, 0,
      -1.0f, 0.03125f, 0, 1, lnst, gv, bev);
  // ---- flash attention -> OT [BH,128,N] fp32 ----
  fattn<<<gAtt, 256, 0, stream>>>(Qf, Kf, VfT, OT);
  // ---- inverse FFT: OT (d-major, n-contiguous reads) -> Yaug ----
  fft_kernel<<<gFft, 512, 0, stream>>>(OT, OT + (size_t)64 * NN, Yaug, Yaug + 1024,
      16 * 128 * NN, 128 * NN, 1, NN,
      NN * 2048, 64, 2048,
      +1.0f, 0.03125f, 1, 0, nullptr, nullptr, nullptr);
  // ---- output projection straight into d_out ----
  float* yout = (float*)d_out;
  pack_w<<<gPackW, 256, 0, stream>>>(Wor, Woi, bor, boi, Wcat, bcat);
  gemm_bf16<<<gGemm, 256, 0, stream>>>(Yaug, Wcat, bcat, yout, yout + 1024, 2048);
}

// Round 13
// 431.433 us; speedup vs baseline: 1.5078x; 1.0006x over previous
//
#include <hip/hip_runtime.h>
#include <math.h>

#define BB 4
#define NN 1024
#define DIMM 1024
#define HHH 16
#define DHH 64
#define BN 4096            // B*N rows
#define EPS_LN 1e-6f

typedef __bf16 bf16_t;
typedef __bf16 bf16x8 __attribute__((ext_vector_type(8)));
typedef float f32x4 __attribute__((ext_vector_type(4)));
typedef float f32x16 __attribute__((ext_vector_type(16)));
#define MFMA16(a, b, c) __builtin_amdgcn_mfma_f32_16x16x32_bf16(a, b, c, 0, 0, 0)
#define MFMA32(a, b, c) __builtin_amdgcn_mfma_f32_32x32x16_bf16(a, b, c, 0, 0, 0)
#define AS1 __attribute__((address_space(1)))
#define AS3 __attribute__((address_space(3)))

__device__ inline unsigned pk2(float a, float b) {
  union { bf16_t h[2]; unsigned u; } c;
  c.h[0] = (bf16_t)a; c.h[1] = (bf16_t)b;
  return c.u;
}
union U16 { uint4 u; bf16x8 v; };

// ============================================================
// pack_x: Axaug[4096][2048] = bf16([xr | xi])
// ============================================================
__global__ __launch_bounds__(256) void pack_x(
    const float* __restrict__ xr, const float* __restrict__ xi,
    bf16_t* __restrict__ out)
{
  int t = blockIdx.x * 256 + threadIdx.x;
  size_t e = (size_t)t * 8;
  int row = (int)(e >> 11), col = (int)(e & 2047);
  const float* src = (col < 1024) ? (xr + (size_t)row * 1024 + col)
                                  : (xi + (size_t)row * 1024 + col - 1024);
  float4 a = *(const float4*)src;
  float4 b = *(const float4*)(src + 4);
  bf16x8 o;
  o[0] = (bf16_t)a.x; o[1] = (bf16_t)a.y; o[2] = (bf16_t)a.z; o[3] = (bf16_t)a.w;
  o[4] = (bf16_t)b.x; o[5] = (bf16_t)b.y; o[6] = (bf16_t)b.z; o[7] = (bf16_t)b.w;
  *(bf16x8*)(out + e) = o;
}

// ============================================================
// pack_w: Wcat[2048][2048]: rows 0-1023 = [Wr | -Wi], rows 1024-2047 = [Wi | Wr]
// ============================================================
__global__ __launch_bounds__(256) void pack_w(
    const float* __restrict__ Wr, const float* __restrict__ Wi,
    const float* __restrict__ br, const float* __restrict__ bi,
    bf16_t* __restrict__ Wcat, float* __restrict__ bcat)
{
  int t = blockIdx.x * 256 + threadIdx.x;
  size_t e = (size_t)t * 8;
  int row = (int)(e >> 11), col = (int)(e & 2047);
  const float* src;
  float sgn = 1.f;
  if (row < 1024) {
    if (col < 1024) src = Wr + (size_t)row * 1024 + col;
    else          { src = Wi + (size_t)row * 1024 + col - 1024; sgn = -1.f; }
  } else {
    int r2 = row - 1024;
    if (col < 1024) src = Wi + (size_t)r2 * 1024 + col;
    else            src = Wr + (size_t)r2 * 1024 + col - 1024;
  }
  float4 a = *(const float4*)src;
  float4 b = *(const float4*)(src + 4);
  bf16x8 o;
  o[0] = (bf16_t)(sgn * a.x); o[1] = (bf16_t)(sgn * a.y);
  o[2] = (bf16_t)(sgn * a.z); o[3] = (bf16_t)(sgn * a.w);
  o[4] = (bf16_t)(sgn * b.x); o[5] = (bf16_t)(sgn * b.y);
  o[6] = (bf16_t)(sgn * b.z); o[7] = (bf16_t)(sgn * b.w);
  *(bf16x8*)(Wcat + e) = o;
  if (e < 2048) {
#pragma unroll
    for (int j = 0; j < 8; ++j) {
      int n = (int)e + j;
      bcat[n] = (n < 1024) ? br[n] : bi[n - 1024];
    }
  }
}

// ============================================================
// bf16 MFMA GEMM (NT), m97 structure (unchanged).
// ============================================================
__global__ __launch_bounds__(256) void gemm_bf16(
    const bf16_t* __restrict__ A, const bf16_t* __restrict__ Bt,
    const float* __restrict__ bias,
    float* __restrict__ Cr, float* __restrict__ Ci, int ldc)
{
  __shared__ bf16_t sA[128 * 64];
  __shared__ bf16_t sB[128 * 64];
  const int tid = threadIdx.x;
  const int w = tid >> 6, l = tid & 63;
  const int lo4 = l & 15, hi = l >> 4;
  const int wr = w >> 1, wc = w & 1;
  const int row0 = blockIdx.y * 128, col0 = blockIdx.x * 128;

  const int srow = (l >> 3);
  const int scol = (l & 7) * 8;
  const bf16_t* gA[4];
  const bf16_t* gB[4];
#pragma unroll
  for (int i = 0; i < 4; ++i) {
    int r = (w * 4 + i) * 8 + srow;
    gA[i] = A  + (size_t)(row0 + r) * 2048 + scol;
    gB[i] = Bt + (size_t)(col0 + r) * 2048 + scol;
  }

  f32x4 acc[4][4] = {};
  for (int k0 = 0; k0 < 2048; k0 += 64) {
    __syncthreads();
#pragma unroll
    for (int i = 0; i < 4; ++i) {
      __builtin_amdgcn_global_load_lds((const AS1 void*)(gA[i] + k0),
                                       (AS3 void*)&sA[(w * 4 + i) * 512], 16, 0, 0);
      __builtin_amdgcn_global_load_lds((const AS1 void*)(gB[i] + k0),
                                       (AS3 void*)&sB[(w * 4 + i) * 512], 16, 0, 0);
    }
    __syncthreads();
#pragma unroll
    for (int kk = 0; kk < 2; ++kk) {
      bf16x8 am[4], bn[4];
#pragma unroll
      for (int i = 0; i < 4; ++i)
        am[i] = *(const bf16x8*)&sA[(wr * 64 + i * 16 + lo4) * 64 + kk * 32 + hi * 8];
#pragma unroll
      for (int j = 0; j < 4; ++j)
        bn[j] = *(const bf16x8*)&sB[(wc * 64 + j * 16 + lo4) * 64 + kk * 32 + hi * 8];
#pragma unroll
      for (int i = 0; i < 4; ++i)
#pragma unroll
        for (int j = 0; j < 4; ++j)
          acc[i][j] = MFMA16(am[i], bn[j], acc[i][j]);
    }
  }
  const int colg0 = col0 + wc * 64;
  float* Cp = (colg0 < 1024) ? Cr : Ci;
  const int cb = colg0 & 1023;
#pragma unroll
  for (int i = 0; i < 4; ++i) {
#pragma unroll
    for (int j = 0; j < 4; ++j) {
      float bv = bias[colg0 + j * 16 + lo4];
#pragma unroll
      for (int r = 0; r < 4; ++r) {
        int rowg = row0 + wr * 64 + i * 16 + hi * 4 + r;
        Cp[(size_t)rowg * ldc + cb + j * 16 + lo4] = acc[i][j][r] + bv;
      }
    }
  }
}

// ============================================================
// LN row stats (unchanged)
// ============================================================
__global__ __launch_bounds__(256) void ln_stats(
    const float* __restrict__ re, const float* __restrict__ im,
    float2* __restrict__ st)
{
  __shared__ float red[8];
  const int row = blockIdx.x;
  const int tid = threadIdx.x;
  const float* pr = re + (size_t)row * DIMM;
  const float* pi = im + (size_t)row * DIMM;
  float s = 0.f, s2 = 0.f;
#pragma unroll
  for (int t = 0; t < 4; ++t) {
    int c = tid + t * 256;
    float vr = pr[c], vi = pi[c];
    float mg = sqrtf(vr * vr + vi * vi);
    s += mg; s2 += mg * mg;
  }
#pragma unroll
  for (int o = 32; o; o >>= 1) { s += __shfl_down(s, o); s2 += __shfl_down(s2, o); }
  if ((tid & 63) == 0) { red[tid >> 6] = s; red[4 + (tid >> 6)] = s2; }
  __syncthreads();
  if (tid == 0) {
    float S = red[0] + red[1] + red[2] + red[3];
    float S2 = red[4] + red[5] + red[6] + red[7];
    float mean = S * (1.f / DIMM);
    float var = S2 * (1.f / DIMM) - mean * mean;
    st[row] = make_float2(mean, rsqrtf(var + EPS_LN));
  }
}

// ============================================================
// 1024-pt RADIX-4 DIF FFT v3 (unchanged from round 12).
// ============================================================
#define LIDX(d_, c_) (((d_) << 10) + ((c_) ^ (((c_) >> 5) & 31) ^ (((d_) & 7) << 2)))

__global__ __launch_bounds__(512) void fft_kernel(
    const float* __restrict__ inR, const float* __restrict__ inI,
    bf16_t* __restrict__ outR, bf16_t* __restrict__ outI,
    int in_sb, int in_sh, int in_sn, int in_sd,
    int out_sb, int out_sh, int out_sn,
    float sign, float oscale, int imode, int omode,
    const float2* __restrict__ stats,
    const float* __restrict__ gamma, const float* __restrict__ beta)
{
  __shared__ float lr[8 * 1024], li[8 * 1024];
  __shared__ float2 tw[1024];
  const int tid = threadIdx.x;
  const int dc = blockIdx.x & 7;          // 8 chunks of 8 d
  const int bh = blockIdx.x >> 3;
  const int b = bh >> 4, h = bh & 15;
  const float* bR = inR + (size_t)b * in_sb + (size_t)h * in_sh;
  const float* bI = inI + (size_t)b * in_sb + (size_t)h * in_sh;
#pragma unroll
  for (int t = tid; t < 1024; t += 512) {
    float ang = sign * 3.14159265358979323846f * (float)t * (1.f / 512.f);
    float sn, cs;
    __sincosf(ang, &sn, &cs);
    tw[t] = make_float2(cs, sn);
  }
  // ---- load (+ optional fused LN) ----
  if (imode == 0) {
    float gg[8], bb[8];
    if (stats) {
#pragma unroll
      for (int ds = 0; ds < 8; ++ds) {
        gg[ds] = gamma[h * DHH + dc * 8 + ds];
        bb[ds] = beta[h * DHH + dc * 8 + ds];
      }
    }
#pragma unroll
    for (int rep = 0; rep < 2; ++rep) {
      int n = tid + rep * 512;
      const float* pR = bR + (size_t)n * in_sn + dc * 8;
      const float* pI = bI + (size_t)n * in_sn + dc * 8;
      union { float4 q[2]; float f[8]; } ur, ui;
      ur.q[0] = *(const float4*)pR;      ur.q[1] = *(const float4*)(pR + 4);
      ui.q[0] = *(const float4*)pI;      ui.q[1] = *(const float4*)(pI + 4);
      if (stats) {
        float2 stv = stats[b * NN + n];
#pragma unroll
        for (int ds = 0; ds < 8; ++ds) {
          float a = ur.f[ds], c2 = ui.f[ds];
          float mag = sqrtf(a * a + c2 * c2);
          float nm = (mag - stv.x) * stv.y * gg[ds] + bb[ds];
          if (mag > 0.f) { float sc = nm / mag; ur.f[ds] = a * sc; ui.f[ds] = c2 * sc; }
          else           { ur.f[ds] = nm; ui.f[ds] = 0.f; }
        }
      }
#pragma unroll
      for (int ds = 0; ds < 8; ++ds) {
        int ax = LIDX(ds, n);
        lr[ax] = ur.f[ds];
        li[ax] = ui.f[ds];
      }
    }
  } else {
    const int ds = tid & 7, nb = tid >> 3;   // nb 0..63
    const float* pR = bR + (size_t)(dc * 8 + ds) * in_sd + nb * 16;
    const float* pI = bI + (size_t)(dc * 8 + ds) * in_sd + nb * 16;
#pragma unroll
    for (int k = 0; k < 16; k += 4) {
      float4 v = *(const float4*)(pR + k);
      float4 w = *(const float4*)(pI + k);
      int c = nb * 16 + k;
      lr[LIDX(ds, c + 0)] = v.x;  li[LIDX(ds, c + 0)] = w.x;
      lr[LIDX(ds, c + 1)] = v.y;  li[LIDX(ds, c + 1)] = w.y;
      lr[LIDX(ds, c + 2)] = v.z;  li[LIDX(ds, c + 2)] = w.z;
      lr[LIDX(ds, c + 3)] = v.w;  li[LIDX(ds, c + 3)] = w.w;
    }
  }
  __syncthreads();
  // ---- 5 radix-4 DIF stages ----
  const int dsub = tid & 7;
  const int jb = tid >> 3;                 // 0..63
  int lq2 = 8;
  for (int st = 0; st < 5; ++st) {
    const int qtr = 1 << lq2;
    const int tmul = 1 << (2 * st);
    for (int jt = 0; jt < 4; ++jt) {
      int j = jb + jt * 64;                // 0..255
      int o = j & (qtr - 1);
      int i0 = ((j >> lq2) << (lq2 + 2)) + o;
      int a0 = LIDX(dsub, i0);
      int a1 = LIDX(dsub, i0 + qtr);
      int a2 = LIDX(dsub, i0 + 2 * qtr);
      int a3 = LIDX(dsub, i0 + 3 * qtr);
      float x0r = lr[a0], x0i = li[a0];
      float x1r = lr[a1], x1i = li[a1];
      float x2r = lr[a2], x2i = li[a2];
      float x3r = lr[a3], x3i = li[a3];
      float ar = x0r + x2r, ai2 = x0i + x2i;
      float br = x0r - x2r, bi  = x0i - x2i;
      float cr = x1r + x3r, ci  = x1i + x3i;
      float dr = x1r - x3r, di  = x1i - x3i;
      float2 t1 = tw[o * tmul];
      float2 t2 = tw[2 * o * tmul];
      float2 t3 = tw[3 * o * tmul];
      lr[a0] = ar + cr;  li[a0] = ai2 + ci;
      float u1r = br - sign * di, u1i = bi + sign * dr;
      lr[a1] = u1r * t1.x - u1i * t1.y;  li[a1] = u1r * t1.y + u1i * t1.x;
      float u2r = ar - cr, u2i = ai2 - ci;
      lr[a2] = u2r * t2.x - u2i * t2.y;  li[a2] = u2r * t2.y + u2i * t2.x;
      float u3r = br + sign * di, u3i = bi - sign * dr;
      lr[a3] = u3r * t3.x - u3i * t3.y;  li[a3] = u3r * t3.y + u3i * t3.x;
    }
    __syncthreads();
    lq2 -= 2;
  }
  // ---- store (base-4 digit reversal folded into LDS read) ----
  bf16_t* oRb = outR + (size_t)b * out_sb + (size_t)h * out_sh;
  bf16_t* oIb = outI + (size_t)b * out_sb + (size_t)h * out_sh;
#pragma unroll
  for (int rep = 0; rep < 2; ++rep) {
    int n = tid + rep * 512;
    int rv2 = __brev((unsigned)n) >> 22;
    int p = ((rv2 & 0x155) << 1) | ((rv2 >> 1) & 0x155);   // base-4 digit reversal
    float fr[8], fi[8];
#pragma unroll
    for (int ds = 0; ds < 8; ++ds) {
      fr[ds] = lr[LIDX(ds, p)] * oscale;
      fi[ds] = li[LIDX(ds, p)] * oscale;
    }
    if (omode == 1) {
      size_t tb = (size_t)(n >> 5) * 4096;
#pragma unroll
      for (int ds = 0; ds < 8; ++ds) {
        int dch = dc * 8 + ds;
        size_t ga = tb + (size_t)dch * 32 + ((n & 31) ^ (((dch >> 1) & 3) << 3));
        oRb[ga] = (bf16_t)fr[ds];
        oIb[ga] = (bf16_t)fi[ds];
      }
    } else {
      int cb = dc * 8;
      if (omode == 2) cb = (dc ^ (n & 7)) * 8;
      bf16x8 v0, w0;
#pragma unroll
      for (int k = 0; k < 8; ++k) {
        v0[k] = (bf16_t)fr[k];
        w0[k] = (bf16_t)fi[k];
      }
      size_t gb = (size_t)n * out_sn + cb;
      *(bf16x8*)(oRb + gb) = v0;
      *(bf16x8*)(oIb + gb) = w0;
    }
  }
}

// ============================================================
// Flash attention v7: LDS-staged K/V with COUNTED-vmcnt pipeline
// (T3/T4). 3 buffers, prefetch depth 2. Per tile: issue stage(t+2)
// -> compute(t) -> s_waitcnt vmcnt(4) (own t+1 loads landed; t+2's
// stay in flight ACROSS the barrier) -> raw s_barrier. Each wave
// waits for its own quarter before the barrier => after the barrier
// all waves' t+1 data is resident. Writes to buf (t+2)%3 begin only
// after the barrier that ended all reads of that buffer.
// ============================================================
__global__ __launch_bounds__(256, 2) void fattn(
    const bf16_t* __restrict__ Qf, const bf16_t* __restrict__ Kfs,
    const bf16_t* __restrict__ Vfs, float* __restrict__ OT)
{
  __shared__ bf16_t K3[3][4096];
  __shared__ bf16_t V3[3][4096];
  const int tid = threadIdx.x;
  const int w = tid >> 6, l = tid & 63;
  const int lq = l & 31;
  const int h = l >> 5;
  const int i = blockIdx.x;
  const int j = i >> 3;
  const int bh = (i & 7) * 8 + (j >> 3);   // XCD-locality swizzle
  const int q0 = (j & 7) * 128 + w * 32;

  bf16x8 bq[8];
  const bf16_t* qp = Qf + ((size_t)bh * NN + q0 + lq) * 128 + h * 8;
#pragma unroll
  for (int kk = 0; kk < 8; ++kk) bq[kk] = *(const bf16x8*)(qp + kk * 16);

  f32x16 o[4] = {};
  float m = -3e38f, ln = 0.f;

  const bf16_t* kg = Kfs + (size_t)bh * 131072 + w * 1024 + l * 8;
  const bf16_t* vg = Vfs + (size_t)bh * 131072 + w * 1024 + l * 8;
  const int kswz = (lq & 7) << 3;
  const int vswz = ((lq >> 1) & 3) << 3;

  // prologue: stage tiles 0,1 into bufs 0,1 (K0,V0,K1,V1 x2 = 8 loads)
#pragma unroll
  for (int tt = 0; tt < 2; ++tt) {
    const bf16_t* kt = kg + (size_t)tt * 4096;
    const bf16_t* vt = vg + (size_t)tt * 4096;
#pragma unroll
    for (int ii = 0; ii < 2; ++ii) {
      __builtin_amdgcn_global_load_lds((const AS1 void*)(kt + ii * 512),
                                       (AS3 void*)&K3[tt][w * 1024 + ii * 512], 16, 0, 0);
      __builtin_amdgcn_global_load_lds((const AS1 void*)(vt + ii * 512),
                                       (AS3 void*)&V3[tt][w * 1024 + ii * 512], 16, 0, 0);
    }
  }
  asm volatile("s_waitcnt vmcnt(4)" ::: "memory");   // tile 0 resident
  __builtin_amdgcn_s_barrier();
  __builtin_amdgcn_sched_barrier(0);

  int cur = 0;
  for (int t = 0; t < 32; ++t) {
    // ---- issue stage(t+2) into buf (cur+2)%3 (stays in flight) ----
    if (t < 30) {
      int nb = cur + 2; if (nb >= 3) nb -= 3;
      const bf16_t* kt = kg + (size_t)(t + 2) * 4096;
      const bf16_t* vt = vg + (size_t)(t + 2) * 4096;
#pragma unroll
      for (int ii = 0; ii < 2; ++ii) {
        __builtin_amdgcn_global_load_lds((const AS1 void*)(kt + ii * 512),
                                         (AS3 void*)&K3[nb][w * 1024 + ii * 512], 16, 0, 0);
        __builtin_amdgcn_global_load_lds((const AS1 void*)(vt + ii * 512),
                                         (AS3 void*)&V3[nb][w * 1024 + ii * 512], 16, 0, 0);
      }
    }

    // ---- S^T[k][q]: K frags from LDS (swizzled), Q in registers ----
    f32x16 s = {};
#pragma unroll
    for (int kk = 0; kk < 8; ++kk) {
      bf16x8 ak = *(const bf16x8*)&K3[cur][lq * 128 + ((kk * 16 + h * 8) ^ kswz)];
      s = MFMA32(ak, bq[kk], s);
    }

    // ---- online softmax with defer-max (THR=8) ----
    float pmax = s[0];
#pragma unroll
    for (int r = 1; r < 16; ++r) pmax = fmaxf(pmax, s[r]);
    pmax = fmaxf(pmax, __shfl_xor(pmax, 32));
    if (!__all(pmax - m <= 8.f)) {
      float mnew = fmaxf(m, pmax);
      float alpha = __expf(m - mnew);
      m = mnew;
      ln *= alpha;
#pragma unroll
      for (int db = 0; db < 4; ++db)
#pragma unroll
        for (int r = 0; r < 16; ++r) o[db][r] *= alpha;
    }
    float pf[16];
    float rs = 0.f;
#pragma unroll
    for (int r = 0; r < 16; ++r) { pf[r] = __expf(s[r] - m); rs += pf[r]; }
    rs += __shfl_xor(rs, 32);
    ln += rs;

    // ---- P -> bf16; 4 select-shuffles across lane halves ----
    unsigned pw[8];
#pragma unroll
    for (int ii = 0; ii < 8; ++ii) pw[ii] = pk2(pf[2 * ii], pf[2 * ii + 1]);
    unsigned r0 = (unsigned)__shfl_xor((int)(h ? pw[0] : pw[2]), 32);
    unsigned r1 = (unsigned)__shfl_xor((int)(h ? pw[1] : pw[3]), 32);
    unsigned r2 = (unsigned)__shfl_xor((int)(h ? pw[4] : pw[6]), 32);
    unsigned r3 = (unsigned)__shfl_xor((int)(h ? pw[5] : pw[7]), 32);
    U16 bp0, bp1;
    bp0.u.x = h ? r0 : pw[0];  bp0.u.y = h ? r1 : pw[1];
    bp0.u.z = h ? pw[2] : r0;  bp0.u.w = h ? pw[3] : r1;
    bp1.u.x = h ? r2 : pw[4];  bp1.u.y = h ? r3 : pw[5];
    bp1.u.z = h ? pw[6] : r2;  bp1.u.w = h ? pw[7] : r3;

    // ---- PV: V frags from LDS (swizzled) ----
#pragma unroll
    for (int db = 0; db < 4; ++db) {
      int r = db * 32 + lq;
      bf16x8 av0 = *(const bf16x8*)&V3[cur][r * 32 + ((h * 8) ^ vswz)];
      bf16x8 av1 = *(const bf16x8*)&V3[cur][r * 32 + ((16 + h * 8) ^ vswz)];
      o[db] = MFMA32(av0, bp0.v, o[db]);
      o[db] = MFMA32(av1, bp1.v, o[db]);
    }

    // ---- counted wait + raw barrier: t+2's loads stay in flight ----
    if (t < 31) {
      if (t < 30) asm volatile("s_waitcnt vmcnt(4)" ::: "memory");
      else        asm volatile("s_waitcnt vmcnt(0)" ::: "memory");
      __builtin_amdgcn_s_barrier();
      __builtin_amdgcn_sched_barrier(0);
    }
    cur = (cur == 2) ? 0 : cur + 1;
  }

  // ---- normalize + coalesced O^T store ----
  float inv = 1.f / ln;
  const size_t otb = (size_t)bh * 128 * NN + q0 + lq;
#pragma unroll
  for (int db = 0; db < 4; ++db)
#pragma unroll
    for (int r = 0; r < 16; ++r) {
      int dl = (r & 3) + 8 * (r >> 2) + 4 * h;
      OT[otb + (size_t)(db * 32 + dl) * NN] = o[db][r] * inv;
    }
}

// ============================================================
// Host-side orchestration
// ============================================================
extern "C" void kernel_launch(void* const* d_in, const int* in_sizes, int n_in,
                              void* d_out, int out_size, void* d_ws, size_t ws_size,
                              hipStream_t stream) {
  const float* xr   = (const float*)d_in[0];
  const float* xi   = (const float*)d_in[1];
  const float* Wqr  = (const float*)d_in[2];
  const float* Wqi  = (const float*)d_in[3];
  const float* bqr  = (const float*)d_in[4];
  const float* bqi  = (const float*)d_in[5];
  const float* Wkr  = (const float*)d_in[6];
  const float* Wki  = (const float*)d_in[7];
  const float* bkr  = (const float*)d_in[8];
  const float* bki  = (const float*)d_in[9];
  const float* Wvr  = (const float*)d_in[10];
  const float* Wvi  = (const float*)d_in[11];
  const float* bvr  = (const float*)d_in[12];
  const float* bvi  = (const float*)d_in[13];
  const float* Wor  = (const float*)d_in[14];
  const float* Woi  = (const float*)d_in[15];
  const float* bor  = (const float*)d_in[16];
  const float* boi  = (const float*)d_in[17];
  const float* gq   = (const float*)d_in[18];
  const float* beq  = (const float*)d_in[19];
  const float* gk   = (const float*)d_in[20];
  const float* bek  = (const float*)d_in[21];
  const float* gv   = (const float*)d_in[22];
  const float* bev  = (const float*)d_in[23];

  char* wp = (char*)d_ws;
  bf16_t* Axaug = (bf16_t*)wp;  wp += (size_t)4096 * 2048 * 2;
  bf16_t* Wcat  = (bf16_t*)wp;  wp += (size_t)2048 * 2048 * 2;
  float*  bcat  = (float*)wp;   wp += (size_t)2048 * 4;
  float2* lnst  = (float2*)wp;  wp += (size_t)4096 * 8;
  float*  Ar    = (float*)wp;   wp += (size_t)4096 * 1024 * 4;
  float*  Ai    = (float*)wp;   wp += (size_t)4096 * 1024 * 4;
  bf16_t* Qf    = (bf16_t*)wp;  wp += (size_t)64 * 1024 * 128 * 2;
  bf16_t* Kf    = (bf16_t*)wp;  wp += (size_t)64 * 1024 * 128 * 2;
  bf16_t* VfT   = (bf16_t*)wp;  wp += (size_t)64 * 1024 * 128 * 2;
  bf16_t* Yaug  = Qf;
  float*  OT    = Ar;   // attn output O^T [BH,128,N] fp32 (spans Ar+Ai)

  const dim3 gGemm(16, 32);
  const int gPackX = (4096 * 2048 / 8) / 256;
  const int gPackW = (2048 * 2048 / 8) / 256;
  const int gFft = 64 * 8;           // bh x 8 d-chunks of 8
  const int gAtt = 64 * 8;

  pack_x<<<gPackX, 256, 0, stream>>>(xr, xi, Axaug);

  // ---- Q (FFT output scale folds in the 1/8 attention scale; LN fused) ----
  pack_w<<<gPackW, 256, 0, stream>>>(Wqr, Wqi, bqr, bqi, Wcat, bcat);
  gemm_bf16<<<gGemm, 256, 0, stream>>>(Axaug, Wcat, bcat, Ar, Ai, 1024);
  ln_stats<<<BN, 256, 0, stream>>>(Ar, Ai, lnst);
  fft_kernel<<<gFft, 512, 0, stream>>>(Ar, Ai, Qf, Qf + 64,
      NN * DIMM, DHH, DIMM, 1,
      16 * NN * 128, NN * 128, 128,
      -1.0f, 0.03125f * 0.125f, 0, 0, lnst, gq, beq);
  // ---- K (row-major + XOR pre-swizzle) ----
  pack_w<<<gPackW, 256, 0, stream>>>(Wkr, Wki, bkr, bki, Wcat, bcat);
  gemm_bf16<<<gGemm, 256, 0, stream>>>(Axaug, Wcat, bcat, Ar, Ai, 1024);
  ln_stats<<<BN, 256, 0, stream>>>(Ar, Ai, lnst);
  fft_kernel<<<gFft, 512, 0, stream>>>(Ar, Ai, Kf, Kf + 64,
      NN * DIMM, DHH, DIMM, 1,
      16 * NN * 128, NN * 128, 128,
      -1.0f, 0.03125f, 0, 2, lnst, gk, bek);
  // ---- V (kv-tile-blocked + XOR pre-swizzle) ----
  pack_w<<<gPackW, 256, 0, stream>>>(Wvr, Wvi, bvr, bvi, Wcat, bcat);
  gemm_bf16<<<gGemm, 256, 0, stream>>>(Axaug, Wcat, bcat, Ar, Ai, 1024);
  ln_stats<<<BN, 256, 0, stream>>>(Ar, Ai, lnst);
  fft_kernel<<<gFft, 512, 0, stream>>>(Ar, Ai, VfT, VfT + 2048,
      NN * DIMM, DHH, DIMM, 1,
      16 * 131072, 131072, 0,
      -1.0f, 0.03125f, 0, 1, lnst, gv, bev);
  // ---- flash attention -> OT [BH,128,N] fp32 ----
  fattn<<<gAtt, 256, 0, stream>>>(Qf, Kf, VfT, OT);
  // ---- inverse FFT: OT (d-major, n-contiguous reads) -> Yaug ----
  fft_kernel<<<gFft, 512, 0, stream>>>(OT, OT + (size_t)64 * NN, Yaug, Yaug + 1024,
      16 * 128 * NN, 128 * NN, 1, NN,
      NN * 2048, 64, 2048,
      +1.0f, 0.03125f, 1, 0, nullptr, nullptr, nullptr);
  // ---- output projection straight into d_out ----
  float* yout = (float*)d_out;
  pack_w<<<gPackW, 256, 0, stream>>>(Wor, Woi, bor, boi, Wcat, bcat);
  gemm_bf16<<<gGemm, 256, 0, stream>>>(Yaug, Wcat, bcat, yout, yout + 1024, 2048);
}

// Round 14
// 410.065 us; speedup vs baseline: 1.5864x; 1.0521x over previous
//
#include <hip/hip_runtime.h>
#include <math.h>

#define BB 4
#define NN 1024
#define DIMM 1024
#define HHH 16
#define DHH 64
#define BN 4096            // B*N rows
#define EPS_LN 1e-6f

typedef __bf16 bf16_t;
typedef __bf16 bf16x8 __attribute__((ext_vector_type(8)));
typedef __bf16 bf16x4 __attribute__((ext_vector_type(4)));
typedef float f32x4 __attribute__((ext_vector_type(4)));
typedef float f32x16 __attribute__((ext_vector_type(16)));
#define MFMA16(a, b, c) __builtin_amdgcn_mfma_f32_16x16x32_bf16(a, b, c, 0, 0, 0)
#define MFMA32(a, b, c) __builtin_amdgcn_mfma_f32_32x32x16_bf16(a, b, c, 0, 0, 0)
#define AS1 __attribute__((address_space(1)))
#define AS3 __attribute__((address_space(3)))

__device__ inline unsigned pk2(float a, float b) {
  union { bf16_t h[2]; unsigned u; } c;
  c.h[0] = (bf16_t)a; c.h[1] = (bf16_t)b;
  return c.u;
}
union U16 { uint4 u; bf16x8 v; };

// ============================================================
// pack_x: Axaug[4096][2048] = bf16([xr | xi])
// ============================================================
__global__ __launch_bounds__(256) void pack_x(
    const float* __restrict__ xr, const float* __restrict__ xi,
    bf16_t* __restrict__ out)
{
  int t = blockIdx.x * 256 + threadIdx.x;
  size_t e = (size_t)t * 8;
  int row = (int)(e >> 11), col = (int)(e & 2047);
  const float* src = (col < 1024) ? (xr + (size_t)row * 1024 + col)
                                  : (xi + (size_t)row * 1024 + col - 1024);
  float4 a = *(const float4*)src;
  float4 b = *(const float4*)(src + 4);
  bf16x8 o;
  o[0] = (bf16_t)a.x; o[1] = (bf16_t)a.y; o[2] = (bf16_t)a.z; o[3] = (bf16_t)a.w;
  o[4] = (bf16_t)b.x; o[5] = (bf16_t)b.y; o[6] = (bf16_t)b.z; o[7] = (bf16_t)b.w;
  *(bf16x8*)(out + e) = o;
}

// ============================================================
// pack_w: writes one projection's augmented weights into a slice:
// rows 0-1023 = [Wr | -Wi], rows 1024-2047 = [Wi | Wr]; bias [br|bi].
// ============================================================
__global__ __launch_bounds__(256) void pack_w(
    const float* __restrict__ Wr, const float* __restrict__ Wi,
    const float* __restrict__ br, const float* __restrict__ bi,
    bf16_t* __restrict__ Wcat, float* __restrict__ bcat)
{
  int t = blockIdx.x * 256 + threadIdx.x;
  size_t e = (size_t)t * 8;
  int row = (int)(e >> 11), col = (int)(e & 2047);
  const float* src;
  float sgn = 1.f;
  if (row < 1024) {
    if (col < 1024) src = Wr + (size_t)row * 1024 + col;
    else          { src = Wi + (size_t)row * 1024 + col - 1024; sgn = -1.f; }
  } else {
    int r2 = row - 1024;
    if (col < 1024) src = Wi + (size_t)r2 * 1024 + col;
    else            src = Wr + (size_t)r2 * 1024 + col - 1024;
  }
  float4 a = *(const float4*)src;
  float4 b = *(const float4*)(src + 4);
  bf16x8 o;
  o[0] = (bf16_t)(sgn * a.x); o[1] = (bf16_t)(sgn * a.y);
  o[2] = (bf16_t)(sgn * a.z); o[3] = (bf16_t)(sgn * a.w);
  o[4] = (bf16_t)(sgn * b.x); o[5] = (bf16_t)(sgn * b.y);
  o[6] = (bf16_t)(sgn * b.z); o[7] = (bf16_t)(sgn * b.w);
  *(bf16x8*)(Wcat + e) = o;
  if (e < 2048) {
#pragma unroll
    for (int j = 0; j < 8; ++j) {
      int n = (int)e + j;
      bcat[n] = (n < 1024) ? br[n] : bi[n - 1024];
    }
  }
}

// ============================================================
// Fused QKV GEMM (NT), m97 structure, N=6144 -> 1536 blocks = 6/CU.
// C6[4096][6144] bf16 = A[4096][2048] @ Wcat3[6144][2048]^T + bias.
// ============================================================
__global__ __launch_bounds__(256) void gemm_qkv(
    const bf16_t* __restrict__ A, const bf16_t* __restrict__ Bt,
    const float* __restrict__ bias, bf16_t* __restrict__ C6)
{
  __shared__ bf16_t sA[128 * 64];
  __shared__ bf16_t sB[128 * 64];
  const int tid = threadIdx.x;
  const int w = tid >> 6, l = tid & 63;
  const int lo4 = l & 15, hi = l >> 4;
  const int wr = w >> 1, wc = w & 1;
  const int row0 = blockIdx.y * 128, col0 = blockIdx.x * 128;

  const int srow = (l >> 3);
  const int scol = (l & 7) * 8;
  const bf16_t* gA[4];
  const bf16_t* gB[4];
#pragma unroll
  for (int i = 0; i < 4; ++i) {
    int r = (w * 4 + i) * 8 + srow;
    gA[i] = A  + (size_t)(row0 + r) * 2048 + scol;
    gB[i] = Bt + (size_t)(col0 + r) * 2048 + scol;
  }

  f32x4 acc[4][4] = {};
  for (int k0 = 0; k0 < 2048; k0 += 64) {
    __syncthreads();
#pragma unroll
    for (int i = 0; i < 4; ++i) {
      __builtin_amdgcn_global_load_lds((const AS1 void*)(gA[i] + k0),
                                       (AS3 void*)&sA[(w * 4 + i) * 512], 16, 0, 0);
      __builtin_amdgcn_global_load_lds((const AS1 void*)(gB[i] + k0),
                                       (AS3 void*)&sB[(w * 4 + i) * 512], 16, 0, 0);
    }
    __syncthreads();
#pragma unroll
    for (int kk = 0; kk < 2; ++kk) {
      bf16x8 am[4], bn[4];
#pragma unroll
      for (int i = 0; i < 4; ++i)
        am[i] = *(const bf16x8*)&sA[(wr * 64 + i * 16 + lo4) * 64 + kk * 32 + hi * 8];
#pragma unroll
      for (int j = 0; j < 4; ++j)
        bn[j] = *(const bf16x8*)&sB[(wc * 64 + j * 16 + lo4) * 64 + kk * 32 + hi * 8];
#pragma unroll
      for (int i = 0; i < 4; ++i)
#pragma unroll
        for (int j = 0; j < 4; ++j)
          acc[i][j] = MFMA16(am[i], bn[j], acc[i][j]);
    }
  }
  const int colg0 = col0 + wc * 64;
#pragma unroll
  for (int i = 0; i < 4; ++i) {
#pragma unroll
    for (int j = 0; j < 4; ++j) {
      float bv = bias[colg0 + j * 16 + lo4];
#pragma unroll
      for (int r = 0; r < 4; ++r) {
        int rowg = row0 + wr * 64 + i * 16 + hi * 4 + r;
        C6[(size_t)rowg * 6144 + colg0 + j * 16 + lo4] = (bf16_t)(acc[i][j][r] + bv);
      }
    }
  }
}

// ============================================================
// O-projection GEMM (unchanged m97 structure, fp32 out to d_out).
// ============================================================
__global__ __launch_bounds__(256) void gemm_bf16(
    const bf16_t* __restrict__ A, const bf16_t* __restrict__ Bt,
    const float* __restrict__ bias,
    float* __restrict__ Cr, float* __restrict__ Ci, int ldc)
{
  __shared__ bf16_t sA[128 * 64];
  __shared__ bf16_t sB[128 * 64];
  const int tid = threadIdx.x;
  const int w = tid >> 6, l = tid & 63;
  const int lo4 = l & 15, hi = l >> 4;
  const int wr = w >> 1, wc = w & 1;
  const int row0 = blockIdx.y * 128, col0 = blockIdx.x * 128;

  const int srow = (l >> 3);
  const int scol = (l & 7) * 8;
  const bf16_t* gA[4];
  const bf16_t* gB[4];
#pragma unroll
  for (int i = 0; i < 4; ++i) {
    int r = (w * 4 + i) * 8 + srow;
    gA[i] = A  + (size_t)(row0 + r) * 2048 + scol;
    gB[i] = Bt + (size_t)(col0 + r) * 2048 + scol;
  }

  f32x4 acc[4][4] = {};
  for (int k0 = 0; k0 < 2048; k0 += 64) {
    __syncthreads();
#pragma unroll
    for (int i = 0; i < 4; ++i) {
      __builtin_amdgcn_global_load_lds((const AS1 void*)(gA[i] + k0),
                                       (AS3 void*)&sA[(w * 4 + i) * 512], 16, 0, 0);
      __builtin_amdgcn_global_load_lds((const AS1 void*)(gB[i] + k0),
                                       (AS3 void*)&sB[(w * 4 + i) * 512], 16, 0, 0);
    }
    __syncthreads();
#pragma unroll
    for (int kk = 0; kk < 2; ++kk) {
      bf16x8 am[4], bn[4];
#pragma unroll
      for (int i = 0; i < 4; ++i)
        am[i] = *(const bf16x8*)&sA[(wr * 64 + i * 16 + lo4) * 64 + kk * 32 + hi * 8];
#pragma unroll
      for (int j = 0; j < 4; ++j)
        bn[j] = *(const bf16x8*)&sB[(wc * 64 + j * 16 + lo4) * 64 + kk * 32 + hi * 8];
#pragma unroll
      for (int i = 0; i < 4; ++i)
#pragma unroll
        for (int j = 0; j < 4; ++j)
          acc[i][j] = MFMA16(am[i], bn[j], acc[i][j]);
    }
  }
  const int colg0 = col0 + wc * 64;
  float* Cp = (colg0 < 1024) ? Cr : Ci;
  const int cb = colg0 & 1023;
#pragma unroll
  for (int i = 0; i < 4; ++i) {
#pragma unroll
    for (int j = 0; j < 4; ++j) {
      float bv = bias[colg0 + j * 16 + lo4];
#pragma unroll
      for (int r = 0; r < 4; ++r) {
        int rowg = row0 + wr * 64 + i * 16 + hi * 4 + r;
        Cp[(size_t)rowg * ldc + cb + j * 16 + lo4] = acc[i][j][r] + bv;
      }
    }
  }
}

// ============================================================
// LN row stats over bf16 C6, all 3 projections in one launch.
// grid (4096, 3); stats[p*4096 + row] = (mean, rsqrt(var+eps)).
// ============================================================
__global__ __launch_bounds__(256) void ln_stats3(
    const bf16_t* __restrict__ C6, float2* __restrict__ st)
{
  __shared__ float red[8];
  const int row = blockIdx.x;
  const int p = blockIdx.y;
  const int tid = threadIdx.x;
  const bf16_t* pr = C6 + (size_t)row * 6144 + p * 2048;
  const bf16_t* pi = pr + 1024;
  bf16x4 vr = *(const bf16x4*)(pr + tid * 4);
  bf16x4 vi = *(const bf16x4*)(pi + tid * 4);
  float s = 0.f, s2 = 0.f;
#pragma unroll
  for (int t = 0; t < 4; ++t) {
    float a = (float)vr[t], b = (float)vi[t];
    float mg = sqrtf(a * a + b * b);
    s += mg; s2 += mg * mg;
  }
#pragma unroll
  for (int o = 32; o; o >>= 1) { s += __shfl_down(s, o); s2 += __shfl_down(s2, o); }
  if ((tid & 63) == 0) { red[tid >> 6] = s; red[4 + (tid >> 6)] = s2; }
  __syncthreads();
  if (tid == 0) {
    float S = red[0] + red[1] + red[2] + red[3];
    float S2 = red[4] + red[5] + red[6] + red[7];
    float mean = S * (1.f / DIMM);
    float var = S2 * (1.f / DIMM) - mean * mean;
    st[(size_t)p * 4096 + row] = make_float2(mean, rsqrtf(var + EPS_LN));
  }
}

// ============================================================
// 1024-pt RADIX-4 DIF FFT v3 — bf16 input (C6 slices / OT), bf16 out.
// imode 0: d-contiguous bf16x8 read (+ optional fused LN).
// imode 1: n-contiguous bf16 read (iFFT from OT [d][N] bf16).
// omode 0/1/2 as before (byte layouts unchanged).
// ============================================================
#define LIDX(d_, c_) (((d_) << 10) + ((c_) ^ (((c_) >> 5) & 31) ^ (((d_) & 7) << 2)))

__global__ __launch_bounds__(512) void fft_kernel(
    const bf16_t* __restrict__ inR, const bf16_t* __restrict__ inI,
    bf16_t* __restrict__ outR, bf16_t* __restrict__ outI,
    int in_sb, int in_sh, int in_sn, int in_sd,
    int out_sb, int out_sh, int out_sn,
    float sign, float oscale, int imode, int omode,
    const float2* __restrict__ stats,
    const float* __restrict__ gamma, const float* __restrict__ beta)
{
  __shared__ float lr[8 * 1024], li[8 * 1024];
  __shared__ float2 tw[1024];
  const int tid = threadIdx.x;
  const int dc = blockIdx.x & 7;          // 8 chunks of 8 d
  const int bh = blockIdx.x >> 3;
  const int b = bh >> 4, h = bh & 15;
  const bf16_t* bR = inR + (size_t)b * in_sb + (size_t)h * in_sh;
  const bf16_t* bI = inI + (size_t)b * in_sb + (size_t)h * in_sh;
#pragma unroll
  for (int t = tid; t < 1024; t += 512) {
    float ang = sign * 3.14159265358979323846f * (float)t * (1.f / 512.f);
    float sn, cs;
    __sincosf(ang, &sn, &cs);
    tw[t] = make_float2(cs, sn);
  }
  // ---- load (+ optional fused LN) ----
  if (imode == 0) {
    float gg[8], bb[8];
    if (stats) {
#pragma unroll
      for (int ds = 0; ds < 8; ++ds) {
        gg[ds] = gamma[h * DHH + dc * 8 + ds];
        bb[ds] = beta[h * DHH + dc * 8 + ds];
      }
    }
#pragma unroll
    for (int rep = 0; rep < 2; ++rep) {
      int n = tid + rep * 512;
      bf16x8 r8 = *(const bf16x8*)(bR + (size_t)n * in_sn + dc * 8);
      bf16x8 i8 = *(const bf16x8*)(bI + (size_t)n * in_sn + dc * 8);
      float ur[8], ui[8];
#pragma unroll
      for (int ds = 0; ds < 8; ++ds) { ur[ds] = (float)r8[ds]; ui[ds] = (float)i8[ds]; }
      if (stats) {
        float2 stv = stats[b * NN + n];
#pragma unroll
        for (int ds = 0; ds < 8; ++ds) {
          float a = ur[ds], c2 = ui[ds];
          float mag = sqrtf(a * a + c2 * c2);
          float nm = (mag - stv.x) * stv.y * gg[ds] + bb[ds];
          if (mag > 0.f) { float sc = nm / mag; ur[ds] = a * sc; ui[ds] = c2 * sc; }
          else           { ur[ds] = nm; ui[ds] = 0.f; }
        }
      }
#pragma unroll
      for (int ds = 0; ds < 8; ++ds) {
        int ax = LIDX(ds, n);
        lr[ax] = ur[ds];
        li[ax] = ui[ds];
      }
    }
  } else {
    const int ds = tid & 7, nb = tid >> 3;   // nb 0..63
    const bf16_t* pR = bR + (size_t)(dc * 8 + ds) * in_sd + nb * 16;
    const bf16_t* pI = bI + (size_t)(dc * 8 + ds) * in_sd + nb * 16;
    bf16x8 a0 = *(const bf16x8*)pR, a1 = *(const bf16x8*)(pR + 8);
    bf16x8 b0 = *(const bf16x8*)pI, b1 = *(const bf16x8*)(pI + 8);
#pragma unroll
    for (int k = 0; k < 8; ++k) {
      int c = nb * 16 + k;
      lr[LIDX(ds, c)] = (float)a0[k];       li[LIDX(ds, c)] = (float)b0[k];
      lr[LIDX(ds, c + 8)] = (float)a1[k];   li[LIDX(ds, c + 8)] = (float)b1[k];
    }
  }
  __syncthreads();
  // ---- 5 radix-4 DIF stages ----
  const int dsub = tid & 7;
  const int jb = tid >> 3;                 // 0..63
  int lq2 = 8;
  for (int st = 0; st < 5; ++st) {
    const int qtr = 1 << lq2;
    const int tmul = 1 << (2 * st);
    for (int jt = 0; jt < 4; ++jt) {
      int j = jb + jt * 64;                // 0..255
      int o = j & (qtr - 1);
      int i0 = ((j >> lq2) << (lq2 + 2)) + o;
      int a0 = LIDX(dsub, i0);
      int a1 = LIDX(dsub, i0 + qtr);
      int a2 = LIDX(dsub, i0 + 2 * qtr);
      int a3 = LIDX(dsub, i0 + 3 * qtr);
      float x0r = lr[a0], x0i = li[a0];
      float x1r = lr[a1], x1i = li[a1];
      float x2r = lr[a2], x2i = li[a2];
      float x3r = lr[a3], x3i = li[a3];
      float ar = x0r + x2r, ai2 = x0i + x2i;
      float br = x0r - x2r, bi  = x0i - x2i;
      float cr = x1r + x3r, ci  = x1i + x3i;
      float dr = x1r - x3r, di  = x1i - x3i;
      float2 t1 = tw[o * tmul];
      float2 t2 = tw[2 * o * tmul];
      float2 t3 = tw[3 * o * tmul];
      lr[a0] = ar + cr;  li[a0] = ai2 + ci;
      float u1r = br - sign * di, u1i = bi + sign * dr;
      lr[a1] = u1r * t1.x - u1i * t1.y;  li[a1] = u1r * t1.y + u1i * t1.x;
      float u2r = ar - cr, u2i = ai2 - ci;
      lr[a2] = u2r * t2.x - u2i * t2.y;  li[a2] = u2r * t2.y + u2i * t2.x;
      float u3r = br + sign * di, u3i = bi - sign * dr;
      lr[a3] = u3r * t3.x - u3i * t3.y;  li[a3] = u3r * t3.y + u3i * t3.x;
    }
    __syncthreads();
    lq2 -= 2;
  }
  // ---- store (base-4 digit reversal folded into LDS read) ----
  bf16_t* oRb = outR + (size_t)b * out_sb + (size_t)h * out_sh;
  bf16_t* oIb = outI + (size_t)b * out_sb + (size_t)h * out_sh;
#pragma unroll
  for (int rep = 0; rep < 2; ++rep) {
    int n = tid + rep * 512;
    int rv2 = __brev((unsigned)n) >> 22;
    int p = ((rv2 & 0x155) << 1) | ((rv2 >> 1) & 0x155);   // base-4 digit reversal
    float fr[8], fi[8];
#pragma unroll
    for (int ds = 0; ds < 8; ++ds) {
      fr[ds] = lr[LIDX(ds, p)] * oscale;
      fi[ds] = li[LIDX(ds, p)] * oscale;
    }
    if (omode == 1) {
      size_t tb = (size_t)(n >> 5) * 4096;
#pragma unroll
      for (int ds = 0; ds < 8; ++ds) {
        int dch = dc * 8 + ds;
        size_t ga = tb + (size_t)dch * 32 + ((n & 31) ^ (((dch >> 1) & 3) << 3));
        oRb[ga] = (bf16_t)fr[ds];
        oIb[ga] = (bf16_t)fi[ds];
      }
    } else {
      int cb = dc * 8;
      if (omode == 2) cb = (dc ^ (n & 7)) * 8;
      bf16x8 v0, w0;
#pragma unroll
      for (int k = 0; k < 8; ++k) {
        v0[k] = (bf16_t)fr[k];
        w0[k] = (bf16_t)fi[k];
      }
      size_t gb = (size_t)n * out_sn + cb;
      *(bf16x8*)(oRb + gb) = v0;
      *(bf16x8*)(oIb + gb) = w0;
    }
  }
}

// ============================================================
// Flash attention v7 (control; OT store now bf16).
// ============================================================
__global__ __launch_bounds__(256, 2) void fattn(
    const bf16_t* __restrict__ Qf, const bf16_t* __restrict__ Kfs,
    const bf16_t* __restrict__ Vfs, bf16_t* __restrict__ OT)
{
  __shared__ bf16_t K3[3][4096];
  __shared__ bf16_t V3[3][4096];
  const int tid = threadIdx.x;
  const int w = tid >> 6, l = tid & 63;
  const int lq = l & 31;
  const int h = l >> 5;
  const int i = blockIdx.x;
  const int j = i >> 3;
  const int bh = (i & 7) * 8 + (j >> 3);   // XCD-locality swizzle
  const int q0 = (j & 7) * 128 + w * 32;

  bf16x8 bq[8];
  const bf16_t* qp = Qf + ((size_t)bh * NN + q0 + lq) * 128 + h * 8;
#pragma unroll
  for (int kk = 0; kk < 8; ++kk) bq[kk] = *(const bf16x8*)(qp + kk * 16);

  f32x16 o[4] = {};
  float m = -3e38f, ln = 0.f;

  const bf16_t* kg = Kfs + (size_t)bh * 131072 + w * 1024 + l * 8;
  const bf16_t* vg = Vfs + (size_t)bh * 131072 + w * 1024 + l * 8;
  const int kswz = (lq & 7) << 3;
  const int vswz = ((lq >> 1) & 3) << 3;

#pragma unroll
  for (int tt = 0; tt < 2; ++tt) {
    const bf16_t* kt = kg + (size_t)tt * 4096;
    const bf16_t* vt = vg + (size_t)tt * 4096;
#pragma unroll
    for (int ii = 0; ii < 2; ++ii) {
      __builtin_amdgcn_global_load_lds((const AS1 void*)(kt + ii * 512),
                                       (AS3 void*)&K3[tt][w * 1024 + ii * 512], 16, 0, 0);
      __builtin_amdgcn_global_load_lds((const AS1 void*)(vt + ii * 512),
                                       (AS3 void*)&V3[tt][w * 1024 + ii * 512], 16, 0, 0);
    }
  }
  asm volatile("s_waitcnt vmcnt(4)" ::: "memory");
  __builtin_amdgcn_s_barrier();
  __builtin_amdgcn_sched_barrier(0);

  int cur = 0;
  for (int t = 0; t < 32; ++t) {
    if (t < 30) {
      int nb = cur + 2; if (nb >= 3) nb -= 3;
      const bf16_t* kt = kg + (size_t)(t + 2) * 4096;
      const bf16_t* vt = vg + (size_t)(t + 2) * 4096;
#pragma unroll
      for (int ii = 0; ii < 2; ++ii) {
        __builtin_amdgcn_global_load_lds((const AS1 void*)(kt + ii * 512),
                                         (AS3 void*)&K3[nb][w * 1024 + ii * 512], 16, 0, 0);
        __builtin_amdgcn_global_load_lds((const AS1 void*)(vt + ii * 512),
                                         (AS3 void*)&V3[nb][w * 1024 + ii * 512], 16, 0, 0);
      }
    }

    f32x16 s = {};
#pragma unroll
    for (int kk = 0; kk < 8; ++kk) {
      bf16x8 ak = *(const bf16x8*)&K3[cur][lq * 128 + ((kk * 16 + h * 8) ^ kswz)];
      s = MFMA32(ak, bq[kk], s);
    }

    float pmax = s[0];
#pragma unroll
    for (int r = 1; r < 16; ++r) pmax = fmaxf(pmax, s[r]);
    pmax = fmaxf(pmax, __shfl_xor(pmax, 32));
    if (!__all(pmax - m <= 8.f)) {
      float mnew = fmaxf(m, pmax);
      float alpha = __expf(m - mnew);
      m = mnew;
      ln *= alpha;
#pragma unroll
      for (int db = 0; db < 4; ++db)
#pragma unroll
        for (int r = 0; r < 16; ++r) o[db][r] *= alpha;
    }
    float pf[16];
    float rs = 0.f;
#pragma unroll
    for (int r = 0; r < 16; ++r) { pf[r] = __expf(s[r] - m); rs += pf[r]; }
    rs += __shfl_xor(rs, 32);
    ln += rs;

    unsigned pw[8];
#pragma unroll
    for (int ii = 0; ii < 8; ++ii) pw[ii] = pk2(pf[2 * ii], pf[2 * ii + 1]);
    unsigned r0 = (unsigned)__shfl_xor((int)(h ? pw[0] : pw[2]), 32);
    unsigned r1 = (unsigned)__shfl_xor((int)(h ? pw[1] : pw[3]), 32);
    unsigned r2 = (unsigned)__shfl_xor((int)(h ? pw[4] : pw[6]), 32);
    unsigned r3 = (unsigned)__shfl_xor((int)(h ? pw[5] : pw[7]), 32);
    U16 bp0, bp1;
    bp0.u.x = h ? r0 : pw[0];  bp0.u.y = h ? r1 : pw[1];
    bp0.u.z = h ? pw[2] : r0;  bp0.u.w = h ? pw[3] : r1;
    bp1.u.x = h ? r2 : pw[4];  bp1.u.y = h ? r3 : pw[5];
    bp1.u.z = h ? pw[6] : r2;  bp1.u.w = h ? pw[7] : r3;

#pragma unroll
    for (int db = 0; db < 4; ++db) {
      int r = db * 32 + lq;
      bf16x8 av0 = *(const bf16x8*)&V3[cur][r * 32 + ((h * 8) ^ vswz)];
      bf16x8 av1 = *(const bf16x8*)&V3[cur][r * 32 + ((16 + h * 8) ^ vswz)];
      o[db] = MFMA32(av0, bp0.v, o[db]);
      o[db] = MFMA32(av1, bp1.v, o[db]);
    }

    if (t < 31) {
      if (t < 30) asm volatile("s_waitcnt vmcnt(4)" ::: "memory");
      else        asm volatile("s_waitcnt vmcnt(0)" ::: "memory");
      __builtin_amdgcn_s_barrier();
      __builtin_amdgcn_sched_barrier(0);
    }
    cur = (cur == 2) ? 0 : cur + 1;
  }

  float inv = 1.f / ln;
  const size_t otb = (size_t)bh * 128 * NN + q0 + lq;
#pragma unroll
  for (int db = 0; db < 4; ++db)
#pragma unroll
    for (int r = 0; r < 16; ++r) {
      int dl = (r & 3) + 8 * (r >> 2) + 4 * h;
      OT[otb + (size_t)(db * 32 + dl) * NN] = (bf16_t)(o[db][r] * inv);
    }
}

// ============================================================
// Host-side orchestration
// ============================================================
extern "C" void kernel_launch(void* const* d_in, const int* in_sizes, int n_in,
                              void* d_out, int out_size, void* d_ws, size_t ws_size,
                              hipStream_t stream) {
  const float* xr   = (const float*)d_in[0];
  const float* xi   = (const float*)d_in[1];
  const float* Wqr  = (const float*)d_in[2];
  const float* Wqi  = (const float*)d_in[3];
  const float* bqr  = (const float*)d_in[4];
  const float* bqi  = (const float*)d_in[5];
  const float* Wkr  = (const float*)d_in[6];
  const float* Wki  = (const float*)d_in[7];
  const float* bkr  = (const float*)d_in[8];
  const float* bki  = (const float*)d_in[9];
  const float* Wvr  = (const float*)d_in[10];
  const float* Wvi  = (const float*)d_in[11];
  const float* bvr  = (const float*)d_in[12];
  const float* bvi  = (const float*)d_in[13];
  const float* Wor  = (const float*)d_in[14];
  const float* Woi  = (const float*)d_in[15];
  const float* bor  = (const float*)d_in[16];
  const float* boi  = (const float*)d_in[17];
  const float* gq   = (const float*)d_in[18];
  const float* beq  = (const float*)d_in[19];
  const float* gk   = (const float*)d_in[20];
  const float* bek  = (const float*)d_in[21];
  const float* gv   = (const float*)d_in[22];
  const float* bev  = (const float*)d_in[23];

  char* wp = (char*)d_ws;
  bf16_t* Axaug = (bf16_t*)wp;  wp += (size_t)4096 * 2048 * 2;     // 16.8 MB
  bf16_t* Wcat3 = (bf16_t*)wp;  wp += (size_t)6144 * 2048 * 2;     // 25.2 MB
  float*  bcat3 = (float*)wp;   wp += (size_t)6144 * 4;
  float2* lnst3 = (float2*)wp;  wp += (size_t)3 * 4096 * 8;
  bf16_t* C6    = (bf16_t*)wp;  wp += (size_t)4096 * 6144 * 2;     // 50.3 MB
  bf16_t* Qf    = (bf16_t*)wp;  wp += (size_t)64 * 1024 * 128 * 2; // 16.8 MB
  bf16_t* Kf    = (bf16_t*)wp;  wp += (size_t)64 * 1024 * 128 * 2;
  bf16_t* VfT   = (bf16_t*)wp;  wp += (size_t)64 * 1024 * 128 * 2;
  bf16_t* OT    = C6;    // [bh][128][1024] bf16; C6 dead after V's FFT
  bf16_t* Yaug  = Qf;    // [4096][2048] bf16; Qf dead after fattn

  const dim3 gQKV(48, 32);            // 6144/128 x 4096/128 = 1536 blocks
  const dim3 gGemmO(16, 32);          // 2048/128 x 4096/128
  const int gPackX = (4096 * 2048 / 8) / 256;
  const int gPackW = (2048 * 2048 / 8) / 256;
  const dim3 gLn(4096, 3);
  const int gFft = 64 * 8;            // bh x 8 d-chunks of 8
  const int gAtt = 64 * 8;

  pack_x<<<gPackX, 256, 0, stream>>>(xr, xi, Axaug);
  pack_w<<<gPackW, 256, 0, stream>>>(Wqr, Wqi, bqr, bqi,
                                     Wcat3, bcat3);
  pack_w<<<gPackW, 256, 0, stream>>>(Wkr, Wki, bkr, bki,
                                     Wcat3 + (size_t)2048 * 2048, bcat3 + 2048);
  pack_w<<<gPackW, 256, 0, stream>>>(Wvr, Wvi, bvr, bvi,
                                     Wcat3 + (size_t)4096 * 2048, bcat3 + 4096);

  // ---- fused QKV projection -> C6 bf16 [4096][6144] ----
  gemm_qkv<<<gQKV, 256, 0, stream>>>(Axaug, Wcat3, bcat3, C6);
  ln_stats3<<<gLn, 256, 0, stream>>>(C6, lnst3);

  // ---- FFTs (LN fused on load); Q carries the 1/8 attention scale ----
  fft_kernel<<<gFft, 512, 0, stream>>>(C6, C6 + 1024, Qf, Qf + 64,
      NN * 6144, DHH, 6144, 1,
      16 * NN * 128, NN * 128, 128,
      -1.0f, 0.03125f * 0.125f, 0, 0, lnst3, gq, beq);
  fft_kernel<<<gFft, 512, 0, stream>>>(C6 + 2048, C6 + 3072, Kf, Kf + 64,
      NN * 6144, DHH, 6144, 1,
      16 * NN * 128, NN * 128, 128,
      -1.0f, 0.03125f, 0, 2, lnst3 + 4096, gk, bek);
  fft_kernel<<<gFft, 512, 0, stream>>>(C6 + 4096, C6 + 5120, VfT, VfT + 2048,
      NN * 6144, DHH, 6144, 1,
      16 * 131072, 131072, 0,
      -1.0f, 0.03125f, 0, 1, lnst3 + 8192, gv, bev);

  // ---- flash attention -> OT bf16 [bh][128][1024] (aliases C6) ----
  fattn<<<gAtt, 256, 0, stream>>>(Qf, Kf, VfT, OT);

  // ---- inverse FFT: OT (d-major bf16) -> Yaug bf16 [4096][2048] ----
  fft_kernel<<<gFft, 512, 0, stream>>>(OT, OT + (size_t)64 * NN, Yaug, Yaug + 1024,
      16 * 128 * NN, 128 * NN, 1, NN,
      NN * 2048, 64, 2048,
      +1.0f, 0.03125f, 1, 0, nullptr, nullptr, nullptr);

  // ---- output projection straight into d_out ----
  float* yout = (float*)d_out;
  pack_w<<<gPackW, 256, 0, stream>>>(Wor, Woi, bor, boi, Wcat3, bcat3);
  gemm_bf16<<<gGemmO, 256, 0, stream>>>(Yaug, Wcat3, bcat3, yout, yout + 1024, 2048);
}

// Round 15
// 402.577 us; speedup vs baseline: 1.6159x; 1.0186x over previous
//
#include <hip/hip_runtime.h>
#include <math.h>

#define BB 4
#define NN 1024
#define DIMM 1024
#define HHH 16
#define DHH 64
#define BN 4096            // B*N rows
#define EPS_LN 1e-6f

typedef __bf16 bf16_t;
typedef __bf16 bf16x8 __attribute__((ext_vector_type(8)));
typedef __bf16 bf16x4 __attribute__((ext_vector_type(4)));
typedef float f32x4 __attribute__((ext_vector_type(4)));
typedef float f32x16 __attribute__((ext_vector_type(16)));
#define MFMA16(a, b, c) __builtin_amdgcn_mfma_f32_16x16x32_bf16(a, b, c, 0, 0, 0)
#define MFMA32(a, b, c) __builtin_amdgcn_mfma_f32_32x32x16_bf16(a, b, c, 0, 0, 0)
#define AS1 __attribute__((address_space(1)))
#define AS3 __attribute__((address_space(3)))

__device__ inline unsigned pk2(float a, float b) {
  union { bf16_t h[2]; unsigned u; } c;
  c.h[0] = (bf16_t)a; c.h[1] = (bf16_t)b;
  return c.u;
}
union U16 { uint4 u; bf16x8 v; };

// ============================================================
// pack_x: Axaug[4096][2048] = bf16([xr | xi])
// ============================================================
__global__ __launch_bounds__(256) void pack_x(
    const float* __restrict__ xr, const float* __restrict__ xi,
    bf16_t* __restrict__ out)
{
  int t = blockIdx.x * 256 + threadIdx.x;
  size_t e = (size_t)t * 8;
  int row = (int)(e >> 11), col = (int)(e & 2047);
  const float* src = (col < 1024) ? (xr + (size_t)row * 1024 + col)
                                  : (xi + (size_t)row * 1024 + col - 1024);
  float4 a = *(const float4*)src;
  float4 b = *(const float4*)(src + 4);
  bf16x8 o;
  o[0] = (bf16_t)a.x; o[1] = (bf16_t)a.y; o[2] = (bf16_t)a.z; o[3] = (bf16_t)a.w;
  o[4] = (bf16_t)b.x; o[5] = (bf16_t)b.y; o[6] = (bf16_t)b.z; o[7] = (bf16_t)b.w;
  *(bf16x8*)(out + e) = o;
}

// ============================================================
// pack_w: one projection's augmented weights into a slice.
// ============================================================
__global__ __launch_bounds__(256) void pack_w(
    const float* __restrict__ Wr, const float* __restrict__ Wi,
    const float* __restrict__ br, const float* __restrict__ bi,
    bf16_t* __restrict__ Wcat, float* __restrict__ bcat)
{
  int t = blockIdx.x * 256 + threadIdx.x;
  size_t e = (size_t)t * 8;
  int row = (int)(e >> 11), col = (int)(e & 2047);
  const float* src;
  float sgn = 1.f;
  if (row < 1024) {
    if (col < 1024) src = Wr + (size_t)row * 1024 + col;
    else          { src = Wi + (size_t)row * 1024 + col - 1024; sgn = -1.f; }
  } else {
    int r2 = row - 1024;
    if (col < 1024) src = Wi + (size_t)r2 * 1024 + col;
    else            src = Wr + (size_t)r2 * 1024 + col - 1024;
  }
  float4 a = *(const float4*)src;
  float4 b = *(const float4*)(src + 4);
  bf16x8 o;
  o[0] = (bf16_t)(sgn * a.x); o[1] = (bf16_t)(sgn * a.y);
  o[2] = (bf16_t)(sgn * a.z); o[3] = (bf16_t)(sgn * a.w);
  o[4] = (bf16_t)(sgn * b.x); o[5] = (bf16_t)(sgn * b.y);
  o[6] = (bf16_t)(sgn * b.z); o[7] = (bf16_t)(sgn * b.w);
  *(bf16x8*)(Wcat + e) = o;
  if (e < 2048) {
#pragma unroll
    for (int j = 0; j < 8; ++j) {
      int n = (int)e + j;
      bcat[n] = (n < 1024) ? br[n] : bi[n - 1024];
    }
  }
}

// ============================================================
// Fused QKV GEMM, T3-min counted pipeline: double-buffered LDS,
// issue tile t+2 after the read-barrier, counted vmcnt(8) so the
// next tile's loads span the MFMA phase (never drain mid-loop).
// ============================================================
__global__ __launch_bounds__(256) void gemm_qkv(
    const bf16_t* __restrict__ A, const bf16_t* __restrict__ Bt,
    const float* __restrict__ bias, bf16_t* __restrict__ C6)
{
  __shared__ bf16_t sA[2][128 * 64];
  __shared__ bf16_t sB[2][128 * 64];
  const int tid = threadIdx.x;
  const int w = tid >> 6, l = tid & 63;
  const int lo4 = l & 15, hi = l >> 4;
  const int wr = w >> 1, wc = w & 1;
  const int row0 = blockIdx.y * 128, col0 = blockIdx.x * 128;

  const int srow = (l >> 3);
  const int scol = (l & 7) * 8;
  const bf16_t* gA[4];
  const bf16_t* gB[4];
#pragma unroll
  for (int i = 0; i < 4; ++i) {
    int r = (w * 4 + i) * 8 + srow;
    gA[i] = A  + (size_t)(row0 + r) * 2048 + scol;
    gB[i] = Bt + (size_t)(col0 + r) * 2048 + scol;
  }

  f32x4 acc[4][4] = {};
  const int nk = 2048 / 64;   // 32
  // prologue: issue tiles 0 and 1
#pragma unroll
  for (int i = 0; i < 4; ++i) {
    __builtin_amdgcn_global_load_lds((const AS1 void*)(gA[i]),
                                     (AS3 void*)&sA[0][(w * 4 + i) * 512], 16, 0, 0);
    __builtin_amdgcn_global_load_lds((const AS1 void*)(gB[i]),
                                     (AS3 void*)&sB[0][(w * 4 + i) * 512], 16, 0, 0);
  }
#pragma unroll
  for (int i = 0; i < 4; ++i) {
    __builtin_amdgcn_global_load_lds((const AS1 void*)(gA[i] + 64),
                                     (AS3 void*)&sA[1][(w * 4 + i) * 512], 16, 0, 0);
    __builtin_amdgcn_global_load_lds((const AS1 void*)(gB[i] + 64),
                                     (AS3 void*)&sB[1][(w * 4 + i) * 512], 16, 0, 0);
  }
  for (int t = 0; t < nk; ++t) {
    const int ct = t & 1;
    if (t + 1 < nk) asm volatile("s_waitcnt vmcnt(8)" ::: "memory");
    else            asm volatile("s_waitcnt vmcnt(0)" ::: "memory");
    __builtin_amdgcn_sched_barrier(0);
    __builtin_amdgcn_s_barrier();
    __builtin_amdgcn_sched_barrier(0);
#pragma unroll
    for (int kk = 0; kk < 2; ++kk) {
      bf16x8 am[4], bn[4];
#pragma unroll
      for (int i = 0; i < 4; ++i)
        am[i] = *(const bf16x8*)&sA[ct][(wr * 64 + i * 16 + lo4) * 64 + kk * 32 + hi * 8];
#pragma unroll
      for (int j = 0; j < 4; ++j)
        bn[j] = *(const bf16x8*)&sB[ct][(wc * 64 + j * 16 + lo4) * 64 + kk * 32 + hi * 8];
#pragma unroll
      for (int i = 0; i < 4; ++i)
#pragma unroll
        for (int j = 0; j < 4; ++j)
          acc[i][j] = MFMA16(am[i], bn[j], acc[i][j]);
    }
    __builtin_amdgcn_s_barrier();
    __builtin_amdgcn_sched_barrier(0);
    if (t + 2 < nk) {
      int k2 = (t + 2) * 64;
#pragma unroll
      for (int i = 0; i < 4; ++i) {
        __builtin_amdgcn_global_load_lds((const AS1 void*)(gA[i] + k2),
                                         (AS3 void*)&sA[ct][(w * 4 + i) * 512], 16, 0, 0);
        __builtin_amdgcn_global_load_lds((const AS1 void*)(gB[i] + k2),
                                         (AS3 void*)&sB[ct][(w * 4 + i) * 512], 16, 0, 0);
      }
    }
  }
  const int colg0 = col0 + wc * 64;
#pragma unroll
  for (int i = 0; i < 4; ++i) {
#pragma unroll
    for (int j = 0; j < 4; ++j) {
      float bv = bias[colg0 + j * 16 + lo4];
#pragma unroll
      for (int r = 0; r < 4; ++r) {
        int rowg = row0 + wr * 64 + i * 16 + hi * 4 + r;
        C6[(size_t)rowg * 6144 + colg0 + j * 16 + lo4] = (bf16_t)(acc[i][j][r] + bv);
      }
    }
  }
}

// ============================================================
// O-projection GEMM — same T3-min pipeline, fp32 split output.
// ============================================================
__global__ __launch_bounds__(256) void gemm_bf16(
    const bf16_t* __restrict__ A, const bf16_t* __restrict__ Bt,
    const float* __restrict__ bias,
    float* __restrict__ Cr, float* __restrict__ Ci, int ldc)
{
  __shared__ bf16_t sA[2][128 * 64];
  __shared__ bf16_t sB[2][128 * 64];
  const int tid = threadIdx.x;
  const int w = tid >> 6, l = tid & 63;
  const int lo4 = l & 15, hi = l >> 4;
  const int wr = w >> 1, wc = w & 1;
  const int row0 = blockIdx.y * 128, col0 = blockIdx.x * 128;

  const int srow = (l >> 3);
  const int scol = (l & 7) * 8;
  const bf16_t* gA[4];
  const bf16_t* gB[4];
#pragma unroll
  for (int i = 0; i < 4; ++i) {
    int r = (w * 4 + i) * 8 + srow;
    gA[i] = A  + (size_t)(row0 + r) * 2048 + scol;
    gB[i] = Bt + (size_t)(col0 + r) * 2048 + scol;
  }

  f32x4 acc[4][4] = {};
  const int nk = 2048 / 64;
#pragma unroll
  for (int i = 0; i < 4; ++i) {
    __builtin_amdgcn_global_load_lds((const AS1 void*)(gA[i]),
                                     (AS3 void*)&sA[0][(w * 4 + i) * 512], 16, 0, 0);
    __builtin_amdgcn_global_load_lds((const AS1 void*)(gB[i]),
                                     (AS3 void*)&sB[0][(w * 4 + i) * 512], 16, 0, 0);
  }
#pragma unroll
  for (int i = 0; i < 4; ++i) {
    __builtin_amdgcn_global_load_lds((const AS1 void*)(gA[i] + 64),
                                     (AS3 void*)&sA[1][(w * 4 + i) * 512], 16, 0, 0);
    __builtin_amdgcn_global_load_lds((const AS1 void*)(gB[i] + 64),
                                     (AS3 void*)&sB[1][(w * 4 + i) * 512], 16, 0, 0);
  }
  for (int t = 0; t < nk; ++t) {
    const int ct = t & 1;
    if (t + 1 < nk) asm volatile("s_waitcnt vmcnt(8)" ::: "memory");
    else            asm volatile("s_waitcnt vmcnt(0)" ::: "memory");
    __builtin_amdgcn_sched_barrier(0);
    __builtin_amdgcn_s_barrier();
    __builtin_amdgcn_sched_barrier(0);
#pragma unroll
    for (int kk = 0; kk < 2; ++kk) {
      bf16x8 am[4], bn[4];
#pragma unroll
      for (int i = 0; i < 4; ++i)
        am[i] = *(const bf16x8*)&sA[ct][(wr * 64 + i * 16 + lo4) * 64 + kk * 32 + hi * 8];
#pragma unroll
      for (int j = 0; j < 4; ++j)
        bn[j] = *(const bf16x8*)&sB[ct][(wc * 64 + j * 16 + lo4) * 64 + kk * 32 + hi * 8];
#pragma unroll
      for (int i = 0; i < 4; ++i)
#pragma unroll
        for (int j = 0; j < 4; ++j)
          acc[i][j] = MFMA16(am[i], bn[j], acc[i][j]);
    }
    __builtin_amdgcn_s_barrier();
    __builtin_amdgcn_sched_barrier(0);
    if (t + 2 < nk) {
      int k2 = (t + 2) * 64;
#pragma unroll
      for (int i = 0; i < 4; ++i) {
        __builtin_amdgcn_global_load_lds((const AS1 void*)(gA[i] + k2),
                                         (AS3 void*)&sA[ct][(w * 4 + i) * 512], 16, 0, 0);
        __builtin_amdgcn_global_load_lds((const AS1 void*)(gB[i] + k2),
                                         (AS3 void*)&sB[ct][(w * 4 + i) * 512], 16, 0, 0);
      }
    }
  }
  const int colg0 = col0 + wc * 64;
  float* Cp = (colg0 < 1024) ? Cr : Ci;
  const int cb = colg0 & 1023;
#pragma unroll
  for (int i = 0; i < 4; ++i) {
#pragma unroll
    for (int j = 0; j < 4; ++j) {
      float bv = bias[colg0 + j * 16 + lo4];
#pragma unroll
      for (int r = 0; r < 4; ++r) {
        int rowg = row0 + wr * 64 + i * 16 + hi * 4 + r;
        Cp[(size_t)rowg * ldc + cb + j * 16 + lo4] = acc[i][j][r] + bv;
      }
    }
  }
}

// ============================================================
// LN row stats over bf16 C6 (unchanged).
// ============================================================
__global__ __launch_bounds__(256) void ln_stats3(
    const bf16_t* __restrict__ C6, float2* __restrict__ st)
{
  __shared__ float red[8];
  const int row = blockIdx.x;
  const int p = blockIdx.y;
  const int tid = threadIdx.x;
  const bf16_t* pr = C6 + (size_t)row * 6144 + p * 2048;
  const bf16_t* pi = pr + 1024;
  bf16x4 vr = *(const bf16x4*)(pr + tid * 4);
  bf16x4 vi = *(const bf16x4*)(pi + tid * 4);
  float s = 0.f, s2 = 0.f;
#pragma unroll
  for (int t = 0; t < 4; ++t) {
    float a = (float)vr[t], b = (float)vi[t];
    float mg = sqrtf(a * a + b * b);
    s += mg; s2 += mg * mg;
  }
#pragma unroll
  for (int o = 32; o; o >>= 1) { s += __shfl_down(s, o); s2 += __shfl_down(s2, o); }
  if ((tid & 63) == 0) { red[tid >> 6] = s; red[4 + (tid >> 6)] = s2; }
  __syncthreads();
  if (tid == 0) {
    float S = red[0] + red[1] + red[2] + red[3];
    float S2 = red[4] + red[5] + red[6] + red[7];
    float mean = S * (1.f / DIMM);
    float var = S2 * (1.f / DIMM) - mean * mean;
    st[(size_t)p * 4096 + row] = make_float2(mean, rsqrtf(var + EPS_LN));
  }
}

// ============================================================
// 1024-pt RADIX-4 DIF FFT v3 — bf16 in/out (unchanged from round 14).
// ============================================================
#define LIDX(d_, c_) (((d_) << 10) + ((c_) ^ (((c_) >> 5) & 31) ^ (((d_) & 7) << 2)))

__global__ __launch_bounds__(512) void fft_kernel(
    const bf16_t* __restrict__ inR, const bf16_t* __restrict__ inI,
    bf16_t* __restrict__ outR, bf16_t* __restrict__ outI,
    int in_sb, int in_sh, int in_sn, int in_sd,
    int out_sb, int out_sh, int out_sn,
    float sign, float oscale, int imode, int omode,
    const float2* __restrict__ stats,
    const float* __restrict__ gamma, const float* __restrict__ beta)
{
  __shared__ float lr[8 * 1024], li[8 * 1024];
  __shared__ float2 tw[1024];
  const int tid = threadIdx.x;
  const int dc = blockIdx.x & 7;
  const int bh = blockIdx.x >> 3;
  const int b = bh >> 4, h = bh & 15;
  const bf16_t* bR = inR + (size_t)b * in_sb + (size_t)h * in_sh;
  const bf16_t* bI = inI + (size_t)b * in_sb + (size_t)h * in_sh;
#pragma unroll
  for (int t = tid; t < 1024; t += 512) {
    float ang = sign * 3.14159265358979323846f * (float)t * (1.f / 512.f);
    float sn, cs;
    __sincosf(ang, &sn, &cs);
    tw[t] = make_float2(cs, sn);
  }
  if (imode == 0) {
    float gg[8], bb[8];
    if (stats) {
#pragma unroll
      for (int ds = 0; ds < 8; ++ds) {
        gg[ds] = gamma[h * DHH + dc * 8 + ds];
        bb[ds] = beta[h * DHH + dc * 8 + ds];
      }
    }
#pragma unroll
    for (int rep = 0; rep < 2; ++rep) {
      int n = tid + rep * 512;
      bf16x8 r8 = *(const bf16x8*)(bR + (size_t)n * in_sn + dc * 8);
      bf16x8 i8 = *(const bf16x8*)(bI + (size_t)n * in_sn + dc * 8);
      float ur[8], ui[8];
#pragma unroll
      for (int ds = 0; ds < 8; ++ds) { ur[ds] = (float)r8[ds]; ui[ds] = (float)i8[ds]; }
      if (stats) {
        float2 stv = stats[b * NN + n];
#pragma unroll
        for (int ds = 0; ds < 8; ++ds) {
          float a = ur[ds], c2 = ui[ds];
          float mag = sqrtf(a * a + c2 * c2);
          float nm = (mag - stv.x) * stv.y * gg[ds] + bb[ds];
          if (mag > 0.f) { float sc = nm / mag; ur[ds] = a * sc; ui[ds] = c2 * sc; }
          else           { ur[ds] = nm; ui[ds] = 0.f; }
        }
      }
#pragma unroll
      for (int ds = 0; ds < 8; ++ds) {
        int ax = LIDX(ds, n);
        lr[ax] = ur[ds];
        li[ax] = ui[ds];
      }
    }
  } else {
    const int ds = tid & 7, nb = tid >> 3;
    const bf16_t* pR = bR + (size_t)(dc * 8 + ds) * in_sd + nb * 16;
    const bf16_t* pI = bI + (size_t)(dc * 8 + ds) * in_sd + nb * 16;
    bf16x8 a0 = *(const bf16x8*)pR, a1 = *(const bf16x8*)(pR + 8);
    bf16x8 b0 = *(const bf16x8*)pI, b1 = *(const bf16x8*)(pI + 8);
#pragma unroll
    for (int k = 0; k < 8; ++k) {
      int c = nb * 16 + k;
      lr[LIDX(ds, c)] = (float)a0[k];       li[LIDX(ds, c)] = (float)b0[k];
      lr[LIDX(ds, c + 8)] = (float)a1[k];   li[LIDX(ds, c + 8)] = (float)b1[k];
    }
  }
  __syncthreads();
  const int dsub = tid & 7;
  const int jb = tid >> 3;
  int lq2 = 8;
  for (int st = 0; st < 5; ++st) {
    const int qtr = 1 << lq2;
    const int tmul = 1 << (2 * st);
    for (int jt = 0; jt < 4; ++jt) {
      int j = jb + jt * 64;
      int o = j & (qtr - 1);
      int i0 = ((j >> lq2) << (lq2 + 2)) + o;
      int a0 = LIDX(dsub, i0);
      int a1 = LIDX(dsub, i0 + qtr);
      int a2 = LIDX(dsub, i0 + 2 * qtr);
      int a3 = LIDX(dsub, i0 + 3 * qtr);
      float x0r = lr[a0], x0i = li[a0];
      float x1r = lr[a1], x1i = li[a1];
      float x2r = lr[a2], x2i = li[a2];
      float x3r = lr[a3], x3i = li[a3];
      float ar = x0r + x2r, ai2 = x0i + x2i;
      float br = x0r - x2r, bi  = x0i - x2i;
      float cr = x1r + x3r, ci  = x1i + x3i;
      float dr = x1r - x3r, di  = x1i - x3i;
      float2 t1 = tw[o * tmul];
      float2 t2 = tw[2 * o * tmul];
      float2 t3 = tw[3 * o * tmul];
      lr[a0] = ar + cr;  li[a0] = ai2 + ci;
      float u1r = br - sign * di, u1i = bi + sign * dr;
      lr[a1] = u1r * t1.x - u1i * t1.y;  li[a1] = u1r * t1.y + u1i * t1.x;
      float u2r = ar - cr, u2i = ai2 - ci;
      lr[a2] = u2r * t2.x - u2i * t2.y;  li[a2] = u2r * t2.y + u2i * t2.x;
      float u3r = br + sign * di, u3i = bi - sign * dr;
      lr[a3] = u3r * t3.x - u3i * t3.y;  li[a3] = u3r * t3.y + u3i * t3.x;
    }
    __syncthreads();
    lq2 -= 2;
  }
  bf16_t* oRb = outR + (size_t)b * out_sb + (size_t)h * out_sh;
  bf16_t* oIb = outI + (size_t)b * out_sb + (size_t)h * out_sh;
#pragma unroll
  for (int rep = 0; rep < 2; ++rep) {
    int n = tid + rep * 512;
    int rv2 = __brev((unsigned)n) >> 22;
    int p = ((rv2 & 0x155) << 1) | ((rv2 >> 1) & 0x155);
    float fr[8], fi[8];
#pragma unroll
    for (int ds = 0; ds < 8; ++ds) {
      fr[ds] = lr[LIDX(ds, p)] * oscale;
      fi[ds] = li[LIDX(ds, p)] * oscale;
    }
    if (omode == 1) {
      size_t tb = (size_t)(n >> 5) * 4096;
#pragma unroll
      for (int ds = 0; ds < 8; ++ds) {
        int dch = dc * 8 + ds;
        size_t ga = tb + (size_t)dch * 32 + ((n & 31) ^ (((dch >> 1) & 3) << 3));
        oRb[ga] = (bf16_t)fr[ds];
        oIb[ga] = (bf16_t)fi[ds];
      }
    } else {
      int cb = dc * 8;
      if (omode == 2) cb = (dc ^ (n & 7)) * 8;
      bf16x8 v0, w0;
#pragma unroll
      for (int k = 0; k < 8; ++k) {
        v0[k] = (bf16_t)fr[k];
        w0[k] = (bf16_t)fi[k];
      }
      size_t gb = (size_t)n * out_sn + cb;
      *(bf16x8*)(oRb + gb) = v0;
      *(bf16x8*)(oIb + gb) = w0;
    }
  }
}

// ============================================================
// Flash attention v7 (unchanged control).
// ============================================================
__global__ __launch_bounds__(256, 2) void fattn(
    const bf16_t* __restrict__ Qf, const bf16_t* __restrict__ Kfs,
    const bf16_t* __restrict__ Vfs, bf16_t* __restrict__ OT)
{
  __shared__ bf16_t K3[3][4096];
  __shared__ bf16_t V3[3][4096];
  const int tid = threadIdx.x;
  const int w = tid >> 6, l = tid & 63;
  const int lq = l & 31;
  const int h = l >> 5;
  const int i = blockIdx.x;
  const int j = i >> 3;
  const int bh = (i & 7) * 8 + (j >> 3);
  const int q0 = (j & 7) * 128 + w * 32;

  bf16x8 bq[8];
  const bf16_t* qp = Qf + ((size_t)bh * NN + q0 + lq) * 128 + h * 8;
#pragma unroll
  for (int kk = 0; kk < 8; ++kk) bq[kk] = *(const bf16x8*)(qp + kk * 16);

  f32x16 o[4] = {};
  float m = -3e38f, ln = 0.f;

  const bf16_t* kg = Kfs + (size_t)bh * 131072 + w * 1024 + l * 8;
  const bf16_t* vg = Vfs + (size_t)bh * 131072 + w * 1024 + l * 8;
  const int kswz = (lq & 7) << 3;
  const int vswz = ((lq >> 1) & 3) << 3;

#pragma unroll
  for (int tt = 0; tt < 2; ++tt) {
    const bf16_t* kt = kg + (size_t)tt * 4096;
    const bf16_t* vt = vg + (size_t)tt * 4096;
#pragma unroll
    for (int ii = 0; ii < 2; ++ii) {
      __builtin_amdgcn_global_load_lds((const AS1 void*)(kt + ii * 512),
                                       (AS3 void*)&K3[tt][w * 1024 + ii * 512], 16, 0, 0);
      __builtin_amdgcn_global_load_lds((const AS1 void*)(vt + ii * 512),
                                       (AS3 void*)&V3[tt][w * 1024 + ii * 512], 16, 0, 0);
    }
  }
  asm volatile("s_waitcnt vmcnt(4)" ::: "memory");
  __builtin_amdgcn_s_barrier();
  __builtin_amdgcn_sched_barrier(0);

  int cur = 0;
  for (int t = 0; t < 32; ++t) {
    if (t < 30) {
      int nb = cur + 2; if (nb >= 3) nb -= 3;
      const bf16_t* kt = kg + (size_t)(t + 2) * 4096;
      const bf16_t* vt = vg + (size_t)(t + 2) * 4096;
#pragma unroll
      for (int ii = 0; ii < 2; ++ii) {
        __builtin_amdgcn_global_load_lds((const AS1 void*)(kt + ii * 512),
                                         (AS3 void*)&K3[nb][w * 1024 + ii * 512], 16, 0, 0);
        __builtin_amdgcn_global_load_lds((const AS1 void*)(vt + ii * 512),
                                         (AS3 void*)&V3[nb][w * 1024 + ii * 512], 16, 0, 0);
      }
    }

    f32x16 s = {};
#pragma unroll
    for (int kk = 0; kk < 8; ++kk) {
      bf16x8 ak = *(const bf16x8*)&K3[cur][lq * 128 + ((kk * 16 + h * 8) ^ kswz)];
      s = MFMA32(ak, bq[kk], s);
    }

    float pmax = s[0];
#pragma unroll
    for (int r = 1; r < 16; ++r) pmax = fmaxf(pmax, s[r]);
    pmax = fmaxf(pmax, __shfl_xor(pmax, 32));
    if (!__all(pmax - m <= 8.f)) {
      float mnew = fmaxf(m, pmax);
      float alpha = __expf(m - mnew);
      m = mnew;
      ln *= alpha;
#pragma unroll
      for (int db = 0; db < 4; ++db)
#pragma unroll
        for (int r = 0; r < 16; ++r) o[db][r] *= alpha;
    }
    float pf[16];
    float rs = 0.f;
#pragma unroll
    for (int r = 0; r < 16; ++r) { pf[r] = __expf(s[r] - m); rs += pf[r]; }
    rs += __shfl_xor(rs, 32);
    ln += rs;

    unsigned pw[8];
#pragma unroll
    for (int ii = 0; ii < 8; ++ii) pw[ii] = pk2(pf[2 * ii], pf[2 * ii + 1]);
    unsigned r0 = (unsigned)__shfl_xor((int)(h ? pw[0] : pw[2]), 32);
    unsigned r1 = (unsigned)__shfl_xor((int)(h ? pw[1] : pw[3]), 32);
    unsigned r2 = (unsigned)__shfl_xor((int)(h ? pw[4] : pw[6]), 32);
    unsigned r3 = (unsigned)__shfl_xor((int)(h ? pw[5] : pw[7]), 32);
    U16 bp0, bp1;
    bp0.u.x = h ? r0 : pw[0];  bp0.u.y = h ? r1 : pw[1];
    bp0.u.z = h ? pw[2] : r0;  bp0.u.w = h ? pw[3] : r1;
    bp1.u.x = h ? r2 : pw[4];  bp1.u.y = h ? r3 : pw[5];
    bp1.u.z = h ? pw[6] : r2;  bp1.u.w = h ? pw[7] : r3;

#pragma unroll
    for (int db = 0; db < 4; ++db) {
      int r = db * 32 + lq;
      bf16x8 av0 = *(const bf16x8*)&V3[cur][r * 32 + ((h * 8) ^ vswz)];
      bf16x8 av1 = *(const bf16x8*)&V3[cur][r * 32 + ((16 + h * 8) ^ vswz)];
      o[db] = MFMA32(av0, bp0.v, o[db]);
      o[db] = MFMA32(av1, bp1.v, o[db]);
    }

    if (t < 31) {
      if (t < 30) asm volatile("s_waitcnt vmcnt(4)" ::: "memory");
      else        asm volatile("s_waitcnt vmcnt(0)" ::: "memory");
      __builtin_amdgcn_s_barrier();
      __builtin_amdgcn_sched_barrier(0);
    }
    cur = (cur == 2) ? 0 : cur + 1;
  }

  float inv = 1.f / ln;
  const size_t otb = (size_t)bh * 128 * NN + q0 + lq;
#pragma unroll
  for (int db = 0; db < 4; ++db)
#pragma unroll
    for (int r = 0; r < 16; ++r) {
      int dl = (r & 3) + 8 * (r >> 2) + 4 * h;
      OT[otb + (size_t)(db * 32 + dl) * NN] = (bf16_t)(o[db][r] * inv);
    }
}

// ============================================================
// Host-side orchestration
// ============================================================
extern "C" void kernel_launch(void* const* d_in, const int* in_sizes, int n_in,
                              void* d_out, int out_size, void* d_ws, size_t ws_size,
                              hipStream_t stream) {
  const float* xr   = (const float*)d_in[0];
  const float* xi   = (const float*)d_in[1];
  const float* Wqr  = (const float*)d_in[2];
  const float* Wqi  = (const float*)d_in[3];
  const float* bqr  = (const float*)d_in[4];
  const float* bqi  = (const float*)d_in[5];
  const float* Wkr  = (const float*)d_in[6];
  const float* Wki  = (const float*)d_in[7];
  const float* bkr  = (const float*)d_in[8];
  const float* bki  = (const float*)d_in[9];
  const float* Wvr  = (const float*)d_in[10];
  const float* Wvi  = (const float*)d_in[11];
  const float* bvr  = (const float*)d_in[12];
  const float* bvi  = (const float*)d_in[13];
  const float* Wor  = (const float*)d_in[14];
  const float* Woi  = (const float*)d_in[15];
  const float* bor  = (const float*)d_in[16];
  const float* boi  = (const float*)d_in[17];
  const float* gq   = (const float*)d_in[18];
  const float* beq  = (const float*)d_in[19];
  const float* gk   = (const float*)d_in[20];
  const float* bek  = (const float*)d_in[21];
  const float* gv   = (const float*)d_in[22];
  const float* bev  = (const float*)d_in[23];

  char* wp = (char*)d_ws;
  bf16_t* Axaug = (bf16_t*)wp;  wp += (size_t)4096 * 2048 * 2;
  bf16_t* Wcat3 = (bf16_t*)wp;  wp += (size_t)6144 * 2048 * 2;
  float*  bcat3 = (float*)wp;   wp += (size_t)6144 * 4;
  float2* lnst3 = (float2*)wp;  wp += (size_t)3 * 4096 * 8;
  bf16_t* C6    = (bf16_t*)wp;  wp += (size_t)4096 * 6144 * 2;
  bf16_t* Qf    = (bf16_t*)wp;  wp += (size_t)64 * 1024 * 128 * 2;
  bf16_t* Kf    = (bf16_t*)wp;  wp += (size_t)64 * 1024 * 128 * 2;
  bf16_t* VfT   = (bf16_t*)wp;  wp += (size_t)64 * 1024 * 128 * 2;
  bf16_t* OT    = C6;
  bf16_t* Yaug  = Qf;

  const dim3 gQKV(48, 32);
  const dim3 gGemmO(16, 32);
  const int gPackX = (4096 * 2048 / 8) / 256;
  const int gPackW = (2048 * 2048 / 8) / 256;
  const dim3 gLn(4096, 3);
  const int gFft = 64 * 8;
  const int gAtt = 64 * 8;

  pack_x<<<gPackX, 256, 0, stream>>>(xr, xi, Axaug);
  pack_w<<<gPackW, 256, 0, stream>>>(Wqr, Wqi, bqr, bqi,
                                     Wcat3, bcat3);
  pack_w<<<gPackW, 256, 0, stream>>>(Wkr, Wki, bkr, bki,
                                     Wcat3 + (size_t)2048 * 2048, bcat3 + 2048);
  pack_w<<<gPackW, 256, 0, stream>>>(Wvr, Wvi, bvr, bvi,
                                     Wcat3 + (size_t)4096 * 2048, bcat3 + 4096);

  gemm_qkv<<<gQKV, 256, 0, stream>>>(Axaug, Wcat3, bcat3, C6);
  ln_stats3<<<gLn, 256, 0, stream>>>(C6, lnst3);

  fft_kernel<<<gFft, 512, 0, stream>>>(C6, C6 + 1024, Qf, Qf + 64,
      NN * 6144, DHH, 6144, 1,
      16 * NN * 128, NN * 128, 128,
      -1.0f, 0.03125f * 0.125f, 0, 0, lnst3, gq, beq);
  fft_kernel<<<gFft, 512, 0, stream>>>(C6 + 2048, C6 + 3072, Kf, Kf + 64,
      NN * 6144, DHH, 6144, 1,
      16 * NN * 128, NN * 128, 128,
      -1.0f, 0.03125f, 0, 2, lnst3 + 4096, gk, bek);
  fft_kernel<<<gFft, 512, 0, stream>>>(C6 + 4096, C6 + 5120, VfT, VfT + 2048,
      NN * 6144, DHH, 6144, 1,
      16 * 131072, 131072, 0,
      -1.0f, 0.03125f, 0, 1, lnst3 + 8192, gv, bev);

  fattn<<<gAtt, 256, 0, stream>>>(Qf, Kf, VfT, OT);

  fft_kernel<<<gFft, 512, 0, stream>>>(OT, OT + (size_t)64 * NN, Yaug, Yaug + 1024,
      16 * 128 * NN, 128 * NN, 1, NN,
      NN * 2048, 64, 2048,
      +1.0f, 0.03125f, 1, 0, nullptr, nullptr, nullptr);

  float* yout = (float*)d_out;
  pack_w<<<gPackW, 256, 0, stream>>>(Wor, Woi, bor, boi, Wcat3, bcat3);
  gemm_bf16<<<gGemmO, 256, 0, stream>>>(Yaug, Wcat3, bcat3, yout, yout + 1024, 2048);
}